// Round 1
// baseline (6566.918 us; speedup 1.0000x reference)
//
#include <hip/hip_runtime.h>
#include <math.h>

// Problem constants
#define BB 2
#define NN 2048
#define DM 1024
#define NH 16
#define NKV 4
#define HD 64
#define RR 256
#define HALF 1024
#define NM 1792   // NN - RR

// ---------------------------------------------------------------------------
// Generic row-tiled fp32 GEMM: C[M x Nc] = A[M x K] @ W[K x Nc]
// 16 rows per block, K staged in 256-chunks in LDS, 256 threads = 1 col each
// per col-tile of 256. Requires M % 16 == 0, K % 256 == 0, Nc % 256 == 0.
// ---------------------------------------------------------------------------
__global__ __launch_bounds__(256) void gemm_rows(
    const float* __restrict__ A, const float* __restrict__ W,
    float* __restrict__ C, int M, int K, int Nc) {
  __shared__ float As[16][256];
  const int row0 = blockIdx.x * 16;
  const int col = blockIdx.y * 256 + threadIdx.x;
  float acc[16];
#pragma unroll
  for (int r = 0; r < 16; ++r) acc[r] = 0.f;
  for (int k0 = 0; k0 < K; k0 += 256) {
    // cooperative load 16x256 tile (float4)
    for (int idx = threadIdx.x; idx < 16 * 64; idx += 256) {
      int r = idx >> 6, c4 = idx & 63;
      const float4* src =
          reinterpret_cast<const float4*>(A + (size_t)(row0 + r) * K + k0) + c4;
      reinterpret_cast<float4*>(&As[r][0])[c4] = *src;
    }
    __syncthreads();
    for (int dk = 0; dk < 256; ++dk) {
      float wv = W[(size_t)(k0 + dk) * Nc + col];
#pragma unroll
      for (int r = 0; r < 16; ++r) acc[r] += As[r][dk] * wv;
    }
    __syncthreads();
  }
  for (int r = 0; r < 16; ++r) C[(size_t)(row0 + r) * Nc + col] = acc[r];
}

// ---------------------------------------------------------------------------
// Normalize each 256-float row of metric in place: row /= max(||row||, 1e-12)
// ---------------------------------------------------------------------------
__global__ __launch_bounds__(256) void normalize_rows(float* __restrict__ m) {
  const int row = blockIdx.x;
  const int t = threadIdx.x;
  float v = m[(size_t)row * 256 + t];
  float ss = v * v;
#pragma unroll
  for (int o = 32; o > 0; o >>= 1) ss += __shfl_xor(ss, o, 64);
  __shared__ float wsum[4];
  if ((t & 63) == 0) wsum[t >> 6] = ss;
  __syncthreads();
  float tot = wsum[0] + wsum[1] + wsum[2] + wsum[3];
  float inv = 1.f / fmaxf(sqrtf(tot), 1e-12f);
  m[(size_t)row * 256 + t] = v * inv;
}

// ---------------------------------------------------------------------------
// Fused scores + row-argmax. Block handles 8 'a' rows (even rows of metric)
// against all 1024 'b' rows (odd rows). Ties -> lowest j (np argmax semantics).
// ---------------------------------------------------------------------------
__global__ __launch_bounds__(256) void scores_argmax(
    const float* __restrict__ metric, float* __restrict__ best_s,
    int* __restrict__ best_b) {
  const int b = blockIdx.y;
  const int i0 = blockIdx.x * 8;
  __shared__ float As[8][256];
  const float* mb = metric + (size_t)b * NN * 256;
  for (int idx = threadIdx.x; idx < 8 * 256; idx += 256) {
    int r = idx >> 8, c = idx & 255;
    As[r][c] = mb[(size_t)(2 * (i0 + r)) * 256 + c];
  }
  __syncthreads();
  float bv[8];
  int bj[8];
#pragma unroll
  for (int r = 0; r < 8; ++r) { bv[r] = -2.f; bj[r] = 0; }
  for (int jj = 0; jj < 4; ++jj) {
    int j = threadIdx.x + jj * 256;  // ascending per-thread -> strict > keeps lowest j
    const float* brow = mb + (size_t)(2 * j + 1) * 256;
    float acc[8];
#pragma unroll
    for (int r = 0; r < 8; ++r) acc[r] = 0.f;
    for (int c = 0; c < 256; ++c) {
      float bvv = brow[c];
#pragma unroll
      for (int r = 0; r < 8; ++r) acc[r] += As[r][c] * bvv;
    }
#pragma unroll
    for (int r = 0; r < 8; ++r)
      if (acc[r] > bv[r]) { bv[r] = acc[r]; bj[r] = j; }
  }
  __shared__ float rv[256];
  __shared__ int ri[256];
  for (int r = 0; r < 8; ++r) {
    rv[threadIdx.x] = bv[r];
    ri[threadIdx.x] = bj[r];
    __syncthreads();
    for (int s = 128; s > 0; s >>= 1) {
      if (threadIdx.x < (unsigned)s) {
        float v2 = rv[threadIdx.x + s];
        int i2 = ri[threadIdx.x + s];
        float v1 = rv[threadIdx.x];
        int i1 = ri[threadIdx.x];
        if (v2 > v1 || (v2 == v1 && i2 < i1)) {
          rv[threadIdx.x] = v2;
          ri[threadIdx.x] = i2;
        }
      }
      __syncthreads();
    }
    if (threadIdx.x == 0) {
      best_s[b * HALF + i0 + r] = rv[0];
      best_b[b * HALF + i0 + r] = ri[0];
    }
    __syncthreads();
  }
}

// ---------------------------------------------------------------------------
// Stable descending bitonic argsort of 1024 scores per batch.
// Comparator: a before b iff (sa > sb) || (sa == sb && ia < ib)  (total order)
// ---------------------------------------------------------------------------
__global__ __launch_bounds__(256) void sort_desc(const float* __restrict__ best_s,
                                                 int* __restrict__ order) {
  const int b = blockIdx.x;
  __shared__ float sv[1024];
  __shared__ int si[1024];
  for (int i = threadIdx.x; i < 1024; i += 256) {
    sv[i] = best_s[b * HALF + i];
    si[i] = i;
  }
  __syncthreads();
  for (int k = 2; k <= 1024; k <<= 1) {
    for (int j = k >> 1; j > 0; j >>= 1) {
      for (int t = threadIdx.x; t < 1024; t += 256) {
        int ixj = t ^ j;
        if (ixj > t) {
          bool dir = ((t & k) == 0);
          float va = sv[t], vb = sv[ixj];
          int ia = si[t], ib = si[ixj];
          bool before = (vb > va) || (vb == va && ib < ia);  // e[ixj] precedes e[t]?
          if (before == dir) {
            sv[t] = vb; sv[ixj] = va;
            si[t] = ib; si[ixj] = ia;
          }
        }
      }
      __syncthreads();
    }
  }
  for (int i = threadIdx.x; i < 1024; i += 256) order[b * HALF + i] = si[i];
}

// ---------------------------------------------------------------------------
// Greedy unique-b selection (sequential, exactly mirrors the JAX scan) +
// keep-index stable compaction + partner / src_row maps. One block per batch.
// ---------------------------------------------------------------------------
__global__ __launch_bounds__(256) void select_and_index(
    const int* __restrict__ best_b, const int* __restrict__ order,
    int* __restrict__ keep_idx, int* __restrict__ src_row,
    int* __restrict__ partner) {
  const int b = blockIdx.x;
  __shared__ int used[HALF];
  __shared__ int sel_a[RR], sel_b[RR];
  __shared__ int removed[NN];
  __shared__ int tsum[256];
  for (int i = threadIdx.x; i < HALF; i += 256) used[i] = 0;
  for (int i = threadIdx.x; i < NN; i += 256) {
    removed[i] = 0;
    partner[b * NN + i] = -1;
  }
  __syncthreads();
  if (threadIdx.x == 0) {
    int cnt = 0;
    for (int step = 0; step < HALF; ++step) {
      int a = order[b * HALF + step];
      int bb = best_b[b * HALF + a];
      if (!used[bb] && cnt < RR) {
        used[bb] = 1;
        sel_a[cnt] = a;
        sel_b[cnt] = bb;
        ++cnt;
      }
    }
    for (int s = cnt; s < RR; ++s) { sel_a[s] = sel_a[0]; sel_b[s] = sel_b[0]; }
  }
  __syncthreads();
  {
    int s = threadIdx.x;  // 256 == RR
    int ga = 2 * sel_a[s], gb = 2 * sel_b[s] + 1;
    removed[gb] = 1;
    partner[b * NN + ga] = gb;
    sel_a[s] = ga;  // store globals in place
    sel_b[s] = gb;
  }
  __syncthreads();
  // exclusive prefix over keep = !removed (8 positions / thread)
  int myc = 0;
#pragma unroll
  for (int q = 0; q < 8; ++q) myc += !removed[8 * threadIdx.x + q];
  tsum[threadIdx.x] = myc;
  __syncthreads();
  for (int off = 1; off < 256; off <<= 1) {
    int v = (threadIdx.x >= (unsigned)off) ? tsum[threadIdx.x - off] : 0;
    __syncthreads();
    tsum[threadIdx.x] += v;
    __syncthreads();
  }
  int pos = tsum[threadIdx.x] - myc;
#pragma unroll
  for (int q = 0; q < 8; ++q) {
    int p = 8 * threadIdx.x + q;
    int sr = -1;
    if (!removed[p]) {
      if (pos < NM) {
        keep_idx[b * NM + pos] = p;
        sr = pos;
      }
      ++pos;
    }
    src_row[b * NN + p] = sr;
  }
  __syncthreads();
  {
    int s = threadIdx.x;
    src_row[b * NN + sel_b[s]] = src_row[b * NN + sel_a[s]];
  }
}

// ---------------------------------------------------------------------------
// Merge: x_m[b,t,:] = kept token (averaged with partner if it's an 'a')
// ---------------------------------------------------------------------------
__global__ __launch_bounds__(256) void merge_kernel(
    const float* __restrict__ x, const int* __restrict__ keep_idx,
    const int* __restrict__ partner, float* __restrict__ x_m) {
  const int mrow = blockIdx.x;
  const int b = mrow / NM;
  const int t = mrow % NM;
  const int p = keep_idx[b * NM + t];
  const int pp = partner[b * NN + p];
  const float4* src =
      reinterpret_cast<const float4*>(x + ((size_t)b * NN + p) * DM);
  float4 val = src[threadIdx.x];
  if (pp >= 0) {
    const float4* s2 =
        reinterpret_cast<const float4*>(x + ((size_t)b * NN + pp) * DM);
    float4 v2 = s2[threadIdx.x];
    val.x = 0.5f * (val.x + v2.x);
    val.y = 0.5f * (val.y + v2.y);
    val.z = 0.5f * (val.z + v2.z);
    val.w = 0.5f * (val.w + v2.w);
  }
  reinterpret_cast<float4*>(x_m + (size_t)mrow * DM)[threadIdx.x] = val;
}

// ---------------------------------------------------------------------------
// RoPE in place: t layout (B*NM, heads, 64); position = row % NM
// ---------------------------------------------------------------------------
__global__ __launch_bounds__(256) void rope_kernel(float* __restrict__ t,
                                                   const float* __restrict__ fc,
                                                   int heads) {
  const int row = blockIdx.x;
  const int tpos = row % NM;
  const int npairs = heads * 32;
  for (int idx = threadIdx.x; idx < npairs; idx += 256) {
    int h = idx >> 5, u = idx & 31;
    float c = fc[(tpos * 32 + u) * 2];
    float s = fc[(tpos * 32 + u) * 2 + 1];
    float* base = t + (size_t)row * heads * 64 + h * 64 + 2 * u;
    float x1 = base[0], x2 = base[1];
    base[0] = x1 * c - x2 * s;
    base[1] = x1 * s + x2 * c;
  }
}

// ---------------------------------------------------------------------------
// Attention: one wave per (b, h, query). Non-causal, GQA (kv head = h/4).
// Scores phase: lane owns a key; PV phase: lane owns an output dim.
// Online softmax in fp32.
// ---------------------------------------------------------------------------
__global__ __launch_bounds__(256) void attn_kernel(
    const float* __restrict__ q, const float* __restrict__ k,
    const float* __restrict__ v, float* __restrict__ o) {
  const int wave = blockIdx.x * 4 + (threadIdx.x >> 6);
  const int lane = threadIdx.x & 63;
  const int qi = wave % NM;
  const int rest = wave / NM;
  const int h = rest % NH;
  const int b = rest / NH;
  const int kvh = h >> 2;
  const float qreg = q[((size_t)(b * NM + qi)) * DM + h * 64 + lane] * 0.125f;
  float m = -1e30f, l = 0.f, acc = 0.f;
  const float* kb = k + (size_t)b * NM * (NKV * HD) + kvh * HD;
  const float* vb = v + (size_t)b * NM * (NKV * HD) + kvh * HD;
  for (int jb = 0; jb < NM; jb += 64) {
    // --- scores: lane owns key j = jb + lane
    const float4* krow =
        reinterpret_cast<const float4*>(kb + (size_t)(jb + lane) * (NKV * HD));
    float s = 0.f;
#pragma unroll
    for (int d4 = 0; d4 < 16; ++d4) {
      float4 kv4 = krow[d4];
      s += __shfl(qreg, 4 * d4 + 0, 64) * kv4.x;
      s += __shfl(qreg, 4 * d4 + 1, 64) * kv4.y;
      s += __shfl(qreg, 4 * d4 + 2, 64) * kv4.z;
      s += __shfl(qreg, 4 * d4 + 3, 64) * kv4.w;
    }
    // --- online softmax update
    float bm = s;
#pragma unroll
    for (int off = 32; off > 0; off >>= 1) bm = fmaxf(bm, __shfl_xor(bm, off, 64));
    float mn = fmaxf(m, bm);
    float alpha = __expf(m - mn);
    float p = __expf(s - mn);
    float ps = p;
#pragma unroll
    for (int off = 32; off > 0; off >>= 1) ps += __shfl_xor(ps, off, 64);
    l = l * alpha + ps;
    m = mn;
    acc *= alpha;
    // --- PV: lane owns output dim = lane
    const float* vrow = vb + (size_t)jb * (NKV * HD) + lane;
#pragma unroll
    for (int jj = 0; jj < 64; ++jj) {
      float pj = __shfl(p, jj, 64);
      acc += pj * vrow[(size_t)jj * (NKV * HD)];
    }
  }
  o[((size_t)(b * NM + qi)) * DM + h * 64 + lane] = acc / l;
}

// ---------------------------------------------------------------------------
// Unmerge scatter: out[b,p,:] = out_m[b,src_row,:] or 0
// ---------------------------------------------------------------------------
__global__ __launch_bounds__(256) void scatter_out(
    const float* __restrict__ out_m, const int* __restrict__ src_row,
    float* __restrict__ out) {
  const int row = blockIdx.x;
  const int b = row >> 11;
  const int p = row & (NN - 1);
  const int sr = src_row[b * NN + p];
  float4 val = make_float4(0.f, 0.f, 0.f, 0.f);
  if (sr >= 0)
    val = reinterpret_cast<const float4*>(out_m +
                                          ((size_t)(b * NM + sr)) * DM)[threadIdx.x];
  reinterpret_cast<float4*>(out + (size_t)row * DM)[threadIdx.x] = val;
}

// ---------------------------------------------------------------------------
extern "C" void kernel_launch(void* const* d_in, const int* in_sizes, int n_in,
                              void* d_out, int out_size, void* d_ws,
                              size_t ws_size, hipStream_t stream) {
  const float* x = (const float*)d_in[0];
  const float* fc = (const float*)d_in[1];
  const float* Wq = (const float*)d_in[2];
  const float* Wk = (const float*)d_in[3];
  const float* Wv = (const float*)d_in[4];
  const float* Wo = (const float*)d_in[5];
  float* out = (float*)d_out;

  char* ws = (char*)d_ws;
  size_t off = 0;
  auto alloc = [&](size_t bytes) {
    void* p = ws + off;
    off += (bytes + 255) & ~(size_t)255;
    return p;
  };
  float* metric = (float*)alloc((size_t)BB * NN * 256 * 4);   // 4 MB
  float* best_s = (float*)alloc((size_t)BB * HALF * 4);
  int* best_b = (int*)alloc((size_t)BB * HALF * 4);
  int* order = (int*)alloc((size_t)BB * HALF * 4);
  int* keep_idx = (int*)alloc((size_t)BB * NM * 4);
  int* src_row = (int*)alloc((size_t)BB * NN * 4);
  int* partner = (int*)alloc((size_t)BB * NN * 4);
  float* x_m = (float*)alloc((size_t)BB * NM * DM * 4);       // 14 MB (reused as out_m)
  float* qb = (float*)alloc((size_t)BB * NM * DM * 4);        // 14 MB
  float* kb = (float*)alloc((size_t)BB * NM * NKV * HD * 4);  // 3.5 MB
  float* vb = (float*)alloc((size_t)BB * NM * NKV * HD * 4);  // 3.5 MB
  float* attn_o = (float*)alloc((size_t)BB * NM * DM * 4);    // 14 MB
  float* out_m = x_m;  // x_m is dead after QKV projections

  // 1. metric = x @ Wk  (full sequence)
  gemm_rows<<<dim3((BB * NN) / 16, 256 / 256), 256, 0, stream>>>(
      x, Wk, metric, BB * NN, DM, 256);
  // 2. normalize rows
  normalize_rows<<<BB * NN, 256, 0, stream>>>(metric);
  // 3. cosine scores + argmax over b-halves
  scores_argmax<<<dim3(HALF / 8, BB), 256, 0, stream>>>(metric, best_s, best_b);
  // 4. stable descending argsort per batch
  sort_desc<<<BB, 256, 0, stream>>>(best_s, order);
  // 5. greedy selection + index maps
  select_and_index<<<BB, 256, 0, stream>>>(best_b, order, keep_idx, src_row,
                                           partner);
  // 6. merge tokens
  merge_kernel<<<BB * NM, 256, 0, stream>>>(x, keep_idx, partner, x_m);
  // 7. projections
  gemm_rows<<<dim3((BB * NM) / 16, 4), 256, 0, stream>>>(x_m, Wq, qb, BB * NM,
                                                         DM, DM);
  gemm_rows<<<dim3((BB * NM) / 16, 1), 256, 0, stream>>>(x_m, Wk, kb, BB * NM,
                                                         DM, NKV * HD);
  gemm_rows<<<dim3((BB * NM) / 16, 1), 256, 0, stream>>>(x_m, Wv, vb, BB * NM,
                                                         DM, NKV * HD);
  // 8. RoPE on q and k
  rope_kernel<<<BB * NM, 256, 0, stream>>>(qb, fc, NH);
  rope_kernel<<<BB * NM, 256, 0, stream>>>(kb, fc, NKV);
  // 9. attention (one wave per (b,h,query))
  attn_kernel<<<(BB * NH * NM) / 4, 256, 0, stream>>>(qb, kb, vb, attn_o);
  // 10. output projection
  gemm_rows<<<dim3((BB * NM) / 16, 4), 256, 0, stream>>>(attn_o, Wo, out_m,
                                                         BB * NM, DM, DM);
  // 11. unmerge scatter
  scatter_out<<<BB * NN, 256, 0, stream>>>(out_m, src_row, out);
}

// Round 2
// 3873.138 us; speedup vs baseline: 1.6955x; 1.6955x over previous
//
#include <hip/hip_runtime.h>
#include <math.h>

// Problem constants
#define BB 2
#define NN 2048
#define DM 1024
#define NH 16
#define NKV 4
#define HD 64
#define RR 256
#define HALF 1024
#define NM 1792   // NN - RR

// ---------------------------------------------------------------------------
// Generic row-tiled fp32 GEMM: C[M x Nc] = A[M x K] @ W[K x Nc]
// ---------------------------------------------------------------------------
__global__ __launch_bounds__(256) void gemm_rows(
    const float* __restrict__ A, const float* __restrict__ W,
    float* __restrict__ C, int M, int K, int Nc) {
  __shared__ float As[16][256];
  const int row0 = blockIdx.x * 16;
  const int col = blockIdx.y * 256 + threadIdx.x;
  float acc[16];
#pragma unroll
  for (int r = 0; r < 16; ++r) acc[r] = 0.f;
  for (int k0 = 0; k0 < K; k0 += 256) {
    for (int idx = threadIdx.x; idx < 16 * 64; idx += 256) {
      int r = idx >> 6, c4 = idx & 63;
      const float4* src =
          reinterpret_cast<const float4*>(A + (size_t)(row0 + r) * K + k0) + c4;
      reinterpret_cast<float4*>(&As[r][0])[c4] = *src;
    }
    __syncthreads();
    for (int dk = 0; dk < 256; ++dk) {
      float wv = W[(size_t)(k0 + dk) * Nc + col];
#pragma unroll
      for (int r = 0; r < 16; ++r) acc[r] += As[r][dk] * wv;
    }
    __syncthreads();
  }
  for (int r = 0; r < 16; ++r) C[(size_t)(row0 + r) * Nc + col] = acc[r];
}

// ---------------------------------------------------------------------------
// Normalize each 256-float row of metric in place
// ---------------------------------------------------------------------------
__global__ __launch_bounds__(256) void normalize_rows(float* __restrict__ m) {
  const int row = blockIdx.x;
  const int t = threadIdx.x;
  float v = m[(size_t)row * 256 + t];
  float ss = v * v;
#pragma unroll
  for (int o = 32; o > 0; o >>= 1) ss += __shfl_xor(ss, o, 64);
  __shared__ float wsum[4];
  if ((t & 63) == 0) wsum[t >> 6] = ss;
  __syncthreads();
  float tot = wsum[0] + wsum[1] + wsum[2] + wsum[3];
  float inv = 1.f / fmaxf(sqrtf(tot), 1e-12f);
  m[(size_t)row * 256 + t] = v * inv;
}

// ---------------------------------------------------------------------------
// Fused scores + row-argmax. Ties -> lowest j (np argmax semantics).
// ---------------------------------------------------------------------------
__global__ __launch_bounds__(256) void scores_argmax(
    const float* __restrict__ metric, float* __restrict__ best_s,
    int* __restrict__ best_b) {
  const int b = blockIdx.y;
  const int i0 = blockIdx.x * 8;
  __shared__ float As[8][256];
  const float* mb = metric + (size_t)b * NN * 256;
  for (int idx = threadIdx.x; idx < 8 * 256; idx += 256) {
    int r = idx >> 8, c = idx & 255;
    As[r][c] = mb[(size_t)(2 * (i0 + r)) * 256 + c];
  }
  __syncthreads();
  float bv[8];
  int bj[8];
#pragma unroll
  for (int r = 0; r < 8; ++r) { bv[r] = -2.f; bj[r] = 0; }
  for (int jj = 0; jj < 4; ++jj) {
    int j = threadIdx.x + jj * 256;
    const float* brow = mb + (size_t)(2 * j + 1) * 256;
    float acc[8];
#pragma unroll
    for (int r = 0; r < 8; ++r) acc[r] = 0.f;
    for (int c = 0; c < 256; ++c) {
      float bvv = brow[c];
#pragma unroll
      for (int r = 0; r < 8; ++r) acc[r] += As[r][c] * bvv;
    }
#pragma unroll
    for (int r = 0; r < 8; ++r)
      if (acc[r] > bv[r]) { bv[r] = acc[r]; bj[r] = j; }
  }
  __shared__ float rv[256];
  __shared__ int ri[256];
  for (int r = 0; r < 8; ++r) {
    rv[threadIdx.x] = bv[r];
    ri[threadIdx.x] = bj[r];
    __syncthreads();
    for (int s = 128; s > 0; s >>= 1) {
      if (threadIdx.x < (unsigned)s) {
        float v2 = rv[threadIdx.x + s];
        int i2 = ri[threadIdx.x + s];
        float v1 = rv[threadIdx.x];
        int i1 = ri[threadIdx.x];
        if (v2 > v1 || (v2 == v1 && i2 < i1)) {
          rv[threadIdx.x] = v2;
          ri[threadIdx.x] = i2;
        }
      }
      __syncthreads();
    }
    if (threadIdx.x == 0) {
      best_s[b * HALF + i0 + r] = rv[0];
      best_b[b * HALF + i0 + r] = ri[0];
    }
    __syncthreads();
  }
}

// ---------------------------------------------------------------------------
// Stable descending bitonic argsort of 1024 scores per batch.
// ---------------------------------------------------------------------------
__global__ __launch_bounds__(256) void sort_desc(const float* __restrict__ best_s,
                                                 int* __restrict__ order) {
  const int b = blockIdx.x;
  __shared__ float sv[1024];
  __shared__ int si[1024];
  for (int i = threadIdx.x; i < 1024; i += 256) {
    sv[i] = best_s[b * HALF + i];
    si[i] = i;
  }
  __syncthreads();
  for (int k = 2; k <= 1024; k <<= 1) {
    for (int j = k >> 1; j > 0; j >>= 1) {
      for (int t = threadIdx.x; t < 1024; t += 256) {
        int ixj = t ^ j;
        if (ixj > t) {
          bool dir = ((t & k) == 0);
          float va = sv[t], vb = sv[ixj];
          int ia = si[t], ib = si[ixj];
          bool before = (vb > va) || (vb == va && ib < ia);
          if (before == dir) {
            sv[t] = vb; sv[ixj] = va;
            si[t] = ib; si[ixj] = ia;
          }
        }
      }
      __syncthreads();
    }
  }
  for (int i = threadIdx.x; i < 1024; i += 256) order[b * HALF + i] = si[i];
}

// ---------------------------------------------------------------------------
// Greedy unique-b selection + index maps. One block per batch.
// ---------------------------------------------------------------------------
__global__ __launch_bounds__(256) void select_and_index(
    const int* __restrict__ best_b, const int* __restrict__ order,
    int* __restrict__ keep_idx, int* __restrict__ src_row,
    int* __restrict__ partner) {
  const int b = blockIdx.x;
  __shared__ int used[HALF];
  __shared__ int sel_a[RR], sel_b[RR];
  __shared__ int removed[NN];
  __shared__ int tsum[256];
  for (int i = threadIdx.x; i < HALF; i += 256) used[i] = 0;
  for (int i = threadIdx.x; i < NN; i += 256) {
    removed[i] = 0;
    partner[b * NN + i] = -1;
  }
  __syncthreads();
  if (threadIdx.x == 0) {
    int cnt = 0;
    for (int step = 0; step < HALF; ++step) {
      int a = order[b * HALF + step];
      int bb = best_b[b * HALF + a];
      if (!used[bb] && cnt < RR) {
        used[bb] = 1;
        sel_a[cnt] = a;
        sel_b[cnt] = bb;
        ++cnt;
      }
    }
    for (int s = cnt; s < RR; ++s) { sel_a[s] = sel_a[0]; sel_b[s] = sel_b[0]; }
  }
  __syncthreads();
  {
    int s = threadIdx.x;
    int ga = 2 * sel_a[s], gb = 2 * sel_b[s] + 1;
    removed[gb] = 1;
    partner[b * NN + ga] = gb;
    sel_a[s] = ga;
    sel_b[s] = gb;
  }
  __syncthreads();
  int myc = 0;
#pragma unroll
  for (int q = 0; q < 8; ++q) myc += !removed[8 * threadIdx.x + q];
  tsum[threadIdx.x] = myc;
  __syncthreads();
  for (int off = 1; off < 256; off <<= 1) {
    int v = (threadIdx.x >= (unsigned)off) ? tsum[threadIdx.x - off] : 0;
    __syncthreads();
    tsum[threadIdx.x] += v;
    __syncthreads();
  }
  int pos = tsum[threadIdx.x] - myc;
#pragma unroll
  for (int q = 0; q < 8; ++q) {
    int p = 8 * threadIdx.x + q;
    int sr = -1;
    if (!removed[p]) {
      if (pos < NM) {
        keep_idx[b * NM + pos] = p;
        sr = pos;
      }
      ++pos;
    }
    src_row[b * NN + p] = sr;
  }
  __syncthreads();
  {
    int s = threadIdx.x;
    src_row[b * NN + sel_b[s]] = src_row[b * NN + sel_a[s]];
  }
}

// ---------------------------------------------------------------------------
// Merge
// ---------------------------------------------------------------------------
__global__ __launch_bounds__(256) void merge_kernel(
    const float* __restrict__ x, const int* __restrict__ keep_idx,
    const int* __restrict__ partner, float* __restrict__ x_m) {
  const int mrow = blockIdx.x;
  const int b = mrow / NM;
  const int t = mrow % NM;
  const int p = keep_idx[b * NM + t];
  const int pp = partner[b * NN + p];
  const float4* src =
      reinterpret_cast<const float4*>(x + ((size_t)b * NN + p) * DM);
  float4 val = src[threadIdx.x];
  if (pp >= 0) {
    const float4* s2 =
        reinterpret_cast<const float4*>(x + ((size_t)b * NN + pp) * DM);
    float4 v2 = s2[threadIdx.x];
    val.x = 0.5f * (val.x + v2.x);
    val.y = 0.5f * (val.y + v2.y);
    val.z = 0.5f * (val.z + v2.z);
    val.w = 0.5f * (val.w + v2.w);
  }
  reinterpret_cast<float4*>(x_m + (size_t)mrow * DM)[threadIdx.x] = val;
}

// ---------------------------------------------------------------------------
// RoPE in place
// ---------------------------------------------------------------------------
__global__ __launch_bounds__(256) void rope_kernel(float* __restrict__ t,
                                                   const float* __restrict__ fc,
                                                   int heads) {
  const int row = blockIdx.x;
  const int tpos = row % NM;
  const int npairs = heads * 32;
  for (int idx = threadIdx.x; idx < npairs; idx += 256) {
    int h = idx >> 5, u = idx & 31;
    float c = fc[(tpos * 32 + u) * 2];
    float s = fc[(tpos * 32 + u) * 2 + 1];
    float* base = t + (size_t)row * heads * 64 + h * 64 + 2 * u;
    float x1 = base[0], x2 = base[1];
    base[0] = x1 * c - x2 * s;
    base[1] = x1 * s + x2 * c;
  }
}

// ---------------------------------------------------------------------------
// Attention v2: ONE WAVE per (b, h, 64-query tile). lane = query.
// K/V addresses are wave-uniform -> scalar loads; per-lane private softmax
// state (no shuffles, no LDS). q vector and output accumulator in registers.
// ---------------------------------------------------------------------------
__global__ __launch_bounds__(64) void attn_kernel(
    const float* __restrict__ q, const float* __restrict__ k,
    const float* __restrict__ v, float* __restrict__ o) {
  const int lane = threadIdx.x;
  const int qt = blockIdx.x % (NM / 64);
  const int rest = blockIdx.x / (NM / 64);
  const int h = rest % NH;
  const int b = rest / NH;
  const int kvh = h >> 2;
  const int qi = qt * 64 + lane;

  float qv[64];
  {
    const float4* qrow = reinterpret_cast<const float4*>(
        q + ((size_t)(b * NM + qi)) * DM + h * 64);
#pragma unroll
    for (int d4 = 0; d4 < 16; ++d4) {
      float4 t = qrow[d4];
      qv[4 * d4 + 0] = t.x * 0.125f;
      qv[4 * d4 + 1] = t.y * 0.125f;
      qv[4 * d4 + 2] = t.z * 0.125f;
      qv[4 * d4 + 3] = t.w * 0.125f;
    }
  }
  float acc[64];
#pragma unroll
  for (int d = 0; d < 64; ++d) acc[d] = 0.f;
  float m = -1e30f, l = 0.f;
  const float* kb = k + (size_t)b * NM * (NKV * HD) + kvh * HD;
  const float* vb = v + (size_t)b * NM * (NKV * HD) + kvh * HD;

  for (int jt = 0; jt < NM; jt += 16) {
    float s[16];
#pragma unroll
    for (int j = 0; j < 16; ++j) {
      const float4* krow =
          reinterpret_cast<const float4*>(kb + (size_t)(jt + j) * (NKV * HD));
      float s0 = 0.f, s1 = 0.f, s2 = 0.f, s3 = 0.f;
#pragma unroll
      for (int d4 = 0; d4 < 16; ++d4) {
        float4 kk = krow[d4];
        s0 += qv[4 * d4 + 0] * kk.x;
        s1 += qv[4 * d4 + 1] * kk.y;
        s2 += qv[4 * d4 + 2] * kk.z;
        s3 += qv[4 * d4 + 3] * kk.w;
      }
      s[j] = (s0 + s1) + (s2 + s3);
    }
    // per-lane online softmax (lane owns its query's state)
    float bm = s[0];
#pragma unroll
    for (int j = 1; j < 16; ++j) bm = fmaxf(bm, s[j]);
    float mn = fmaxf(m, bm);
    float alpha = __expf(m - mn);
    float ps = 0.f;
#pragma unroll
    for (int j = 0; j < 16; ++j) {
      s[j] = __expf(s[j] - mn);
      ps += s[j];
    }
    l = l * alpha + ps;
    m = mn;
#pragma unroll
    for (int d = 0; d < 64; ++d) acc[d] *= alpha;
#pragma unroll
    for (int j = 0; j < 16; ++j) {
      const float4* vrow =
          reinterpret_cast<const float4*>(vb + (size_t)(jt + j) * (NKV * HD));
      float pj = s[j];
#pragma unroll
      for (int d4 = 0; d4 < 16; ++d4) {
        float4 vv = vrow[d4];
        acc[4 * d4 + 0] += pj * vv.x;
        acc[4 * d4 + 1] += pj * vv.y;
        acc[4 * d4 + 2] += pj * vv.z;
        acc[4 * d4 + 3] += pj * vv.w;
      }
    }
  }
  float invl = 1.f / l;
  float4* orow =
      reinterpret_cast<float4*>(o + ((size_t)(b * NM + qi)) * DM + h * 64);
#pragma unroll
  for (int d4 = 0; d4 < 16; ++d4) {
    float4 t;
    t.x = acc[4 * d4 + 0] * invl;
    t.y = acc[4 * d4 + 1] * invl;
    t.z = acc[4 * d4 + 2] * invl;
    t.w = acc[4 * d4 + 3] * invl;
    orow[d4] = t;
  }
}

// ---------------------------------------------------------------------------
// Unmerge scatter
// ---------------------------------------------------------------------------
__global__ __launch_bounds__(256) void scatter_out(
    const float* __restrict__ out_m, const int* __restrict__ src_row,
    float* __restrict__ out) {
  const int row = blockIdx.x;
  const int b = row >> 11;
  const int p = row & (NN - 1);
  const int sr = src_row[b * NN + p];
  float4 val = make_float4(0.f, 0.f, 0.f, 0.f);
  if (sr >= 0)
    val = reinterpret_cast<const float4*>(out_m +
                                          ((size_t)(b * NM + sr)) * DM)[threadIdx.x];
  reinterpret_cast<float4*>(out + (size_t)row * DM)[threadIdx.x] = val;
}

// ---------------------------------------------------------------------------
extern "C" void kernel_launch(void* const* d_in, const int* in_sizes, int n_in,
                              void* d_out, int out_size, void* d_ws,
                              size_t ws_size, hipStream_t stream) {
  const float* x = (const float*)d_in[0];
  const float* fc = (const float*)d_in[1];
  const float* Wq = (const float*)d_in[2];
  const float* Wk = (const float*)d_in[3];
  const float* Wv = (const float*)d_in[4];
  const float* Wo = (const float*)d_in[5];
  float* out = (float*)d_out;

  char* ws = (char*)d_ws;
  size_t off = 0;
  auto alloc = [&](size_t bytes) {
    void* p = ws + off;
    off += (bytes + 255) & ~(size_t)255;
    return p;
  };
  float* metric = (float*)alloc((size_t)BB * NN * 256 * 4);
  float* best_s = (float*)alloc((size_t)BB * HALF * 4);
  int* best_b = (int*)alloc((size_t)BB * HALF * 4);
  int* order = (int*)alloc((size_t)BB * HALF * 4);
  int* keep_idx = (int*)alloc((size_t)BB * NM * 4);
  int* src_row = (int*)alloc((size_t)BB * NN * 4);
  int* partner = (int*)alloc((size_t)BB * NN * 4);
  float* x_m = (float*)alloc((size_t)BB * NM * DM * 4);
  float* qb = (float*)alloc((size_t)BB * NM * DM * 4);
  float* kb = (float*)alloc((size_t)BB * NM * NKV * HD * 4);
  float* vb = (float*)alloc((size_t)BB * NM * NKV * HD * 4);
  float* attn_o = (float*)alloc((size_t)BB * NM * DM * 4);
  float* out_m = x_m;

  gemm_rows<<<dim3((BB * NN) / 16, 1), 256, 0, stream>>>(x, Wk, metric,
                                                         BB * NN, DM, 256);
  normalize_rows<<<BB * NN, 256, 0, stream>>>(metric);
  scores_argmax<<<dim3(HALF / 8, BB), 256, 0, stream>>>(metric, best_s, best_b);
  sort_desc<<<BB, 256, 0, stream>>>(best_s, order);
  select_and_index<<<BB, 256, 0, stream>>>(best_b, order, keep_idx, src_row,
                                           partner);
  merge_kernel<<<BB * NM, 256, 0, stream>>>(x, keep_idx, partner, x_m);
  gemm_rows<<<dim3((BB * NM) / 16, 4), 256, 0, stream>>>(x_m, Wq, qb, BB * NM,
                                                         DM, DM);
  gemm_rows<<<dim3((BB * NM) / 16, 1), 256, 0, stream>>>(x_m, Wk, kb, BB * NM,
                                                         DM, NKV * HD);
  gemm_rows<<<dim3((BB * NM) / 16, 1), 256, 0, stream>>>(x_m, Wv, vb, BB * NM,
                                                         DM, NKV * HD);
  rope_kernel<<<BB * NM, 256, 0, stream>>>(qb, fc, NH);
  rope_kernel<<<BB * NM, 256, 0, stream>>>(kb, fc, NKV);
  attn_kernel<<<(NM / 64) * NH * BB, 64, 0, stream>>>(qb, kb, vb, attn_o);
  gemm_rows<<<dim3((BB * NM) / 16, 4), 256, 0, stream>>>(attn_o, Wo, out_m,
                                                         BB * NM, DM, DM);
  scatter_out<<<BB * NN, 256, 0, stream>>>(out_m, src_row, out);
}

// Round 3
// 2015.636 us; speedup vs baseline: 3.2580x; 1.9215x over previous
//
#include <hip/hip_runtime.h>
#include <hip/hip_bf16.h>
#include <math.h>

// Problem constants
#define BB 2
#define NN 2048
#define DM 1024
#define NH 16
#define NKV 4
#define HD 64
#define RR 256
#define HALF 1024
#define NM 1792   // NN - RR
#define NSPLIT 4
#define KPS (NM / NSPLIT)  // 448 keys per split
#define QT32 (NM / 32)     // 56 query tiles of 32

// ---------------------------------------------------------------------------
// Generic row-tiled fp32 GEMM: C[M x Nc] = A[M x K] @ W[K x Nc]
// ---------------------------------------------------------------------------
__global__ __launch_bounds__(256) void gemm_rows(
    const float* __restrict__ A, const float* __restrict__ W,
    float* __restrict__ C, int M, int K, int Nc) {
  __shared__ float As[16][256];
  const int row0 = blockIdx.x * 16;
  const int col = blockIdx.y * 256 + threadIdx.x;
  float acc[16];
#pragma unroll
  for (int r = 0; r < 16; ++r) acc[r] = 0.f;
  for (int k0 = 0; k0 < K; k0 += 256) {
    for (int idx = threadIdx.x; idx < 16 * 64; idx += 256) {
      int r = idx >> 6, c4 = idx & 63;
      const float4* src =
          reinterpret_cast<const float4*>(A + (size_t)(row0 + r) * K + k0) + c4;
      reinterpret_cast<float4*>(&As[r][0])[c4] = *src;
    }
    __syncthreads();
    for (int dk = 0; dk < 256; ++dk) {
      float wv = W[(size_t)(k0 + dk) * Nc + col];
#pragma unroll
      for (int r = 0; r < 16; ++r) acc[r] += As[r][dk] * wv;
    }
    __syncthreads();
  }
  for (int r = 0; r < 16; ++r) C[(size_t)(row0 + r) * Nc + col] = acc[r];
}

// ---------------------------------------------------------------------------
// Normalize each 256-float row of metric in place
// ---------------------------------------------------------------------------
__global__ __launch_bounds__(256) void normalize_rows(float* __restrict__ m) {
  const int row = blockIdx.x;
  const int t = threadIdx.x;
  float v = m[(size_t)row * 256 + t];
  float ss = v * v;
#pragma unroll
  for (int o = 32; o > 0; o >>= 1) ss += __shfl_xor(ss, o, 64);
  __shared__ float wsum[4];
  if ((t & 63) == 0) wsum[t >> 6] = ss;
  __syncthreads();
  float tot = wsum[0] + wsum[1] + wsum[2] + wsum[3];
  float inv = 1.f / fmaxf(sqrtf(tot), 1e-12f);
  m[(size_t)row * 256 + t] = v * inv;
}

// ---------------------------------------------------------------------------
// Fused scores + row-argmax. Ties -> lowest j (np argmax semantics).
// ---------------------------------------------------------------------------
__global__ __launch_bounds__(256) void scores_argmax(
    const float* __restrict__ metric, float* __restrict__ best_s,
    int* __restrict__ best_b) {
  const int b = blockIdx.y;
  const int i0 = blockIdx.x * 8;
  __shared__ float As[8][256];
  const float* mb = metric + (size_t)b * NN * 256;
  for (int idx = threadIdx.x; idx < 8 * 256; idx += 256) {
    int r = idx >> 8, c = idx & 255;
    As[r][c] = mb[(size_t)(2 * (i0 + r)) * 256 + c];
  }
  __syncthreads();
  float bv[8];
  int bj[8];
#pragma unroll
  for (int r = 0; r < 8; ++r) { bv[r] = -2.f; bj[r] = 0; }
  for (int jj = 0; jj < 4; ++jj) {
    int j = threadIdx.x + jj * 256;
    const float* brow = mb + (size_t)(2 * j + 1) * 256;
    float acc[8];
#pragma unroll
    for (int r = 0; r < 8; ++r) acc[r] = 0.f;
    for (int c = 0; c < 256; ++c) {
      float bvv = brow[c];
#pragma unroll
      for (int r = 0; r < 8; ++r) acc[r] += As[r][c] * bvv;
    }
#pragma unroll
    for (int r = 0; r < 8; ++r)
      if (acc[r] > bv[r]) { bv[r] = acc[r]; bj[r] = j; }
  }
  __shared__ float rv[256];
  __shared__ int ri[256];
  for (int r = 0; r < 8; ++r) {
    rv[threadIdx.x] = bv[r];
    ri[threadIdx.x] = bj[r];
    __syncthreads();
    for (int s = 128; s > 0; s >>= 1) {
      if (threadIdx.x < (unsigned)s) {
        float v2 = rv[threadIdx.x + s];
        int i2 = ri[threadIdx.x + s];
        float v1 = rv[threadIdx.x];
        int i1 = ri[threadIdx.x];
        if (v2 > v1 || (v2 == v1 && i2 < i1)) {
          rv[threadIdx.x] = v2;
          ri[threadIdx.x] = i2;
        }
      }
      __syncthreads();
    }
    if (threadIdx.x == 0) {
      best_s[b * HALF + i0 + r] = rv[0];
      best_b[b * HALF + i0 + r] = ri[0];
    }
    __syncthreads();
  }
}

// ---------------------------------------------------------------------------
// Stable descending bitonic argsort of 1024 scores per batch.
// ---------------------------------------------------------------------------
__global__ __launch_bounds__(256) void sort_desc(const float* __restrict__ best_s,
                                                 int* __restrict__ order) {
  const int b = blockIdx.x;
  __shared__ float sv[1024];
  __shared__ int si[1024];
  for (int i = threadIdx.x; i < 1024; i += 256) {
    sv[i] = best_s[b * HALF + i];
    si[i] = i;
  }
  __syncthreads();
  for (int k = 2; k <= 1024; k <<= 1) {
    for (int j = k >> 1; j > 0; j >>= 1) {
      for (int t = threadIdx.x; t < 1024; t += 256) {
        int ixj = t ^ j;
        if (ixj > t) {
          bool dir = ((t & k) == 0);
          float va = sv[t], vb = sv[ixj];
          int ia = si[t], ib = si[ixj];
          bool before = (vb > va) || (vb == va && ib < ia);
          if (before == dir) {
            sv[t] = vb; sv[ixj] = va;
            si[t] = ib; si[ixj] = ia;
          }
        }
      }
      __syncthreads();
    }
  }
  for (int i = threadIdx.x; i < 1024; i += 256) order[b * HALF + i] = si[i];
}

// ---------------------------------------------------------------------------
// Greedy unique-b selection + index maps. One block per batch.
// ---------------------------------------------------------------------------
__global__ __launch_bounds__(256) void select_and_index(
    const int* __restrict__ best_b, const int* __restrict__ order,
    int* __restrict__ keep_idx, int* __restrict__ src_row,
    int* __restrict__ partner) {
  const int b = blockIdx.x;
  __shared__ int used[HALF];
  __shared__ int sel_a[RR], sel_b[RR];
  __shared__ int removed[NN];
  __shared__ int tsum[256];
  for (int i = threadIdx.x; i < HALF; i += 256) used[i] = 0;
  for (int i = threadIdx.x; i < NN; i += 256) {
    removed[i] = 0;
    partner[b * NN + i] = -1;
  }
  __syncthreads();
  if (threadIdx.x == 0) {
    int cnt = 0;
    for (int step = 0; step < HALF; ++step) {
      int a = order[b * HALF + step];
      int bb = best_b[b * HALF + a];
      if (!used[bb] && cnt < RR) {
        used[bb] = 1;
        sel_a[cnt] = a;
        sel_b[cnt] = bb;
        ++cnt;
      }
    }
    for (int s = cnt; s < RR; ++s) { sel_a[s] = sel_a[0]; sel_b[s] = sel_b[0]; }
  }
  __syncthreads();
  {
    int s = threadIdx.x;
    int ga = 2 * sel_a[s], gb = 2 * sel_b[s] + 1;
    removed[gb] = 1;
    partner[b * NN + ga] = gb;
    sel_a[s] = ga;
    sel_b[s] = gb;
  }
  __syncthreads();
  int myc = 0;
#pragma unroll
  for (int q = 0; q < 8; ++q) myc += !removed[8 * threadIdx.x + q];
  tsum[threadIdx.x] = myc;
  __syncthreads();
  for (int off = 1; off < 256; off <<= 1) {
    int v = (threadIdx.x >= (unsigned)off) ? tsum[threadIdx.x - off] : 0;
    __syncthreads();
    tsum[threadIdx.x] += v;
    __syncthreads();
  }
  int pos = tsum[threadIdx.x] - myc;
#pragma unroll
  for (int q = 0; q < 8; ++q) {
    int p = 8 * threadIdx.x + q;
    int sr = -1;
    if (!removed[p]) {
      if (pos < NM) {
        keep_idx[b * NM + pos] = p;
        sr = pos;
      }
      ++pos;
    }
    src_row[b * NN + p] = sr;
  }
  __syncthreads();
  {
    int s = threadIdx.x;
    src_row[b * NN + sel_b[s]] = src_row[b * NN + sel_a[s]];
  }
}

// ---------------------------------------------------------------------------
// Merge
// ---------------------------------------------------------------------------
__global__ __launch_bounds__(256) void merge_kernel(
    const float* __restrict__ x, const int* __restrict__ keep_idx,
    const int* __restrict__ partner, float* __restrict__ x_m) {
  const int mrow = blockIdx.x;
  const int b = mrow / NM;
  const int t = mrow % NM;
  const int p = keep_idx[b * NM + t];
  const int pp = partner[b * NN + p];
  const float4* src =
      reinterpret_cast<const float4*>(x + ((size_t)b * NN + p) * DM);
  float4 val = src[threadIdx.x];
  if (pp >= 0) {
    const float4* s2 =
        reinterpret_cast<const float4*>(x + ((size_t)b * NN + pp) * DM);
    float4 v2 = s2[threadIdx.x];
    val.x = 0.5f * (val.x + v2.x);
    val.y = 0.5f * (val.y + v2.y);
    val.z = 0.5f * (val.z + v2.z);
    val.w = 0.5f * (val.w + v2.w);
  }
  reinterpret_cast<float4*>(x_m + (size_t)mrow * DM)[threadIdx.x] = val;
}

// ---------------------------------------------------------------------------
// RoPE in place
// ---------------------------------------------------------------------------
__global__ __launch_bounds__(256) void rope_kernel(float* __restrict__ t,
                                                   const float* __restrict__ fc,
                                                   int heads) {
  const int row = blockIdx.x;
  const int tpos = row % NM;
  const int npairs = heads * 32;
  for (int idx = threadIdx.x; idx < npairs; idx += 256) {
    int h = idx >> 5, u = idx & 31;
    float c = fc[(tpos * 32 + u) * 2];
    float s = fc[(tpos * 32 + u) * 2 + 1];
    float* base = t + (size_t)row * heads * 64 + h * 64 + 2 * u;
    float x1 = base[0], x2 = base[1];
    base[0] = x1 * c - x2 * s;
    base[1] = x1 * s + x2 * c;
  }
}

// ---------------------------------------------------------------------------
// Attention v3: block = (b, kvh, split, qtile32); 4 waves = 4 GQA heads
// sharing K/V tiles staged in LDS. Within a wave: 32 queries, 2 lanes per
// query (lane&31 = query, lane>>5 = dim-half of 32). Split-K over NSPLIT
// chunks; partials (m, l fp32; acc bf16) to workspace; combined later.
// ---------------------------------------------------------------------------
__global__ __launch_bounds__(256) void attn_kernel(
    const float* __restrict__ q, const float* __restrict__ k,
    const float* __restrict__ v, float* __restrict__ pm,
    float* __restrict__ pl, __hip_bfloat16* __restrict__ pacc) {
  __shared__ float Ks[64][64];
  __shared__ float Vs[64][64];
  int bid = blockIdx.x;
  const int qt = bid % QT32; bid /= QT32;
  const int split = bid % NSPLIT; bid /= NSPLIT;
  const int kvh = bid % NKV;
  const int b = bid / NKV;
  const int wv = threadIdx.x >> 6;
  const int lane = threadIdx.x & 63;
  const int h = kvh * 4 + wv;
  const int qlocal = lane & 31;
  const int qhalf = lane >> 5;
  const int qi = qt * 32 + qlocal;

  // load my 32 dims of q, pre-scaled
  float qv[32];
  {
    const float4* qrow = reinterpret_cast<const float4*>(
        q + ((size_t)(b * NM + qi)) * DM + h * 64 + qhalf * 32);
#pragma unroll
    for (int d4 = 0; d4 < 8; ++d4) {
      float4 t = qrow[d4];
      qv[4 * d4 + 0] = t.x * 0.125f;
      qv[4 * d4 + 1] = t.y * 0.125f;
      qv[4 * d4 + 2] = t.z * 0.125f;
      qv[4 * d4 + 3] = t.w * 0.125f;
    }
  }
  float acc[32];
#pragma unroll
  for (int d = 0; d < 32; ++d) acc[d] = 0.f;
  float m = -1e30f, l = 0.f;

  const float* kb = k + (size_t)b * NM * (NKV * HD) + kvh * HD;
  const float* vb = v + (size_t)b * NM * (NKV * HD) + kvh * HD;

  for (int t = 0; t < KPS / 64; ++t) {
    const int j0 = split * KPS + t * 64;
    // cooperative staging: 64 keys x 64 dims for K and V (1024 float4 each)
    __syncthreads();
    for (int idx = threadIdx.x; idx < 1024; idx += 256) {
      int row = idx >> 4, c4 = idx & 15;
      reinterpret_cast<float4*>(&Ks[row][0])[c4] =
          reinterpret_cast<const float4*>(kb + (size_t)(j0 + row) * (NKV * HD))[c4];
      reinterpret_cast<float4*>(&Vs[row][0])[c4] =
          reinterpret_cast<const float4*>(vb + (size_t)(j0 + row) * (NKV * HD))[c4];
    }
    __syncthreads();
#pragma unroll
    for (int sub = 0; sub < 4; ++sub) {
      float s[16];
#pragma unroll
      for (int j16 = 0; j16 < 16; ++j16) {
        const int j = sub * 16 + j16;
        const float4* kr = reinterpret_cast<const float4*>(&Ks[j][qhalf * 32]);
        float s0 = 0.f, s1 = 0.f, s2 = 0.f, s3 = 0.f;
#pragma unroll
        for (int d4 = 0; d4 < 8; ++d4) {
          float4 kk = kr[d4];
          s0 += qv[4 * d4 + 0] * kk.x;
          s1 += qv[4 * d4 + 1] * kk.y;
          s2 += qv[4 * d4 + 2] * kk.z;
          s3 += qv[4 * d4 + 3] * kk.w;
        }
        float sj = (s0 + s1) + (s2 + s3);
        sj += __shfl_xor(sj, 32, 64);  // combine the two dim-halves
        s[j16] = sj;
      }
      // per-query online softmax (both halves hold identical s -> identical state)
      float bm = s[0];
#pragma unroll
      for (int j16 = 1; j16 < 16; ++j16) bm = fmaxf(bm, s[j16]);
      float mn = fmaxf(m, bm);
      float alpha = __expf(m - mn);
      float ps = 0.f;
#pragma unroll
      for (int j16 = 0; j16 < 16; ++j16) {
        s[j16] = __expf(s[j16] - mn);
        ps += s[j16];
      }
      l = l * alpha + ps;
      m = mn;
#pragma unroll
      for (int d = 0; d < 32; ++d) acc[d] *= alpha;
#pragma unroll
      for (int j16 = 0; j16 < 16; ++j16) {
        const int j = sub * 16 + j16;
        const float4* vr = reinterpret_cast<const float4*>(&Vs[j][qhalf * 32]);
        float pj = s[j16];
#pragma unroll
        for (int d4 = 0; d4 < 8; ++d4) {
          float4 vvv = vr[d4];
          acc[4 * d4 + 0] += pj * vvv.x;
          acc[4 * d4 + 1] += pj * vvv.y;
          acc[4 * d4 + 2] += pj * vvv.z;
          acc[4 * d4 + 3] += pj * vvv.w;
        }
      }
    }
  }
  // write partials
  const size_t row = (size_t)(b * NH + h) * NM + qi;
  if (qhalf == 0) {
    pm[row * NSPLIT + split] = m;
    pl[row * NSPLIT + split] = l;
  }
  __hip_bfloat16* pa = pacc + (row * NSPLIT + split) * 64 + qhalf * 32;
#pragma unroll
  for (int d = 0; d < 32; ++d) pa[d] = __float2bfloat16(acc[d]);
}

// ---------------------------------------------------------------------------
// Split-K combine: out[row, d] = sum_s e^{m_s-M} acc_s[d] / sum_s e^{m_s-M} l_s
// 4 rows per block, lane = dim.
// ---------------------------------------------------------------------------
__global__ __launch_bounds__(256) void attn_combine(
    const float* __restrict__ pm, const float* __restrict__ pl,
    const __hip_bfloat16* __restrict__ pacc, float* __restrict__ o) {
  const size_t row = (size_t)blockIdx.x * 4 + (threadIdx.x >> 6);
  const int d = threadIdx.x & 63;
  float ms[NSPLIT];
  float M = -1e30f;
#pragma unroll
  for (int s = 0; s < NSPLIT; ++s) {
    ms[s] = pm[row * NSPLIT + s];
    M = fmaxf(M, ms[s]);
  }
  float num = 0.f, den = 0.f;
#pragma unroll
  for (int s = 0; s < NSPLIT; ++s) {
    float w = __expf(ms[s] - M);
    num += w * __bfloat162float(pacc[(row * NSPLIT + s) * 64 + d]);
    den += w * pl[row * NSPLIT + s];
  }
  const int qi = (int)(row % NM);
  const int h = (int)((row / NM) % NH);
  const int b = (int)(row / ((size_t)NM * NH));
  o[((size_t)(b * NM + qi)) * DM + h * 64 + d] = num / den;
}

// ---------------------------------------------------------------------------
// Unmerge scatter
// ---------------------------------------------------------------------------
__global__ __launch_bounds__(256) void scatter_out(
    const float* __restrict__ out_m, const int* __restrict__ src_row,
    float* __restrict__ out) {
  const int row = blockIdx.x;
  const int b = row >> 11;
  const int p = row & (NN - 1);
  const int sr = src_row[b * NN + p];
  float4 val = make_float4(0.f, 0.f, 0.f, 0.f);
  if (sr >= 0)
    val = reinterpret_cast<const float4*>(out_m +
                                          ((size_t)(b * NM + sr)) * DM)[threadIdx.x];
  reinterpret_cast<float4*>(out + (size_t)row * DM)[threadIdx.x] = val;
}

// ---------------------------------------------------------------------------
extern "C" void kernel_launch(void* const* d_in, const int* in_sizes, int n_in,
                              void* d_out, int out_size, void* d_ws,
                              size_t ws_size, hipStream_t stream) {
  const float* x = (const float*)d_in[0];
  const float* fc = (const float*)d_in[1];
  const float* Wq = (const float*)d_in[2];
  const float* Wk = (const float*)d_in[3];
  const float* Wv = (const float*)d_in[4];
  const float* Wo = (const float*)d_in[5];
  float* out = (float*)d_out;

  char* ws = (char*)d_ws;
  size_t off = 0;
  auto alloc = [&](size_t bytes) {
    void* p = ws + off;
    off += (bytes + 255) & ~(size_t)255;
    return p;
  };
  float* metric = (float*)alloc((size_t)BB * NN * 256 * 4);
  float* best_s = (float*)alloc((size_t)BB * HALF * 4);
  int* best_b = (int*)alloc((size_t)BB * HALF * 4);
  int* order = (int*)alloc((size_t)BB * HALF * 4);
  int* keep_idx = (int*)alloc((size_t)BB * NM * 4);
  int* src_row = (int*)alloc((size_t)BB * NN * 4);
  int* partner = (int*)alloc((size_t)BB * NN * 4);
  float* x_m = (float*)alloc((size_t)BB * NM * DM * 4);
  float* qb = (float*)alloc((size_t)BB * NM * DM * 4);
  float* kb = (float*)alloc((size_t)BB * NM * NKV * HD * 4);
  float* vb = (float*)alloc((size_t)BB * NM * NKV * HD * 4);
  float* attn_o = (float*)alloc((size_t)BB * NM * DM * 4);
  float* pm = (float*)alloc((size_t)BB * NH * NM * NSPLIT * 4);
  float* pl = (float*)alloc((size_t)BB * NH * NM * NSPLIT * 4);
  __hip_bfloat16* pacc =
      (__hip_bfloat16*)alloc((size_t)BB * NH * NM * NSPLIT * 64 * 2);
  float* out_m = x_m;

  gemm_rows<<<dim3((BB * NN) / 16, 1), 256, 0, stream>>>(x, Wk, metric,
                                                         BB * NN, DM, 256);
  normalize_rows<<<BB * NN, 256, 0, stream>>>(metric);
  scores_argmax<<<dim3(HALF / 8, BB), 256, 0, stream>>>(metric, best_s, best_b);
  sort_desc<<<BB, 256, 0, stream>>>(best_s, order);
  select_and_index<<<BB, 256, 0, stream>>>(best_b, order, keep_idx, src_row,
                                           partner);
  merge_kernel<<<BB * NM, 256, 0, stream>>>(x, keep_idx, partner, x_m);
  gemm_rows<<<dim3((BB * NM) / 16, 4), 256, 0, stream>>>(x_m, Wq, qb, BB * NM,
                                                         DM, DM);
  gemm_rows<<<dim3((BB * NM) / 16, 1), 256, 0, stream>>>(x_m, Wk, kb, BB * NM,
                                                         DM, NKV * HD);
  gemm_rows<<<dim3((BB * NM) / 16, 1), 256, 0, stream>>>(x_m, Wv, vb, BB * NM,
                                                         DM, NKV * HD);
  rope_kernel<<<BB * NM, 256, 0, stream>>>(qb, fc, NH);
  rope_kernel<<<BB * NM, 256, 0, stream>>>(kb, fc, NKV);
  attn_kernel<<<BB * NKV * NSPLIT * QT32, 256, 0, stream>>>(qb, kb, vb, pm, pl,
                                                            pacc);
  attn_combine<<<(BB * NH * NM) / 4, 256, 0, stream>>>(pm, pl, pacc, attn_o);
  gemm_rows<<<dim3((BB * NM) / 16, 4), 256, 0, stream>>>(attn_o, Wo, out_m,
                                                         BB * NM, DM, DM);
  scatter_out<<<BB * NN, 256, 0, stream>>>(out_m, src_row, out);
}

// Round 4
// 1555.462 us; speedup vs baseline: 4.2218x; 1.2958x over previous
//
#include <hip/hip_runtime.h>
#include <hip/hip_bf16.h>
#include <math.h>

// Problem constants
#define BB 2
#define NN 2048
#define DM 1024
#define NH 16
#define NKV 4
#define HD 64
#define RR 256
#define HALF 1024
#define NM 1792   // NN - RR

typedef __bf16 bf16x8 __attribute__((ext_vector_type(8)));
typedef float f32x4 __attribute__((ext_vector_type(4)));

// ---------------------------------------------------------------------------
// fp32 GEMM, 1 col/thread (used for metric / Wk / Wv, Nc = 256)
// ---------------------------------------------------------------------------
__global__ __launch_bounds__(256) void gemm_rows(
    const float* __restrict__ A, const float* __restrict__ W,
    float* __restrict__ C, int M, int K, int Nc) {
  __shared__ float As[16][256];
  const int row0 = blockIdx.x * 16;
  const int col = blockIdx.y * 256 + threadIdx.x;
  float acc[16];
#pragma unroll
  for (int r = 0; r < 16; ++r) acc[r] = 0.f;
  for (int k0 = 0; k0 < K; k0 += 256) {
    for (int idx = threadIdx.x; idx < 16 * 64; idx += 256) {
      int r = idx >> 6, c4 = idx & 63;
      const float4* src =
          reinterpret_cast<const float4*>(A + (size_t)(row0 + r) * K + k0) + c4;
      reinterpret_cast<float4*>(&As[r][0])[c4] = *src;
    }
    __syncthreads();
#pragma unroll 4
    for (int dk = 0; dk < 256; ++dk) {
      float wv = W[(size_t)(k0 + dk) * Nc + col];
#pragma unroll
      for (int r = 0; r < 16; ++r) acc[r] += As[r][dk] * wv;
    }
    __syncthreads();
  }
  for (int r = 0; r < 16; ++r) C[(size_t)(row0 + r) * Nc + col] = acc[r];
}

// ---------------------------------------------------------------------------
// fp32 GEMM, 4 cols/thread via float4 W loads (Nc == 1024: Wq, Wo).
// 0.25 LDS broadcast reads per FMA instead of 1.
// ---------------------------------------------------------------------------
__global__ __launch_bounds__(256) void gemm_rows4(
    const float* __restrict__ A, const float* __restrict__ W,
    float* __restrict__ C, int M, int K) {
  __shared__ float As[16][256];
  const int row0 = blockIdx.x * 16;
  const int col4 = threadIdx.x * 4;
  float4 acc[16];
#pragma unroll
  for (int r = 0; r < 16; ++r) acc[r] = make_float4(0.f, 0.f, 0.f, 0.f);
  for (int k0 = 0; k0 < K; k0 += 256) {
    for (int idx = threadIdx.x; idx < 16 * 64; idx += 256) {
      int r = idx >> 6, c4 = idx & 63;
      const float4* src =
          reinterpret_cast<const float4*>(A + (size_t)(row0 + r) * K + k0) + c4;
      reinterpret_cast<float4*>(&As[r][0])[c4] = *src;
    }
    __syncthreads();
#pragma unroll 4
    for (int dk = 0; dk < 256; ++dk) {
      float4 wv = *reinterpret_cast<const float4*>(
          W + (size_t)(k0 + dk) * 1024 + col4);
#pragma unroll
      for (int r = 0; r < 16; ++r) {
        float a = As[r][dk];
        acc[r].x += a * wv.x;
        acc[r].y += a * wv.y;
        acc[r].z += a * wv.z;
        acc[r].w += a * wv.w;
      }
    }
    __syncthreads();
  }
  for (int r = 0; r < 16; ++r)
    *reinterpret_cast<float4*>(C + (size_t)(row0 + r) * 1024 + col4) = acc[r];
}

// ---------------------------------------------------------------------------
// Normalize each 256-float row of metric in place
// ---------------------------------------------------------------------------
__global__ __launch_bounds__(256) void normalize_rows(float* __restrict__ m) {
  const int row = blockIdx.x;
  const int t = threadIdx.x;
  float v = m[(size_t)row * 256 + t];
  float ss = v * v;
#pragma unroll
  for (int o = 32; o > 0; o >>= 1) ss += __shfl_xor(ss, o, 64);
  __shared__ float wsum[4];
  if ((t & 63) == 0) wsum[t >> 6] = ss;
  __syncthreads();
  float tot = wsum[0] + wsum[1] + wsum[2] + wsum[3];
  float inv = 1.f / fmaxf(sqrtf(tot), 1e-12f);
  m[(size_t)row * 256 + t] = v * inv;
}

// ---------------------------------------------------------------------------
// Fused scores + row-argmax (fp32, exact selection semantics).
// ---------------------------------------------------------------------------
__global__ __launch_bounds__(256) void scores_argmax(
    const float* __restrict__ metric, float* __restrict__ best_s,
    int* __restrict__ best_b) {
  const int b = blockIdx.y;
  const int i0 = blockIdx.x * 8;
  __shared__ float As[8][256];
  const float* mb = metric + (size_t)b * NN * 256;
  for (int idx = threadIdx.x; idx < 8 * 256; idx += 256) {
    int r = idx >> 8, c = idx & 255;
    As[r][c] = mb[(size_t)(2 * (i0 + r)) * 256 + c];
  }
  __syncthreads();
  float bv[8];
  int bj[8];
#pragma unroll
  for (int r = 0; r < 8; ++r) { bv[r] = -2.f; bj[r] = 0; }
  for (int jj = 0; jj < 4; ++jj) {
    int j = threadIdx.x + jj * 256;
    const float* brow = mb + (size_t)(2 * j + 1) * 256;
    float acc[8];
#pragma unroll
    for (int r = 0; r < 8; ++r) acc[r] = 0.f;
    for (int c = 0; c < 256; ++c) {
      float bvv = brow[c];
#pragma unroll
      for (int r = 0; r < 8; ++r) acc[r] += As[r][c] * bvv;
    }
#pragma unroll
    for (int r = 0; r < 8; ++r)
      if (acc[r] > bv[r]) { bv[r] = acc[r]; bj[r] = j; }
  }
  __shared__ float rv[256];
  __shared__ int ri[256];
  for (int r = 0; r < 8; ++r) {
    rv[threadIdx.x] = bv[r];
    ri[threadIdx.x] = bj[r];
    __syncthreads();
    for (int s = 128; s > 0; s >>= 1) {
      if (threadIdx.x < (unsigned)s) {
        float v2 = rv[threadIdx.x + s];
        int i2 = ri[threadIdx.x + s];
        float v1 = rv[threadIdx.x];
        int i1 = ri[threadIdx.x];
        if (v2 > v1 || (v2 == v1 && i2 < i1)) {
          rv[threadIdx.x] = v2;
          ri[threadIdx.x] = i2;
        }
      }
      __syncthreads();
    }
    if (threadIdx.x == 0) {
      best_s[b * HALF + i0 + r] = rv[0];
      best_b[b * HALF + i0 + r] = ri[0];
    }
    __syncthreads();
  }
}

// ---------------------------------------------------------------------------
// Stable descending bitonic argsort of 1024 scores per batch.
// ---------------------------------------------------------------------------
__global__ __launch_bounds__(256) void sort_desc(const float* __restrict__ best_s,
                                                 int* __restrict__ order) {
  const int b = blockIdx.x;
  __shared__ float sv[1024];
  __shared__ int si[1024];
  for (int i = threadIdx.x; i < 1024; i += 256) {
    sv[i] = best_s[b * HALF + i];
    si[i] = i;
  }
  __syncthreads();
  for (int k = 2; k <= 1024; k <<= 1) {
    for (int j = k >> 1; j > 0; j >>= 1) {
      for (int t = threadIdx.x; t < 1024; t += 256) {
        int ixj = t ^ j;
        if (ixj > t) {
          bool dir = ((t & k) == 0);
          float va = sv[t], vb = sv[ixj];
          int ia = si[t], ib = si[ixj];
          bool before = (vb > va) || (vb == va && ib < ia);
          if (before == dir) {
            sv[t] = vb; sv[ixj] = va;
            si[t] = ib; si[ixj] = ia;
          }
        }
      }
      __syncthreads();
    }
  }
  for (int i = threadIdx.x; i < 1024; i += 256) order[b * HALF + i] = si[i];
}

// ---------------------------------------------------------------------------
// Greedy unique-b selection + index maps. One block per batch.
// ---------------------------------------------------------------------------
__global__ __launch_bounds__(256) void select_and_index(
    const int* __restrict__ best_b, const int* __restrict__ order,
    int* __restrict__ keep_idx, int* __restrict__ src_row,
    int* __restrict__ partner) {
  const int b = blockIdx.x;
  __shared__ int used[HALF];
  __shared__ int sel_a[RR], sel_b[RR];
  __shared__ int removed[NN];
  __shared__ int tsum[256];
  for (int i = threadIdx.x; i < HALF; i += 256) used[i] = 0;
  for (int i = threadIdx.x; i < NN; i += 256) {
    removed[i] = 0;
    partner[b * NN + i] = -1;
  }
  __syncthreads();
  if (threadIdx.x == 0) {
    int cnt = 0;
    for (int step = 0; step < HALF; ++step) {
      int a = order[b * HALF + step];
      int bb = best_b[b * HALF + a];
      if (!used[bb] && cnt < RR) {
        used[bb] = 1;
        sel_a[cnt] = a;
        sel_b[cnt] = bb;
        ++cnt;
      }
    }
    for (int s = cnt; s < RR; ++s) { sel_a[s] = sel_a[0]; sel_b[s] = sel_b[0]; }
  }
  __syncthreads();
  {
    int s = threadIdx.x;
    int ga = 2 * sel_a[s], gb = 2 * sel_b[s] + 1;
    removed[gb] = 1;
    partner[b * NN + ga] = gb;
    sel_a[s] = ga;
    sel_b[s] = gb;
  }
  __syncthreads();
  int myc = 0;
#pragma unroll
  for (int q = 0; q < 8; ++q) myc += !removed[8 * threadIdx.x + q];
  tsum[threadIdx.x] = myc;
  __syncthreads();
  for (int off = 1; off < 256; off <<= 1) {
    int v = (threadIdx.x >= (unsigned)off) ? tsum[threadIdx.x - off] : 0;
    __syncthreads();
    tsum[threadIdx.x] += v;
    __syncthreads();
  }
  int pos = tsum[threadIdx.x] - myc;
#pragma unroll
  for (int q = 0; q < 8; ++q) {
    int p = 8 * threadIdx.x + q;
    int sr = -1;
    if (!removed[p]) {
      if (pos < NM) {
        keep_idx[b * NM + pos] = p;
        sr = pos;
      }
      ++pos;
    }
    src_row[b * NN + p] = sr;
  }
  __syncthreads();
  {
    int s = threadIdx.x;
    src_row[b * NN + sel_b[s]] = src_row[b * NN + sel_a[s]];
  }
}

// ---------------------------------------------------------------------------
// Merge
// ---------------------------------------------------------------------------
__global__ __launch_bounds__(256) void merge_kernel(
    const float* __restrict__ x, const int* __restrict__ keep_idx,
    const int* __restrict__ partner, float* __restrict__ x_m) {
  const int mrow = blockIdx.x;
  const int b = mrow / NM;
  const int t = mrow % NM;
  const int p = keep_idx[b * NM + t];
  const int pp = partner[b * NN + p];
  const float4* src =
      reinterpret_cast<const float4*>(x + ((size_t)b * NN + p) * DM);
  float4 val = src[threadIdx.x];
  if (pp >= 0) {
    const float4* s2 =
        reinterpret_cast<const float4*>(x + ((size_t)b * NN + pp) * DM);
    float4 v2 = s2[threadIdx.x];
    val.x = 0.5f * (val.x + v2.x);
    val.y = 0.5f * (val.y + v2.y);
    val.z = 0.5f * (val.z + v2.z);
    val.w = 0.5f * (val.w + v2.w);
  }
  reinterpret_cast<float4*>(x_m + (size_t)mrow * DM)[threadIdx.x] = val;
}

// ---------------------------------------------------------------------------
// RoPE + head-major repack + bf16 convert.
// src fp32 [b, n, heads, 64]  ->  dst bf16 [b, heads, n, 64], scaled.
// ---------------------------------------------------------------------------
__global__ void rope_repack(const float* __restrict__ src,
                            const float* __restrict__ fc,
                            __bf16* __restrict__ dst, int heads, float scale) {
  const int row = blockIdx.x;
  const int t = row % NM;
  const int b = row / NM;
  const int npairs = heads * 32;
  for (int idx = threadIdx.x; idx < npairs; idx += blockDim.x) {
    int h = idx >> 5, u = idx & 31;
    float c = fc[(t * 32 + u) * 2];
    float s = fc[(t * 32 + u) * 2 + 1];
    const float* p = src + (size_t)row * heads * 64 + h * 64 + 2 * u;
    float x1 = p[0], x2 = p[1];
    __bf16* d = dst + ((size_t)(b * heads + h) * NM + t) * 64 + 2 * u;
    d[0] = (__bf16)((x1 * c - x2 * s) * scale);
    d[1] = (__bf16)((x1 * s + x2 * c) * scale);
  }
}

// ---------------------------------------------------------------------------
// V repack: fp32 [b, n, kvh, 64] -> bf16 transposed [b, kvh, 64 (dim), NM (key)]
// via LDS transpose, one block per (b, kvh, 64-key tile).
// ---------------------------------------------------------------------------
__global__ __launch_bounds__(256) void v_repack(const float* __restrict__ vb,
                                                __bf16* __restrict__ vtb) {
  __shared__ float ld[64][65];
  int bid = blockIdx.x;
  const int kt = bid % (NM / 64); bid /= (NM / 64);
  const int kvh = bid % NKV;
  const int b = bid / NKV;
  const int j0 = kt * 64;
  for (int t2 = threadIdx.x; t2 < 1024; t2 += 256) {
    int key = t2 >> 4, c4 = t2 & 15;
    float4 v4 = *reinterpret_cast<const float4*>(
        vb + (((size_t)(b * NM + j0 + key)) * NKV + kvh) * 64 + c4 * 4);
    ld[key][c4 * 4 + 0] = v4.x;
    ld[key][c4 * 4 + 1] = v4.y;
    ld[key][c4 * 4 + 2] = v4.z;
    ld[key][c4 * 4 + 3] = v4.w;
  }
  __syncthreads();
  const int dim = threadIdx.x >> 2, kc = threadIdx.x & 3;
  __bf16* out = vtb + ((size_t)(b * NKV + kvh) * 64 + dim) * NM + j0 + kc * 16;
#pragma unroll
  for (int kk = 0; kk < 16; ++kk) out[kk] = (__bf16)ld[kc * 16 + kk][dim];
}

// ---------------------------------------------------------------------------
// Flash attention, bf16 MFMA (16x16x32). Block = (b, kvh, 16-query tile);
// wave w handles head kvh*4+w. K/V 64-key tiles staged in LDS (shared by the
// 4 GQA heads); P transits per-wave LDS (no barrier). fp32 softmax state.
// Layouts (m89/m120-verified): A[m=lane&15][k=(lane>>4)*8+j],
// B[k=(lane>>4)*8+j][n=lane&15], D col=lane&15, row=(lane>>4)*4+reg.
// ---------------------------------------------------------------------------
#define KT 64
#define LDK 72  // padded bf16 stride (144 B) -> 2-way bank alias only (free)
#define LDP 72

__global__ __launch_bounds__(256) void attn_mfma(
    const __bf16* __restrict__ qbh,  // [b, h, n, 64], pre-scaled by 0.125
    const __bf16* __restrict__ kbh,  // [b, kvh, n, 64]
    const __bf16* __restrict__ vtb,  // [b, kvh, 64, NM]
    float* __restrict__ attn_o) {    // [b, n, h*64+d]
  __shared__ __align__(16) __bf16 Ks[KT * LDK];
  __shared__ __align__(16) __bf16 Vt[64 * LDK];
  __shared__ __align__(16) __bf16 Pt[4 * 16 * LDP];
  int bid = blockIdx.x;
  const int qt = bid % (NM / 16); bid /= (NM / 16);
  const int kvh = bid % NKV;
  const int b = bid / NKV;
  const int w = threadIdx.x >> 6;
  const int lane = threadIdx.x & 63;
  const int h = kvh * 4 + w;
  const int g = lane >> 4;
  const int ml = lane & 15;
  __bf16* Pw = Pt + w * 16 * LDP;

  // Q fragments (held in registers for the whole kernel)
  const __bf16* qrow =
      qbh + ((size_t)(b * NH + h) * NM + qt * 16 + ml) * 64;
  bf16x8 qa0 = *reinterpret_cast<const bf16x8*>(qrow + g * 8);
  bf16x8 qa1 = *reinterpret_cast<const bf16x8*>(qrow + 32 + g * 8);

  f32x4 acc[4];
#pragma unroll
  for (int mt = 0; mt < 4; ++mt) acc[mt] = (f32x4){0.f, 0.f, 0.f, 0.f};
  float mstate[4], lstate[4];
#pragma unroll
  for (int r = 0; r < 4; ++r) { mstate[r] = -1e30f; lstate[r] = 0.f; }

  const __bf16* ksrc0 = kbh + (size_t)(b * NKV + kvh) * NM * 64;
  const __bf16* vsrc0 = vtb + (size_t)(b * NKV + kvh) * 64 * NM;

  for (int jt = 0; jt < NM / KT; ++jt) {
    __syncthreads();
    // stage K tile [key][dim] and Vt tile [dim][key] (bf16, 16B chunks)
    {
      const __bf16* ks = ksrc0 + (size_t)jt * KT * 64;
      for (int t2 = threadIdx.x; t2 < 512; t2 += 256) {
        int row = t2 >> 3, c8 = t2 & 7;
        *reinterpret_cast<float4*>(&Ks[row * LDK + c8 * 8]) =
            *reinterpret_cast<const float4*>(ks + row * 64 + c8 * 8);
      }
      const __bf16* vs = vsrc0 + jt * KT;
      for (int t2 = threadIdx.x; t2 < 512; t2 += 256) {
        int dim = t2 >> 3, k8 = t2 & 7;
        *reinterpret_cast<float4*>(&Vt[dim * LDK + k8 * 8]) =
            *reinterpret_cast<const float4*>(vs + (size_t)dim * NM + k8 * 8);
      }
    }
    __syncthreads();
    // ---- S = Q K^T  (16 queries x 64 keys)
    f32x4 S[4];
#pragma unroll
    for (int nt = 0; nt < 4; ++nt) {
      bf16x8 kb0 =
          *reinterpret_cast<const bf16x8*>(&Ks[(nt * 16 + ml) * LDK + g * 8]);
      bf16x8 kb1 = *reinterpret_cast<const bf16x8*>(
          &Ks[(nt * 16 + ml) * LDK + 32 + g * 8]);
      f32x4 s = (f32x4){0.f, 0.f, 0.f, 0.f};
      s = __builtin_amdgcn_mfma_f32_16x16x32_bf16(qa0, kb0, s, 0, 0, 0);
      s = __builtin_amdgcn_mfma_f32_16x16x32_bf16(qa1, kb1, s, 0, 0, 0);
      S[nt] = s;
    }
    // ---- online softmax (lane holds queries g*4+r; state replicated x16)
    float mnew[4], alpha[4], rs[4];
#pragma unroll
    for (int r = 0; r < 4; ++r) {
      float mx = fmaxf(fmaxf(S[0][r], S[1][r]), fmaxf(S[2][r], S[3][r]));
      mx = fmaxf(mx, __shfl_xor(mx, 1, 64));
      mx = fmaxf(mx, __shfl_xor(mx, 2, 64));
      mx = fmaxf(mx, __shfl_xor(mx, 4, 64));
      mx = fmaxf(mx, __shfl_xor(mx, 8, 64));
      mnew[r] = fmaxf(mstate[r], mx);
      alpha[r] = __expf(mstate[r] - mnew[r]);
      mstate[r] = mnew[r];
      rs[r] = 0.f;
    }
#pragma unroll
    for (int nt = 0; nt < 4; ++nt) {
#pragma unroll
      for (int r = 0; r < 4; ++r) {
        float p = __expf(S[nt][r] - mnew[r]);
        rs[r] += p;
        Pw[(g * 4 + r) * LDP + nt * 16 + ml] = (__bf16)p;
      }
    }
#pragma unroll
    for (int r = 0; r < 4; ++r) {
      float t = rs[r];
      t += __shfl_xor(t, 1, 64);
      t += __shfl_xor(t, 2, 64);
      t += __shfl_xor(t, 4, 64);
      t += __shfl_xor(t, 8, 64);
      lstate[r] = lstate[r] * alpha[r] + t;
    }
#pragma unroll
    for (int mt = 0; mt < 4; ++mt) {
#pragma unroll
      for (int r = 0; r < 4; ++r) acc[mt][r] *= alpha[r];
    }
    // ---- O += P V   (P read back in A-layout from per-wave LDS)
    bf16x8 pa0 = *reinterpret_cast<const bf16x8*>(&Pw[ml * LDP + g * 8]);
    bf16x8 pa1 = *reinterpret_cast<const bf16x8*>(&Pw[ml * LDP + 32 + g * 8]);
#pragma unroll
    for (int mt = 0; mt < 4; ++mt) {
      bf16x8 vb0 =
          *reinterpret_cast<const bf16x8*>(&Vt[(mt * 16 + ml) * LDK + g * 8]);
      bf16x8 vb1 = *reinterpret_cast<const bf16x8*>(
          &Vt[(mt * 16 + ml) * LDK + 32 + g * 8]);
      acc[mt] = __builtin_amdgcn_mfma_f32_16x16x32_bf16(pa0, vb0, acc[mt], 0, 0, 0);
      acc[mt] = __builtin_amdgcn_mfma_f32_16x16x32_bf16(pa1, vb1, acc[mt], 0, 0, 0);
    }
  }
  // epilogue: lane holds D[q = g*4+r][dim = mt*16+ml]
  float invl[4];
#pragma unroll
  for (int r = 0; r < 4; ++r) invl[r] = 1.f / lstate[r];
#pragma unroll
  for (int mt = 0; mt < 4; ++mt) {
#pragma unroll
    for (int r = 0; r < 4; ++r) {
      int q = qt * 16 + g * 4 + r;
      attn_o[((size_t)(b * NM + q)) * DM + h * 64 + mt * 16 + ml] =
          acc[mt][r] * invl[r];
    }
  }
}

// ---------------------------------------------------------------------------
// Unmerge scatter
// ---------------------------------------------------------------------------
__global__ __launch_bounds__(256) void scatter_out(
    const float* __restrict__ out_m, const int* __restrict__ src_row,
    float* __restrict__ out) {
  const int row = blockIdx.x;
  const int b = row >> 11;
  const int p = row & (NN - 1);
  const int sr = src_row[b * NN + p];
  float4 val = make_float4(0.f, 0.f, 0.f, 0.f);
  if (sr >= 0)
    val = reinterpret_cast<const float4*>(out_m +
                                          ((size_t)(b * NM + sr)) * DM)[threadIdx.x];
  reinterpret_cast<float4*>(out + (size_t)row * DM)[threadIdx.x] = val;
}

// ---------------------------------------------------------------------------
extern "C" void kernel_launch(void* const* d_in, const int* in_sizes, int n_in,
                              void* d_out, int out_size, void* d_ws,
                              size_t ws_size, hipStream_t stream) {
  const float* x = (const float*)d_in[0];
  const float* fc = (const float*)d_in[1];
  const float* Wq = (const float*)d_in[2];
  const float* Wk = (const float*)d_in[3];
  const float* Wv = (const float*)d_in[4];
  const float* Wo = (const float*)d_in[5];
  float* out = (float*)d_out;

  char* ws = (char*)d_ws;
  size_t off = 0;
  auto alloc = [&](size_t bytes) {
    void* p = ws + off;
    off += (bytes + 255) & ~(size_t)255;
    return p;
  };
  float* metric = (float*)alloc((size_t)BB * NN * 256 * 4);
  float* best_s = (float*)alloc((size_t)BB * HALF * 4);
  int* best_b = (int*)alloc((size_t)BB * HALF * 4);
  int* order = (int*)alloc((size_t)BB * HALF * 4);
  int* keep_idx = (int*)alloc((size_t)BB * NM * 4);
  int* src_row = (int*)alloc((size_t)BB * NN * 4);
  int* partner = (int*)alloc((size_t)BB * NN * 4);
  float* x_m = (float*)alloc((size_t)BB * NM * DM * 4);
  float* qb = (float*)alloc((size_t)BB * NM * DM * 4);
  float* kb = (float*)alloc((size_t)BB * NM * NKV * HD * 4);
  float* vb = (float*)alloc((size_t)BB * NM * NKV * HD * 4);
  float* attn_o = (float*)alloc((size_t)BB * NM * DM * 4);
  __bf16* qbh = (__bf16*)alloc((size_t)BB * NH * NM * 64 * 2);
  __bf16* kbh = (__bf16*)alloc((size_t)BB * NKV * NM * 64 * 2);
  __bf16* vtb = (__bf16*)alloc((size_t)BB * NKV * 64 * NM * 2);
  float* out_m = x_m;

  // selection path (fp32, exact)
  gemm_rows<<<dim3((BB * NN) / 16, 1), 256, 0, stream>>>(x, Wk, metric,
                                                         BB * NN, DM, 256);
  normalize_rows<<<BB * NN, 256, 0, stream>>>(metric);
  scores_argmax<<<dim3(HALF / 8, BB), 256, 0, stream>>>(metric, best_s, best_b);
  sort_desc<<<BB, 256, 0, stream>>>(best_s, order);
  select_and_index<<<BB, 256, 0, stream>>>(best_b, order, keep_idx, src_row,
                                           partner);
  merge_kernel<<<BB * NM, 256, 0, stream>>>(x, keep_idx, partner, x_m);
  // projections (fp32)
  gemm_rows4<<<(BB * NM) / 16, 256, 0, stream>>>(x_m, Wq, qb, BB * NM, DM);
  gemm_rows<<<dim3((BB * NM) / 16, 1), 256, 0, stream>>>(x_m, Wk, kb, BB * NM,
                                                         DM, NKV * HD);
  gemm_rows<<<dim3((BB * NM) / 16, 1), 256, 0, stream>>>(x_m, Wv, vb, BB * NM,
                                                         DM, NKV * HD);
  // RoPE + bf16 repack
  rope_repack<<<BB * NM, 256, 0, stream>>>(qb, fc, qbh, NH, 0.125f);
  rope_repack<<<BB * NM, 128, 0, stream>>>(kb, fc, kbh, NKV, 1.0f);
  v_repack<<<BB * NKV * (NM / 64), 256, 0, stream>>>(vb, vtb);
  // MFMA flash attention
  attn_mfma<<<BB * NKV * (NM / 16), 256, 0, stream>>>(qbh, kbh, vtb, attn_o);
  // output projection (fp32)
  gemm_rows4<<<(BB * NM) / 16, 256, 0, stream>>>(attn_o, Wo, out_m, BB * NM, DM);
  scatter_out<<<BB * NN, 256, 0, stream>>>(out_m, src_row, out);
}

// Round 5
// 620.779 us; speedup vs baseline: 10.5785x; 2.5057x over previous
//
#include <hip/hip_runtime.h>
#include <hip/hip_bf16.h>
#include <math.h>

// Problem constants
#define BB 2
#define NN 2048
#define DM 1024
#define NH 16
#define NKV 4
#define HD 64
#define RR 256
#define HALF 1024
#define NM 1792   // NN - RR

typedef __bf16 bf16x8 __attribute__((ext_vector_type(8)));
typedef float f32x4 __attribute__((ext_vector_type(4)));

__device__ inline unsigned pk2(float a, float b) {
  union { __bf16 h; unsigned short u; } ua, ub;
  ua.h = (__bf16)a;
  ub.h = (__bf16)b;
  return (unsigned)ua.u | ((unsigned)ub.u << 16);
}

__device__ inline unsigned shu(unsigned v, int s) {
  return (unsigned)__shfl((int)v, s, 64);
}

// ---------------------------------------------------------------------------
// bf16 MFMA GEMM: C[M x N] (+)= A[M x K] @ Bt[N x K]^T.  BM=BN=BK=64.
// 256 thr = 4 waves; wave w computes rows [w*16, w*16+16) x 64 cols.
// LDS tiles stored fragment-linear: chunk(blk, s)[lane] at ((blk*2+s)*64+lane)*16B
// -> every ds_read_b128 is lane*16B contiguous (2-way alias only = free).
// ---------------------------------------------------------------------------
__global__ __launch_bounds__(256) void gemm_bf16(
    const __bf16* __restrict__ A, const __bf16* __restrict__ Bt,
    float* __restrict__ C, int M, int N, int K, int accflag) {
  __shared__ __align__(16) __bf16 As[4096];
  __shared__ __align__(16) __bf16 Bs[4096];
  const int bm0 = blockIdx.x * 64;
  const int bn0 = blockIdx.y * 64;
  const int w = threadIdx.x >> 6;
  const int lane = threadIdx.x & 63;
  f32x4 acc[4];
#pragma unroll
  for (int nt = 0; nt < 4; ++nt) acc[nt] = (f32x4){0.f, 0.f, 0.f, 0.f};
  for (int kk = 0; kk < K; kk += 64) {
    __syncthreads();
#pragma unroll
    for (int t2 = threadIdx.x; t2 < 512; t2 += 256) {
      const int blk = t2 >> 7, s = (t2 >> 6) & 1, l = t2 & 63;
      const int kc = kk + s * 32 + ((l >> 4) << 3);
      *(float4*)&As[t2 * 8] =
          *(const float4*)(A + (size_t)(bm0 + blk * 16 + (l & 15)) * K + kc);
      *(float4*)&Bs[t2 * 8] =
          *(const float4*)(Bt + (size_t)(bn0 + blk * 16 + (l & 15)) * K + kc);
    }
    __syncthreads();
#pragma unroll
    for (int s = 0; s < 2; ++s) {
      bf16x8 a = *(const bf16x8*)&As[((w * 2 + s) * 64 + lane) * 8];
#pragma unroll
      for (int nt = 0; nt < 4; ++nt) {
        bf16x8 bfr = *(const bf16x8*)&Bs[((nt * 2 + s) * 64 + lane) * 8];
        acc[nt] =
            __builtin_amdgcn_mfma_f32_16x16x32_bf16(a, bfr, acc[nt], 0, 0, 0);
      }
    }
  }
  const int g = lane >> 4, ml = lane & 15;
#pragma unroll
  for (int nt = 0; nt < 4; ++nt)
#pragma unroll
    for (int r = 0; r < 4; ++r) {
      const size_t idx =
          (size_t)(bm0 + w * 16 + g * 4 + r) * N + bn0 + nt * 16 + ml;
      float v = acc[nt][r];
      if (accflag) v += C[idx];
      C[idx] = v;
    }
}

// ---------------------------------------------------------------------------
// x -> (xh, xl) bf16 split (fp32-accurate MFMA path for the selection metric)
// ---------------------------------------------------------------------------
__global__ __launch_bounds__(256) void hilo_split(const float* __restrict__ x,
                                                  __bf16* __restrict__ xh,
                                                  __bf16* __restrict__ xl) {
  const int i = blockIdx.x * 256 + threadIdx.x;
  float4 v = ((const float4*)x)[i];
  float f[4] = {v.x, v.y, v.z, v.w};
  union { __bf16 h[4]; uint2 u; } H, L;
#pragma unroll
  for (int j = 0; j < 4; ++j) {
    __bf16 hh = (__bf16)f[j];
    H.h[j] = hh;
    L.h[j] = (__bf16)(f[j] - (float)hh);
  }
  ((uint2*)xh)[i] = H.u;
  ((uint2*)xl)[i] = L.u;
}

// ---------------------------------------------------------------------------
// W [K x N] fp32 -> Wt [N x K] bf16 (transpose+convert), 64x64 LDS tiles
// ---------------------------------------------------------------------------
__global__ __launch_bounds__(256) void transpose_bf16(
    const float* __restrict__ W, __bf16* __restrict__ Wt, int K, int N) {
  __shared__ float ld[64][65];
  const int k0 = blockIdx.x * 64, n0 = blockIdx.y * 64;
  for (int i = threadIdx.x; i < 1024; i += 256) {
    int r = i >> 4, c4 = i & 15;
    float4 v = *(const float4*)(W + (size_t)(k0 + r) * N + n0 + c4 * 4);
    ld[r][c4 * 4 + 0] = v.x;
    ld[r][c4 * 4 + 1] = v.y;
    ld[r][c4 * 4 + 2] = v.z;
    ld[r][c4 * 4 + 3] = v.w;
  }
  __syncthreads();
  for (int i = threadIdx.x; i < 4096; i += 256) {
    int n = i >> 6, k = i & 63;
    Wt[(size_t)(n0 + n) * K + k0 + k] = (__bf16)ld[k][n];
  }
}

__global__ __launch_bounds__(256) void transpose_hilo(
    const float* __restrict__ W, __bf16* __restrict__ Wh,
    __bf16* __restrict__ Wl, int K, int N) {
  __shared__ float ld[64][65];
  const int k0 = blockIdx.x * 64, n0 = blockIdx.y * 64;
  for (int i = threadIdx.x; i < 1024; i += 256) {
    int r = i >> 4, c4 = i & 15;
    float4 v = *(const float4*)(W + (size_t)(k0 + r) * N + n0 + c4 * 4);
    ld[r][c4 * 4 + 0] = v.x;
    ld[r][c4 * 4 + 1] = v.y;
    ld[r][c4 * 4 + 2] = v.z;
    ld[r][c4 * 4 + 3] = v.w;
  }
  __syncthreads();
  for (int i = threadIdx.x; i < 4096; i += 256) {
    int n = i >> 6, k = i & 63;
    float v = ld[k][n];
    __bf16 hh = (__bf16)v;
    Wh[(size_t)(n0 + n) * K + k0 + k] = hh;
    Wl[(size_t)(n0 + n) * K + k0 + k] = (__bf16)(v - (float)hh);
  }
}

// ---------------------------------------------------------------------------
// Normalize each 256-float row of metric in place
// ---------------------------------------------------------------------------
__global__ __launch_bounds__(256) void normalize_rows(float* __restrict__ m) {
  const int row = blockIdx.x;
  const int t = threadIdx.x;
  float v = m[(size_t)row * 256 + t];
  float ss = v * v;
#pragma unroll
  for (int o = 32; o > 0; o >>= 1) ss += __shfl_xor(ss, o, 64);
  __shared__ float wsum[4];
  if ((t & 63) == 0) wsum[t >> 6] = ss;
  __syncthreads();
  float tot = wsum[0] + wsum[1] + wsum[2] + wsum[3];
  float inv = 1.f / fmaxf(sqrtf(tot), 1e-12f);
  m[(size_t)row * 256 + t] = v * inv;
}

// ---------------------------------------------------------------------------
// Fused scores + row-argmax (fp32, exact selection semantics).
// ---------------------------------------------------------------------------
__global__ __launch_bounds__(256) void scores_argmax(
    const float* __restrict__ metric, float* __restrict__ best_s,
    int* __restrict__ best_b) {
  const int b = blockIdx.y;
  const int i0 = blockIdx.x * 8;
  __shared__ float As[8][256];
  const float* mb = metric + (size_t)b * NN * 256;
  for (int idx = threadIdx.x; idx < 8 * 256; idx += 256) {
    int r = idx >> 8, c = idx & 255;
    As[r][c] = mb[(size_t)(2 * (i0 + r)) * 256 + c];
  }
  __syncthreads();
  float bv[8];
  int bj[8];
#pragma unroll
  for (int r = 0; r < 8; ++r) { bv[r] = -2.f; bj[r] = 0; }
  for (int jj = 0; jj < 4; ++jj) {
    int j = threadIdx.x + jj * 256;
    const float* brow = mb + (size_t)(2 * j + 1) * 256;
    float acc[8];
#pragma unroll
    for (int r = 0; r < 8; ++r) acc[r] = 0.f;
    for (int c = 0; c < 256; ++c) {
      float bvv = brow[c];
#pragma unroll
      for (int r = 0; r < 8; ++r) acc[r] += As[r][c] * bvv;
    }
#pragma unroll
    for (int r = 0; r < 8; ++r)
      if (acc[r] > bv[r]) { bv[r] = acc[r]; bj[r] = j; }
  }
  __shared__ float rv[256];
  __shared__ int ri[256];
  for (int r = 0; r < 8; ++r) {
    rv[threadIdx.x] = bv[r];
    ri[threadIdx.x] = bj[r];
    __syncthreads();
    for (int s = 128; s > 0; s >>= 1) {
      if (threadIdx.x < (unsigned)s) {
        float v2 = rv[threadIdx.x + s];
        int i2 = ri[threadIdx.x + s];
        float v1 = rv[threadIdx.x];
        int i1 = ri[threadIdx.x];
        if (v2 > v1 || (v2 == v1 && i2 < i1)) {
          rv[threadIdx.x] = v2;
          ri[threadIdx.x] = i2;
        }
      }
      __syncthreads();
    }
    if (threadIdx.x == 0) {
      best_s[b * HALF + i0 + r] = rv[0];
      best_b[b * HALF + i0 + r] = ri[0];
    }
    __syncthreads();
  }
}

// ---------------------------------------------------------------------------
// Stable descending bitonic argsort of 1024 scores per batch.
// ---------------------------------------------------------------------------
__global__ __launch_bounds__(256) void sort_desc(const float* __restrict__ best_s,
                                                 int* __restrict__ order) {
  const int b = blockIdx.x;
  __shared__ float sv[1024];
  __shared__ int si[1024];
  for (int i = threadIdx.x; i < 1024; i += 256) {
    sv[i] = best_s[b * HALF + i];
    si[i] = i;
  }
  __syncthreads();
  for (int k = 2; k <= 1024; k <<= 1) {
    for (int j = k >> 1; j > 0; j >>= 1) {
      for (int t = threadIdx.x; t < 1024; t += 256) {
        int ixj = t ^ j;
        if (ixj > t) {
          bool dir = ((t & k) == 0);
          float va = sv[t], vb = sv[ixj];
          int ia = si[t], ib = si[ixj];
          bool before = (vb > va) || (vb == va && ib < ia);
          if (before == dir) {
            sv[t] = vb; sv[ixj] = va;
            si[t] = ib; si[ixj] = ia;
          }
        }
      }
      __syncthreads();
    }
  }
  for (int i = threadIdx.x; i < 1024; i += 256) order[b * HALF + i] = si[i];
}

// ---------------------------------------------------------------------------
// Greedy unique-b selection + index maps. One block per batch.
// ---------------------------------------------------------------------------
__global__ __launch_bounds__(256) void select_and_index(
    const int* __restrict__ best_b, const int* __restrict__ order,
    int* __restrict__ keep_idx, int* __restrict__ src_row,
    int* __restrict__ partner) {
  const int b = blockIdx.x;
  __shared__ int used[HALF];
  __shared__ int sel_a[RR], sel_b[RR];
  __shared__ int removed[NN];
  __shared__ int tsum[256];
  for (int i = threadIdx.x; i < HALF; i += 256) used[i] = 0;
  for (int i = threadIdx.x; i < NN; i += 256) {
    removed[i] = 0;
    partner[b * NN + i] = -1;
  }
  __syncthreads();
  if (threadIdx.x == 0) {
    int cnt = 0;
    for (int step = 0; step < HALF; ++step) {
      int a = order[b * HALF + step];
      int bb = best_b[b * HALF + a];
      if (!used[bb] && cnt < RR) {
        used[bb] = 1;
        sel_a[cnt] = a;
        sel_b[cnt] = bb;
        ++cnt;
      }
    }
    for (int s = cnt; s < RR; ++s) { sel_a[s] = sel_a[0]; sel_b[s] = sel_b[0]; }
  }
  __syncthreads();
  {
    int s = threadIdx.x;
    int ga = 2 * sel_a[s], gb = 2 * sel_b[s] + 1;
    removed[gb] = 1;
    partner[b * NN + ga] = gb;
    sel_a[s] = ga;
    sel_b[s] = gb;
  }
  __syncthreads();
  int myc = 0;
#pragma unroll
  for (int q = 0; q < 8; ++q) myc += !removed[8 * threadIdx.x + q];
  tsum[threadIdx.x] = myc;
  __syncthreads();
  for (int off = 1; off < 256; off <<= 1) {
    int v = (threadIdx.x >= (unsigned)off) ? tsum[threadIdx.x - off] : 0;
    __syncthreads();
    tsum[threadIdx.x] += v;
    __syncthreads();
  }
  int pos = tsum[threadIdx.x] - myc;
#pragma unroll
  for (int q = 0; q < 8; ++q) {
    int p = 8 * threadIdx.x + q;
    int sr = -1;
    if (!removed[p]) {
      if (pos < NM) {
        keep_idx[b * NM + pos] = p;
        sr = pos;
      }
      ++pos;
    }
    src_row[b * NN + p] = sr;
  }
  __syncthreads();
  {
    int s = threadIdx.x;
    src_row[b * NN + sel_b[s]] = src_row[b * NN + sel_a[s]];
  }
}

// ---------------------------------------------------------------------------
// Merge -> bf16 x_mb (feeds the bf16 MFMA projections)
// ---------------------------------------------------------------------------
__global__ __launch_bounds__(256) void merge_kernel(
    const float* __restrict__ x, const int* __restrict__ keep_idx,
    const int* __restrict__ partner, __bf16* __restrict__ x_mb) {
  const int mrow = blockIdx.x;
  const int b = mrow / NM;
  const int t = mrow % NM;
  const int p = keep_idx[b * NM + t];
  const int pp = partner[b * NN + p];
  const float4* src =
      reinterpret_cast<const float4*>(x + ((size_t)b * NN + p) * DM);
  float4 val = src[threadIdx.x];
  if (pp >= 0) {
    const float4* s2 =
        reinterpret_cast<const float4*>(x + ((size_t)b * NN + pp) * DM);
    float4 v2 = s2[threadIdx.x];
    val.x = 0.5f * (val.x + v2.x);
    val.y = 0.5f * (val.y + v2.y);
    val.z = 0.5f * (val.z + v2.z);
    val.w = 0.5f * (val.w + v2.w);
  }
  union { __bf16 h[4]; uint2 u; } U;
  U.h[0] = (__bf16)val.x;
  U.h[1] = (__bf16)val.y;
  U.h[2] = (__bf16)val.z;
  U.h[3] = (__bf16)val.w;
  ((uint2*)(x_mb + (size_t)mrow * DM))[threadIdx.x] = U.u;
}

// ---------------------------------------------------------------------------
// RoPE + head-major repack + bf16 convert.
// src fp32 [b, n, heads, 64]  ->  dst bf16 [b, heads, n, 64], scaled.
// ---------------------------------------------------------------------------
__global__ void rope_repack(const float* __restrict__ src,
                            const float* __restrict__ fc,
                            __bf16* __restrict__ dst, int heads, float scale) {
  const int row = blockIdx.x;
  const int t = row % NM;
  const int b = row / NM;
  const int npairs = heads * 32;
  for (int idx = threadIdx.x; idx < npairs; idx += blockDim.x) {
    int h = idx >> 5, u = idx & 31;
    float c = fc[(t * 32 + u) * 2];
    float s = fc[(t * 32 + u) * 2 + 1];
    const float* p = src + (size_t)row * heads * 64 + h * 64 + 2 * u;
    float x1 = p[0], x2 = p[1];
    __bf16* d = dst + ((size_t)(b * heads + h) * NM + t) * 64 + 2 * u;
    d[0] = (__bf16)((x1 * c - x2 * s) * scale);
    d[1] = (__bf16)((x1 * s + x2 * c) * scale);
  }
}

// ---------------------------------------------------------------------------
// V repack: fp32 [b, n, kvh, 64] -> bf16 transposed [b, kvh, 64 (dim), NM (key)]
// ---------------------------------------------------------------------------
__global__ __launch_bounds__(256) void v_repack(const float* __restrict__ vb,
                                                __bf16* __restrict__ vtb) {
  __shared__ float ld[64][65];
  int bid = blockIdx.x;
  const int kt = bid % (NM / 64); bid /= (NM / 64);
  const int kvh = bid % NKV;
  const int b = bid / NKV;
  const int j0 = kt * 64;
  for (int t2 = threadIdx.x; t2 < 1024; t2 += 256) {
    int key = t2 >> 4, c4 = t2 & 15;
    float4 v4 = *reinterpret_cast<const float4*>(
        vb + (((size_t)(b * NM + j0 + key)) * NKV + kvh) * 64 + c4 * 4);
    ld[key][c4 * 4 + 0] = v4.x;
    ld[key][c4 * 4 + 1] = v4.y;
    ld[key][c4 * 4 + 2] = v4.z;
    ld[key][c4 * 4 + 3] = v4.w;
  }
  __syncthreads();
  const int dim = threadIdx.x >> 2, kc = threadIdx.x & 3;
  __bf16* out = vtb + ((size_t)(b * NKV + kvh) * 64 + dim) * NM + j0 + kc * 16;
#pragma unroll
  for (int kk = 0; kk < 16; ++kk) out[kk] = (__bf16)ld[kc * 16 + kk][dim];
}

// ---------------------------------------------------------------------------
// Flash attention v3, bf16 MFMA, S^T orientation.
// Block = (b, kvh, 16-query tile); wave w = head kvh*4+w.
// S^T = K.Q^T  -> lane holds S[q=ml][key = nt*16 + g*4 + r]  (softmax row on
// lane=ml, reduced over g via shfl_xor 16/32). P enters PV as B-operand via
// 16 shuffles (no P LDS round-trip). K/V LDS tiles are fragment-linear
// (lane*16B reads -> conflict-free). O accumulated transposed; bf16 out.
// ---------------------------------------------------------------------------
__global__ __launch_bounds__(256) void attn_mfma(
    const __bf16* __restrict__ qbh,  // [b, h, n, 64], pre-scaled by 0.125
    const __bf16* __restrict__ kbh,  // [b, kvh, n, 64]
    const __bf16* __restrict__ vtb,  // [b, kvh, 64, NM]
    __bf16* __restrict__ attn_ob) {  // [b, n, 1024]
  __shared__ __align__(16) __bf16 Ks[4096];
  __shared__ __align__(16) __bf16 Vs[4096];
  int bid = blockIdx.x;
  const int qt = bid % (NM / 16); bid /= (NM / 16);
  const int kvh = bid % NKV;
  const int b = bid / NKV;
  const int w = threadIdx.x >> 6;
  const int lane = threadIdx.x & 63;
  const int h = kvh * 4 + w;
  const int g = lane >> 4;
  const int ml = lane & 15;

  // Q fragment (B-operand for S^T): Q[q=ml][dim=g*8+j]
  const __bf16* qrow = qbh + ((size_t)(b * NH + h) * NM + qt * 16 + ml) * 64;
  bf16x8 qa0 = *reinterpret_cast<const bf16x8*>(qrow + g * 8);
  bf16x8 qa1 = *reinterpret_cast<const bf16x8*>(qrow + 32 + g * 8);

  f32x4 acc[4];
#pragma unroll
  for (int mt = 0; mt < 4; ++mt) acc[mt] = (f32x4){0.f, 0.f, 0.f, 0.f};
  float mstate = -1e30f, lstate = 0.f;  // per lane: q = ml (replicated over g)

  const __bf16* kp = kbh + (size_t)(b * NKV + kvh) * NM * 64;
  const __bf16* vp = vtb + (size_t)(b * NKV + kvh) * 64 * NM;
  const int src0 = ((lane >> 4) & 1) * 32 + ml;
  const int src1 = src0 + 16;
  const int sel = g >> 1;

  for (int jt = 0; jt < NM / 64; ++jt) {
    __syncthreads();
#pragma unroll
    for (int t2 = threadIdx.x; t2 < 512; t2 += 256) {
      const int blk = t2 >> 7, s = (t2 >> 6) & 1, l = t2 & 63;
      *(float4*)&Ks[t2 * 8] = *(const float4*)(
          kp + (size_t)(jt * 64 + blk * 16 + (l & 15)) * 64 + s * 32 +
          ((l >> 4) << 3));
      *(float4*)&Vs[t2 * 8] = *(const float4*)(
          vp + (size_t)(blk * 16 + (l & 15)) * NM + jt * 64 + s * 32 +
          ((l >> 4) << 3));
    }
    __syncthreads();
    // ---- S^T = K Q^T: A = K[key=nt*16+ml][dim], B = Q[q=ml][dim]
    f32x4 S[4];
#pragma unroll
    for (int nt = 0; nt < 4; ++nt) {
      bf16x8 k0 = *(const bf16x8*)&Ks[(nt * 128 + lane) * 8];
      bf16x8 k1 = *(const bf16x8*)&Ks[(nt * 128 + 64 + lane) * 8];
      f32x4 s4 = (f32x4){0.f, 0.f, 0.f, 0.f};
      s4 = __builtin_amdgcn_mfma_f32_16x16x32_bf16(k0, qa0, s4, 0, 0, 0);
      s4 = __builtin_amdgcn_mfma_f32_16x16x32_bf16(k1, qa1, s4, 0, 0, 0);
      S[nt] = s4;  // S[q=ml][key = nt*16 + g*4 + r]
    }
    // ---- online softmax for q = ml
    float mx = S[0][0];
#pragma unroll
    for (int nt = 0; nt < 4; ++nt)
#pragma unroll
      for (int r = 0; r < 4; ++r) mx = fmaxf(mx, S[nt][r]);
    mx = fmaxf(mx, __shfl_xor(mx, 16, 64));
    mx = fmaxf(mx, __shfl_xor(mx, 32, 64));
    float mnew = fmaxf(mstate, mx);
    float alpha = __expf(mstate - mnew);
    float p[4][4];
    float rs = 0.f;
#pragma unroll
    for (int nt = 0; nt < 4; ++nt)
#pragma unroll
      for (int r = 0; r < 4; ++r) {
        p[nt][r] = __expf(S[nt][r] - mnew);
        rs += p[nt][r];
      }
    rs += __shfl_xor(rs, 16, 64);
    rs += __shfl_xor(rs, 32, 64);
    lstate = lstate * alpha + rs;
    mstate = mnew;
#pragma unroll
    for (int mt = 0; mt < 4; ++mt) {
      acc[mt][0] *= alpha; acc[mt][1] *= alpha;
      acc[mt][2] *= alpha; acc[mt][3] *= alpha;
    }
    // ---- pack P to bf16 pairs, redistribute to B-fragment via shuffles
    unsigned pk[4][2];
#pragma unroll
    for (int nt = 0; nt < 4; ++nt) {
      pk[nt][0] = pk2(p[nt][0], p[nt][1]);
      pk[nt][1] = pk2(p[nt][2], p[nt][3]);
    }
    unsigned A00 = shu(pk[0][0], src0), A01 = shu(pk[0][1], src0);
    unsigned A10 = shu(pk[1][0], src0), A11 = shu(pk[1][1], src0);
    unsigned B00 = shu(pk[0][0], src1), B01 = shu(pk[0][1], src1);
    unsigned B10 = shu(pk[1][0], src1), B11 = shu(pk[1][1], src1);
    unsigned C00 = shu(pk[2][0], src0), C01 = shu(pk[2][1], src0);
    unsigned C10 = shu(pk[3][0], src0), C11 = shu(pk[3][1], src0);
    unsigned D00 = shu(pk[2][0], src1), D01 = shu(pk[2][1], src1);
    unsigned D10 = shu(pk[3][0], src1), D11 = shu(pk[3][1], src1);
    union { uint4 u; bf16x8 v; } P0, P1;
    P0.u.x = sel ? A10 : A00; P0.u.y = sel ? A11 : A01;
    P0.u.z = sel ? B10 : B00; P0.u.w = sel ? B11 : B01;
    P1.u.x = sel ? C10 : C00; P1.u.y = sel ? C11 : C01;
    P1.u.z = sel ? D10 : D00; P1.u.w = sel ? D11 : D01;
    // ---- O^T += V^T P^T:  A = V[key][dim=mt*16+ml], B = P[q=ml][key]
#pragma unroll
    for (int mt = 0; mt < 4; ++mt) {
      bf16x8 v0 = *(const bf16x8*)&Vs[(mt * 128 + lane) * 8];
      bf16x8 v1 = *(const bf16x8*)&Vs[(mt * 128 + 64 + lane) * 8];
      acc[mt] = __builtin_amdgcn_mfma_f32_16x16x32_bf16(v0, P0.v, acc[mt], 0, 0, 0);
      acc[mt] = __builtin_amdgcn_mfma_f32_16x16x32_bf16(v1, P1.v, acc[mt], 0, 0, 0);
    }
  }
  // epilogue: acc[mt][r] = O[q=ml][dim = mt*16 + g*4 + r]
  float invl = 1.f / lstate;
#pragma unroll
  for (int mt = 0; mt < 4; ++mt) {
    unsigned lo = pk2(acc[mt][0] * invl, acc[mt][1] * invl);
    unsigned hi = pk2(acc[mt][2] * invl, acc[mt][3] * invl);
    size_t off =
        ((size_t)(b * NM) + qt * 16 + ml) * DM + h * 64 + mt * 16 + g * 4;
    uint2 u; u.x = lo; u.y = hi;
    *reinterpret_cast<uint2*>(attn_ob + off) = u;
  }
}

// ---------------------------------------------------------------------------
// Unmerge scatter
// ---------------------------------------------------------------------------
__global__ __launch_bounds__(256) void scatter_out(
    const float* __restrict__ out_m, const int* __restrict__ src_row,
    float* __restrict__ out) {
  const int row = blockIdx.x;
  const int b = row >> 11;
  const int p = row & (NN - 1);
  const int sr = src_row[b * NN + p];
  float4 val = make_float4(0.f, 0.f, 0.f, 0.f);
  if (sr >= 0)
    val = reinterpret_cast<const float4*>(out_m +
                                          ((size_t)(b * NM + sr)) * DM)[threadIdx.x];
  reinterpret_cast<float4*>(out + (size_t)row * DM)[threadIdx.x] = val;
}

// ---------------------------------------------------------------------------
extern "C" void kernel_launch(void* const* d_in, const int* in_sizes, int n_in,
                              void* d_out, int out_size, void* d_ws,
                              size_t ws_size, hipStream_t stream) {
  const float* x = (const float*)d_in[0];
  const float* fc = (const float*)d_in[1];
  const float* Wq = (const float*)d_in[2];
  const float* Wk = (const float*)d_in[3];
  const float* Wv = (const float*)d_in[4];
  const float* Wo = (const float*)d_in[5];
  float* out = (float*)d_out;

  char* ws = (char*)d_ws;
  size_t off = 0;
  auto alloc = [&](size_t bytes) {
    void* p = ws + off;
    off += (bytes + 255) & ~(size_t)255;
    return p;
  };
  float* metric = (float*)alloc((size_t)BB * NN * 256 * 4);   // 4 MB
  float* best_s = (float*)alloc((size_t)BB * HALF * 4);
  int* best_b = (int*)alloc((size_t)BB * HALF * 4);
  int* order = (int*)alloc((size_t)BB * HALF * 4);
  int* keep_idx = (int*)alloc((size_t)BB * NM * 4);
  int* src_row = (int*)alloc((size_t)BB * NN * 4);
  int* partner = (int*)alloc((size_t)BB * NN * 4);
  // shared big region: xh+xl (metric phase) -> qb (proj phase) -> out_m (tail)
  char* bigreg = (char*)alloc((size_t)18 * 1024 * 1024);
  __bf16* xh = (__bf16*)bigreg;                              // 8.4 MB
  __bf16* xl = (__bf16*)(bigreg + (size_t)9 * 1024 * 1024);  // 8.4 MB
  float* qb = (float*)bigreg;                                // 14.3 MB
  float* out_m = (float*)bigreg;                             // 14.3 MB
  __bf16* x_mb = (__bf16*)alloc((size_t)BB * NM * DM * 2);
  float* kb = (float*)alloc((size_t)BB * NM * NKV * HD * 4);
  float* vb = (float*)alloc((size_t)BB * NM * NKV * HD * 4);
  __bf16* qbh = (__bf16*)alloc((size_t)BB * NH * NM * 64 * 2);
  __bf16* kbh = (__bf16*)alloc((size_t)BB * NKV * NM * 64 * 2);
  __bf16* vtb = (__bf16*)alloc((size_t)BB * NKV * 64 * NM * 2);
  __bf16* attn_ob = (__bf16*)alloc((size_t)BB * NM * DM * 2);
  __bf16* Wqt = (__bf16*)alloc((size_t)DM * DM * 2);
  __bf16* Wkth = (__bf16*)alloc((size_t)256 * DM * 2);
  __bf16* Wktl = (__bf16*)alloc((size_t)256 * DM * 2);
  __bf16* Wvt = (__bf16*)alloc((size_t)256 * DM * 2);
  __bf16* Wot = (__bf16*)alloc((size_t)DM * DM * 2);

  // ---- weight/input converts
  hilo_split<<<(BB * NN * DM / 4) / 256, 256, 0, stream>>>(x, xh, xl);
  transpose_hilo<<<dim3(16, 4), 256, 0, stream>>>(Wk, Wkth, Wktl, DM, 256);
  transpose_bf16<<<dim3(16, 16), 256, 0, stream>>>(Wq, Wqt, DM, DM);
  transpose_bf16<<<dim3(16, 4), 256, 0, stream>>>(Wv, Wvt, DM, 256);
  transpose_bf16<<<dim3(16, 16), 256, 0, stream>>>(Wo, Wot, DM, DM);
  // ---- metric = x @ Wk (fp32-accurate via bf16 hi/lo split, 3 passes)
  gemm_bf16<<<dim3(64, 4), 256, 0, stream>>>(xh, Wkth, metric, BB * NN, 256, DM, 0);
  gemm_bf16<<<dim3(64, 4), 256, 0, stream>>>(xh, Wktl, metric, BB * NN, 256, DM, 1);
  gemm_bf16<<<dim3(64, 4), 256, 0, stream>>>(xl, Wkth, metric, BB * NN, 256, DM, 1);
  // ---- selection (fp32, exact)
  normalize_rows<<<BB * NN, 256, 0, stream>>>(metric);
  scores_argmax<<<dim3(HALF / 8, BB), 256, 0, stream>>>(metric, best_s, best_b);
  sort_desc<<<BB, 256, 0, stream>>>(best_s, order);
  select_and_index<<<BB, 256, 0, stream>>>(best_b, order, keep_idx, src_row,
                                           partner);
  merge_kernel<<<BB * NM, 256, 0, stream>>>(x, keep_idx, partner, x_mb);
  // ---- projections (bf16 MFMA)
  gemm_bf16<<<dim3(56, 16), 256, 0, stream>>>(x_mb, Wqt, qb, BB * NM, DM, DM, 0);
  gemm_bf16<<<dim3(56, 4), 256, 0, stream>>>(x_mb, Wkth, kb, BB * NM, 256, DM, 0);
  gemm_bf16<<<dim3(56, 4), 256, 0, stream>>>(x_mb, Wvt, vb, BB * NM, 256, DM, 0);
  // ---- RoPE + repack
  rope_repack<<<BB * NM, 256, 0, stream>>>(qb, fc, qbh, NH, 0.125f);
  rope_repack<<<BB * NM, 128, 0, stream>>>(kb, fc, kbh, NKV, 1.0f);
  v_repack<<<BB * NKV * (NM / 64), 256, 0, stream>>>(vb, vtb);
  // ---- attention
  attn_mfma<<<BB * NKV * (NM / 16), 256, 0, stream>>>(qbh, kbh, vtb, attn_ob);
  // ---- output projection + unmerge
  gemm_bf16<<<dim3(56, 16), 256, 0, stream>>>(attn_ob, Wot, out_m, BB * NM, DM,
                                              DM, 0);
  scatter_out<<<BB * NN, 256, 0, stream>>>(out_m, src_row, out);
}

// Round 6
// 478.768 us; speedup vs baseline: 13.7163x; 1.2966x over previous
//
#include <hip/hip_runtime.h>
#include <hip/hip_bf16.h>
#include <math.h>

// Problem constants
#define BB 2
#define NN 2048
#define DM 1024
#define NH 16
#define NKV 4
#define HD 64
#define RR 256
#define HALF 1024
#define NM 1792   // NN - RR

typedef __bf16 bf16x8 __attribute__((ext_vector_type(8)));
typedef float f32x4 __attribute__((ext_vector_type(4)));

__device__ inline unsigned pk2(float a, float b) {
  union { __bf16 h; unsigned short u; } ua, ub;
  ua.h = (__bf16)a;
  ub.h = (__bf16)b;
  return (unsigned)ua.u | ((unsigned)ub.u << 16);
}

__device__ inline unsigned shu(unsigned v, int s) {
  return (unsigned)__shfl((int)v, s, 64);
}

// ---------------------------------------------------------------------------
// bf16 MFMA GEMM: C[M x N] (+)= A[M x K] @ Bt[N x K]^T.  BM=BN=BK=64.
// LDS tiles fragment-linear -> every ds_read_b128 is lane*16B (conflict-free).
// ---------------------------------------------------------------------------
__global__ __launch_bounds__(256) void gemm_bf16(
    const __bf16* __restrict__ A, const __bf16* __restrict__ Bt,
    float* __restrict__ C, int M, int N, int K, int accflag) {
  __shared__ __align__(16) __bf16 As[4096];
  __shared__ __align__(16) __bf16 Bs[4096];
  const int bm0 = blockIdx.x * 64;
  const int bn0 = blockIdx.y * 64;
  const int w = threadIdx.x >> 6;
  const int lane = threadIdx.x & 63;
  f32x4 acc[4];
#pragma unroll
  for (int nt = 0; nt < 4; ++nt) acc[nt] = (f32x4){0.f, 0.f, 0.f, 0.f};
  for (int kk = 0; kk < K; kk += 64) {
    __syncthreads();
#pragma unroll
    for (int t2 = threadIdx.x; t2 < 512; t2 += 256) {
      const int blk = t2 >> 7, s = (t2 >> 6) & 1, l = t2 & 63;
      const int kc = kk + s * 32 + ((l >> 4) << 3);
      *(float4*)&As[t2 * 8] =
          *(const float4*)(A + (size_t)(bm0 + blk * 16 + (l & 15)) * K + kc);
      *(float4*)&Bs[t2 * 8] =
          *(const float4*)(Bt + (size_t)(bn0 + blk * 16 + (l & 15)) * K + kc);
    }
    __syncthreads();
#pragma unroll
    for (int s = 0; s < 2; ++s) {
      bf16x8 a = *(const bf16x8*)&As[((w * 2 + s) * 64 + lane) * 8];
#pragma unroll
      for (int nt = 0; nt < 4; ++nt) {
        bf16x8 bfr = *(const bf16x8*)&Bs[((nt * 2 + s) * 64 + lane) * 8];
        acc[nt] =
            __builtin_amdgcn_mfma_f32_16x16x32_bf16(a, bfr, acc[nt], 0, 0, 0);
      }
    }
  }
  const int g = lane >> 4, ml = lane & 15;
#pragma unroll
  for (int nt = 0; nt < 4; ++nt)
#pragma unroll
    for (int r = 0; r < 4; ++r) {
      const size_t idx =
          (size_t)(bm0 + w * 16 + g * 4 + r) * N + bn0 + nt * 16 + ml;
      float v = acc[nt][r];
      if (accflag) v += C[idx];
      C[idx] = v;
    }
}

// ---------------------------------------------------------------------------
// x -> (xh, xl) bf16 split
// ---------------------------------------------------------------------------
__global__ __launch_bounds__(256) void hilo_split(const float* __restrict__ x,
                                                  __bf16* __restrict__ xh,
                                                  __bf16* __restrict__ xl) {
  const int i = blockIdx.x * 256 + threadIdx.x;
  float4 v = ((const float4*)x)[i];
  float f[4] = {v.x, v.y, v.z, v.w};
  union { __bf16 h[4]; uint2 u; } H, L;
#pragma unroll
  for (int j = 0; j < 4; ++j) {
    __bf16 hh = (__bf16)f[j];
    H.h[j] = hh;
    L.h[j] = (__bf16)(f[j] - (float)hh);
  }
  ((uint2*)xh)[i] = H.u;
  ((uint2*)xl)[i] = L.u;
}

// ---------------------------------------------------------------------------
// W [K x N] fp32 -> Wt [N x K] bf16 transpose+convert
// ---------------------------------------------------------------------------
__global__ __launch_bounds__(256) void transpose_bf16(
    const float* __restrict__ W, __bf16* __restrict__ Wt, int K, int N) {
  __shared__ float ld[64][65];
  const int k0 = blockIdx.x * 64, n0 = blockIdx.y * 64;
  for (int i = threadIdx.x; i < 1024; i += 256) {
    int r = i >> 4, c4 = i & 15;
    float4 v = *(const float4*)(W + (size_t)(k0 + r) * N + n0 + c4 * 4);
    ld[r][c4 * 4 + 0] = v.x;
    ld[r][c4 * 4 + 1] = v.y;
    ld[r][c4 * 4 + 2] = v.z;
    ld[r][c4 * 4 + 3] = v.w;
  }
  __syncthreads();
  for (int i = threadIdx.x; i < 4096; i += 256) {
    int n = i >> 6, k = i & 63;
    Wt[(size_t)(n0 + n) * K + k0 + k] = (__bf16)ld[k][n];
  }
}

__global__ __launch_bounds__(256) void transpose_hilo(
    const float* __restrict__ W, __bf16* __restrict__ Wh,
    __bf16* __restrict__ Wl, int K, int N) {
  __shared__ float ld[64][65];
  const int k0 = blockIdx.x * 64, n0 = blockIdx.y * 64;
  for (int i = threadIdx.x; i < 1024; i += 256) {
    int r = i >> 4, c4 = i & 15;
    float4 v = *(const float4*)(W + (size_t)(k0 + r) * N + n0 + c4 * 4);
    ld[r][c4 * 4 + 0] = v.x;
    ld[r][c4 * 4 + 1] = v.y;
    ld[r][c4 * 4 + 2] = v.z;
    ld[r][c4 * 4 + 3] = v.w;
  }
  __syncthreads();
  for (int i = threadIdx.x; i < 4096; i += 256) {
    int n = i >> 6, k = i & 63;
    float v = ld[k][n];
    __bf16 hh = (__bf16)v;
    Wh[(size_t)(n0 + n) * K + k0 + k] = hh;
    Wl[(size_t)(n0 + n) * K + k0 + k] = (__bf16)(v - (float)hh);
  }
}

// ---------------------------------------------------------------------------
// Normalize each 256-float row of metric in place
// ---------------------------------------------------------------------------
__global__ __launch_bounds__(256) void normalize_rows(float* __restrict__ m) {
  const int row = blockIdx.x;
  const int t = threadIdx.x;
  float v = m[(size_t)row * 256 + t];
  float ss = v * v;
#pragma unroll
  for (int o = 32; o > 0; o >>= 1) ss += __shfl_xor(ss, o, 64);
  __shared__ float wsum[4];
  if ((t & 63) == 0) wsum[t >> 6] = ss;
  __syncthreads();
  float tot = wsum[0] + wsum[1] + wsum[2] + wsum[3];
  float inv = 1.f / fmaxf(sqrtf(tot), 1e-12f);
  m[(size_t)row * 256 + t] = v * inv;
}

// ---------------------------------------------------------------------------
// Fused scores + row-argmax (fp32, exact selection semantics).
// ---------------------------------------------------------------------------
__global__ __launch_bounds__(256) void scores_argmax(
    const float* __restrict__ metric, float* __restrict__ best_s,
    int* __restrict__ best_b) {
  const int b = blockIdx.y;
  const int i0 = blockIdx.x * 8;
  __shared__ float As[8][256];
  const float* mb = metric + (size_t)b * NN * 256;
  for (int idx = threadIdx.x; idx < 8 * 256; idx += 256) {
    int r = idx >> 8, c = idx & 255;
    As[r][c] = mb[(size_t)(2 * (i0 + r)) * 256 + c];
  }
  __syncthreads();
  float bv[8];
  int bj[8];
#pragma unroll
  for (int r = 0; r < 8; ++r) { bv[r] = -2.f; bj[r] = 0; }
  for (int jj = 0; jj < 4; ++jj) {
    int j = threadIdx.x + jj * 256;
    const float* brow = mb + (size_t)(2 * j + 1) * 256;
    float acc[8];
#pragma unroll
    for (int r = 0; r < 8; ++r) acc[r] = 0.f;
    for (int c = 0; c < 256; ++c) {
      float bvv = brow[c];
#pragma unroll
      for (int r = 0; r < 8; ++r) acc[r] += As[r][c] * bvv;
    }
#pragma unroll
    for (int r = 0; r < 8; ++r)
      if (acc[r] > bv[r]) { bv[r] = acc[r]; bj[r] = j; }
  }
  __shared__ float rv[256];
  __shared__ int ri[256];
  for (int r = 0; r < 8; ++r) {
    rv[threadIdx.x] = bv[r];
    ri[threadIdx.x] = bj[r];
    __syncthreads();
    for (int s = 128; s > 0; s >>= 1) {
      if (threadIdx.x < (unsigned)s) {
        float v2 = rv[threadIdx.x + s];
        int i2 = ri[threadIdx.x + s];
        float v1 = rv[threadIdx.x];
        int i1 = ri[threadIdx.x];
        if (v2 > v1 || (v2 == v1 && i2 < i1)) {
          rv[threadIdx.x] = v2;
          ri[threadIdx.x] = i2;
        }
      }
      __syncthreads();
    }
    if (threadIdx.x == 0) {
      best_s[b * HALF + i0 + r] = rv[0];
      best_b[b * HALF + i0 + r] = ri[0];
    }
    __syncthreads();
  }
}

// ---------------------------------------------------------------------------
// Stable descending bitonic argsort of 1024 scores per batch. 512 threads.
// ---------------------------------------------------------------------------
__global__ __launch_bounds__(512) void sort_desc(const float* __restrict__ best_s,
                                                 int* __restrict__ order) {
  const int b = blockIdx.x;
  __shared__ float sv[1024];
  __shared__ int si[1024];
  for (int i = threadIdx.x; i < 1024; i += 512) {
    sv[i] = best_s[b * HALF + i];
    si[i] = i;
  }
  __syncthreads();
  for (int k = 2; k <= 1024; k <<= 1) {
    for (int j = k >> 1; j > 0; j >>= 1) {
      for (int t = threadIdx.x; t < 1024; t += 512) {
        int ixj = t ^ j;
        if (ixj > t) {
          bool dir = ((t & k) == 0);
          float va = sv[t], vb = sv[ixj];
          int ia = si[t], ib = si[ixj];
          bool before = (vb > va) || (vb == va && ib < ia);
          if (before == dir) {
            sv[t] = vb; sv[ixj] = va;
            si[t] = ib; si[ixj] = ia;
          }
        }
      }
      __syncthreads();
    }
  }
  for (int i = threadIdx.x; i < 1024; i += 512) order[b * HALF + i] = si[i];
}

// ---------------------------------------------------------------------------
// Parallel greedy selection. EXACTLY equivalent to the serial scan:
// a token 'a' is taken iff it is the first-in-order token mapping to its
// bin b (winner of b, via atomicMin on rank) AND fewer than RR winners
// precede it in order. Then keep-compaction + partner/src_row maps.
// ---------------------------------------------------------------------------
__global__ __launch_bounds__(256) void select_and_index(
    const int* __restrict__ best_b, const int* __restrict__ order,
    int* __restrict__ keep_idx, int* __restrict__ src_row,
    int* __restrict__ partner) {
  const int b = blockIdx.x;
  __shared__ int rankA[HALF];    // rank of token a in the order
  __shared__ int minrank[HALF];  // per-bin earliest rank
  __shared__ int taken[HALF];    // per-step winner flag
  __shared__ int sel_a[RR], sel_b[RR];
  __shared__ int removed[NN];
  __shared__ int tsum[256];
  const int t = threadIdx.x;

  for (int i = t; i < HALF; i += 256) { minrank[i] = 0x7fffffff; taken[i] = 0; }
  for (int i = t; i < NN; i += 256) {
    removed[i] = 0;
    partner[b * NN + i] = -1;
  }
  __syncthreads();
  // build rank (inverse permutation); keep own order slice in registers
  int ord[4];
#pragma unroll
  for (int q = 0; q < 4; ++q) {
    int step = t * 4 + q;
    ord[q] = order[b * HALF + step];
    rankA[ord[q]] = step;
  }
  __syncthreads();
  // per-bin winner = min rank
#pragma unroll
  for (int q = 0; q < 4; ++q) {
    int a = t * 4 + q;
    atomicMin(&minrank[best_b[b * HALF + a]], rankA[a]);
  }
  __syncthreads();
  // mark winner steps (distinct bins -> distinct steps, no write conflicts)
  for (int i = t; i < HALF; i += 256) {
    int mr = minrank[i];
    if (mr != 0x7fffffff) taken[mr] = 1;
  }
  __syncthreads();
  // prefix-sum of winner flags over steps (4 contiguous steps / thread)
  int c[4];
  int mysum = 0;
#pragma unroll
  for (int q = 0; q < 4; ++q) { c[q] = taken[t * 4 + q]; mysum += c[q]; }
  tsum[t] = mysum;
  __syncthreads();
  for (int off = 1; off < 256; off <<= 1) {
    int v = (t >= off) ? tsum[t - off] : 0;
    __syncthreads();
    tsum[t] += v;
    __syncthreads();
  }
  int run = tsum[t] - mysum;
#pragma unroll
  for (int q = 0; q < 4; ++q) {
    if (c[q] && run < RR) {
      int a = ord[q];  // order[t*4+q]
      sel_a[run] = 2 * a;
      sel_b[run] = 2 * best_b[b * HALF + a] + 1;
    }
    run += c[q];
  }
  __syncthreads();
  const int cnt = min(tsum[255], RR);
  if (t >= cnt) { sel_a[t] = sel_a[0]; sel_b[t] = sel_b[0]; }
  __syncthreads();
  {
    int ga = sel_a[t], gb = sel_b[t];
    removed[gb] = 1;
    partner[b * NN + ga] = gb;
  }
  __syncthreads();
  // exclusive prefix over keep = !removed (8 positions / thread)
  int myc = 0;
#pragma unroll
  for (int q = 0; q < 8; ++q) myc += !removed[8 * t + q];
  tsum[t] = myc;
  __syncthreads();
  for (int off = 1; off < 256; off <<= 1) {
    int v = (t >= off) ? tsum[t - off] : 0;
    __syncthreads();
    tsum[t] += v;
    __syncthreads();
  }
  int pos = tsum[t] - myc;
#pragma unroll
  for (int q = 0; q < 8; ++q) {
    int p = 8 * t + q;
    int sr = -1;
    if (!removed[p]) {
      if (pos < NM) {
        keep_idx[b * NM + pos] = p;
        sr = pos;
      }
      ++pos;
    }
    src_row[b * NN + p] = sr;
  }
  __syncthreads();
  src_row[b * NN + sel_b[t]] = src_row[b * NN + sel_a[t]];
}

// ---------------------------------------------------------------------------
// Merge -> bf16 x_mb
// ---------------------------------------------------------------------------
__global__ __launch_bounds__(256) void merge_kernel(
    const float* __restrict__ x, const int* __restrict__ keep_idx,
    const int* __restrict__ partner, __bf16* __restrict__ x_mb) {
  const int mrow = blockIdx.x;
  const int b = mrow / NM;
  const int t = mrow % NM;
  const int p = keep_idx[b * NM + t];
  const int pp = partner[b * NN + p];
  const float4* src =
      reinterpret_cast<const float4*>(x + ((size_t)b * NN + p) * DM);
  float4 val = src[threadIdx.x];
  if (pp >= 0) {
    const float4* s2 =
        reinterpret_cast<const float4*>(x + ((size_t)b * NN + pp) * DM);
    float4 v2 = s2[threadIdx.x];
    val.x = 0.5f * (val.x + v2.x);
    val.y = 0.5f * (val.y + v2.y);
    val.z = 0.5f * (val.z + v2.z);
    val.w = 0.5f * (val.w + v2.w);
  }
  union { __bf16 h[4]; uint2 u; } U;
  U.h[0] = (__bf16)val.x;
  U.h[1] = (__bf16)val.y;
  U.h[2] = (__bf16)val.z;
  U.h[3] = (__bf16)val.w;
  ((uint2*)(x_mb + (size_t)mrow * DM))[threadIdx.x] = U.u;
}

// ---------------------------------------------------------------------------
// RoPE + head-major repack + bf16 convert.
// ---------------------------------------------------------------------------
__global__ void rope_repack(const float* __restrict__ src,
                            const float* __restrict__ fc,
                            __bf16* __restrict__ dst, int heads, float scale) {
  const int row = blockIdx.x;
  const int t = row % NM;
  const int b = row / NM;
  const int npairs = heads * 32;
  for (int idx = threadIdx.x; idx < npairs; idx += blockDim.x) {
    int h = idx >> 5, u = idx & 31;
    float c = fc[(t * 32 + u) * 2];
    float s = fc[(t * 32 + u) * 2 + 1];
    const float* p = src + (size_t)row * heads * 64 + h * 64 + 2 * u;
    float x1 = p[0], x2 = p[1];
    __bf16* d = dst + ((size_t)(b * heads + h) * NM + t) * 64 + 2 * u;
    d[0] = (__bf16)((x1 * c - x2 * s) * scale);
    d[1] = (__bf16)((x1 * s + x2 * c) * scale);
  }
}

// ---------------------------------------------------------------------------
// V repack: fp32 [b, n, kvh, 64] -> bf16 transposed [b, kvh, 64, NM]
// ---------------------------------------------------------------------------
__global__ __launch_bounds__(256) void v_repack(const float* __restrict__ vb,
                                                __bf16* __restrict__ vtb) {
  __shared__ float ld[64][65];
  int bid = blockIdx.x;
  const int kt = bid % (NM / 64); bid /= (NM / 64);
  const int kvh = bid % NKV;
  const int b = bid / NKV;
  const int j0 = kt * 64;
  for (int t2 = threadIdx.x; t2 < 1024; t2 += 256) {
    int key = t2 >> 4, c4 = t2 & 15;
    float4 v4 = *reinterpret_cast<const float4*>(
        vb + (((size_t)(b * NM + j0 + key)) * NKV + kvh) * 64 + c4 * 4);
    ld[key][c4 * 4 + 0] = v4.x;
    ld[key][c4 * 4 + 1] = v4.y;
    ld[key][c4 * 4 + 2] = v4.z;
    ld[key][c4 * 4 + 3] = v4.w;
  }
  __syncthreads();
  const int dim = threadIdx.x >> 2, kc = threadIdx.x & 3;
  __bf16* out = vtb + ((size_t)(b * NKV + kvh) * 64 + dim) * NM + j0 + kc * 16;
#pragma unroll
  for (int kk = 0; kk < 16; ++kk) out[kk] = (__bf16)ld[kc * 16 + kk][dim];
}

// ---------------------------------------------------------------------------
// Flash attention, bf16 MFMA, S^T orientation (conflict-free LDS).
// ---------------------------------------------------------------------------
__global__ __launch_bounds__(256) void attn_mfma(
    const __bf16* __restrict__ qbh,  // [b, h, n, 64], pre-scaled by 0.125
    const __bf16* __restrict__ kbh,  // [b, kvh, n, 64]
    const __bf16* __restrict__ vtb,  // [b, kvh, 64, NM]
    __bf16* __restrict__ attn_ob) {  // [b, n, 1024]
  __shared__ __align__(16) __bf16 Ks[4096];
  __shared__ __align__(16) __bf16 Vs[4096];
  int bid = blockIdx.x;
  const int qt = bid % (NM / 16); bid /= (NM / 16);
  const int kvh = bid % NKV;
  const int b = bid / NKV;
  const int w = threadIdx.x >> 6;
  const int lane = threadIdx.x & 63;
  const int h = kvh * 4 + w;
  const int g = lane >> 4;
  const int ml = lane & 15;

  const __bf16* qrow = qbh + ((size_t)(b * NH + h) * NM + qt * 16 + ml) * 64;
  bf16x8 qa0 = *reinterpret_cast<const bf16x8*>(qrow + g * 8);
  bf16x8 qa1 = *reinterpret_cast<const bf16x8*>(qrow + 32 + g * 8);

  f32x4 acc[4];
#pragma unroll
  for (int mt = 0; mt < 4; ++mt) acc[mt] = (f32x4){0.f, 0.f, 0.f, 0.f};
  float mstate = -1e30f, lstate = 0.f;

  const __bf16* kp = kbh + (size_t)(b * NKV + kvh) * NM * 64;
  const __bf16* vp = vtb + (size_t)(b * NKV + kvh) * 64 * NM;
  const int src0 = ((lane >> 4) & 1) * 32 + ml;
  const int src1 = src0 + 16;
  const int sel = g >> 1;

  for (int jt = 0; jt < NM / 64; ++jt) {
    __syncthreads();
#pragma unroll
    for (int t2 = threadIdx.x; t2 < 512; t2 += 256) {
      const int blk = t2 >> 7, s = (t2 >> 6) & 1, l = t2 & 63;
      *(float4*)&Ks[t2 * 8] = *(const float4*)(
          kp + (size_t)(jt * 64 + blk * 16 + (l & 15)) * 64 + s * 32 +
          ((l >> 4) << 3));
      *(float4*)&Vs[t2 * 8] = *(const float4*)(
          vp + (size_t)(blk * 16 + (l & 15)) * NM + jt * 64 + s * 32 +
          ((l >> 4) << 3));
    }
    __syncthreads();
    f32x4 S[4];
#pragma unroll
    for (int nt = 0; nt < 4; ++nt) {
      bf16x8 k0 = *(const bf16x8*)&Ks[(nt * 128 + lane) * 8];
      bf16x8 k1 = *(const bf16x8*)&Ks[(nt * 128 + 64 + lane) * 8];
      f32x4 s4 = (f32x4){0.f, 0.f, 0.f, 0.f};
      s4 = __builtin_amdgcn_mfma_f32_16x16x32_bf16(k0, qa0, s4, 0, 0, 0);
      s4 = __builtin_amdgcn_mfma_f32_16x16x32_bf16(k1, qa1, s4, 0, 0, 0);
      S[nt] = s4;
    }
    float mx = S[0][0];
#pragma unroll
    for (int nt = 0; nt < 4; ++nt)
#pragma unroll
      for (int r = 0; r < 4; ++r) mx = fmaxf(mx, S[nt][r]);
    mx = fmaxf(mx, __shfl_xor(mx, 16, 64));
    mx = fmaxf(mx, __shfl_xor(mx, 32, 64));
    float mnew = fmaxf(mstate, mx);
    float alpha = __expf(mstate - mnew);
    float p[4][4];
    float rs = 0.f;
#pragma unroll
    for (int nt = 0; nt < 4; ++nt)
#pragma unroll
      for (int r = 0; r < 4; ++r) {
        p[nt][r] = __expf(S[nt][r] - mnew);
        rs += p[nt][r];
      }
    rs += __shfl_xor(rs, 16, 64);
    rs += __shfl_xor(rs, 32, 64);
    lstate = lstate * alpha + rs;
    mstate = mnew;
#pragma unroll
    for (int mt = 0; mt < 4; ++mt) {
      acc[mt][0] *= alpha; acc[mt][1] *= alpha;
      acc[mt][2] *= alpha; acc[mt][3] *= alpha;
    }
    unsigned pk[4][2];
#pragma unroll
    for (int nt = 0; nt < 4; ++nt) {
      pk[nt][0] = pk2(p[nt][0], p[nt][1]);
      pk[nt][1] = pk2(p[nt][2], p[nt][3]);
    }
    unsigned A00 = shu(pk[0][0], src0), A01 = shu(pk[0][1], src0);
    unsigned A10 = shu(pk[1][0], src0), A11 = shu(pk[1][1], src0);
    unsigned B00 = shu(pk[0][0], src1), B01 = shu(pk[0][1], src1);
    unsigned B10 = shu(pk[1][0], src1), B11 = shu(pk[1][1], src1);
    unsigned C00 = shu(pk[2][0], src0), C01 = shu(pk[2][1], src0);
    unsigned C10 = shu(pk[3][0], src0), C11 = shu(pk[3][1], src0);
    unsigned D00 = shu(pk[2][0], src1), D01 = shu(pk[2][1], src1);
    unsigned D10 = shu(pk[3][0], src1), D11 = shu(pk[3][1], src1);
    union { uint4 u; bf16x8 v; } P0, P1;
    P0.u.x = sel ? A10 : A00; P0.u.y = sel ? A11 : A01;
    P0.u.z = sel ? B10 : B00; P0.u.w = sel ? B11 : B01;
    P1.u.x = sel ? C10 : C00; P1.u.y = sel ? C11 : C01;
    P1.u.z = sel ? D10 : D00; P1.u.w = sel ? D11 : D01;
#pragma unroll
    for (int mt = 0; mt < 4; ++mt) {
      bf16x8 v0 = *(const bf16x8*)&Vs[(mt * 128 + lane) * 8];
      bf16x8 v1 = *(const bf16x8*)&Vs[(mt * 128 + 64 + lane) * 8];
      acc[mt] = __builtin_amdgcn_mfma_f32_16x16x32_bf16(v0, P0.v, acc[mt], 0, 0, 0);
      acc[mt] = __builtin_amdgcn_mfma_f32_16x16x32_bf16(v1, P1.v, acc[mt], 0, 0, 0);
    }
  }
  float invl = 1.f / lstate;
#pragma unroll
  for (int mt = 0; mt < 4; ++mt) {
    unsigned lo = pk2(acc[mt][0] * invl, acc[mt][1] * invl);
    unsigned hi = pk2(acc[mt][2] * invl, acc[mt][3] * invl);
    size_t off =
        ((size_t)(b * NM) + qt * 16 + ml) * DM + h * 64 + mt * 16 + g * 4;
    uint2 u; u.x = lo; u.y = hi;
    *reinterpret_cast<uint2*>(attn_ob + off) = u;
  }
}

// ---------------------------------------------------------------------------
// Unmerge scatter
// ---------------------------------------------------------------------------
__global__ __launch_bounds__(256) void scatter_out(
    const float* __restrict__ out_m, const int* __restrict__ src_row,
    float* __restrict__ out) {
  const int row = blockIdx.x;
  const int b = row >> 11;
  const int p = row & (NN - 1);
  const int sr = src_row[b * NN + p];
  float4 val = make_float4(0.f, 0.f, 0.f, 0.f);
  if (sr >= 0)
    val = reinterpret_cast<const float4*>(out_m +
                                          ((size_t)(b * NM + sr)) * DM)[threadIdx.x];
  reinterpret_cast<float4*>(out + (size_t)row * DM)[threadIdx.x] = val;
}

// ---------------------------------------------------------------------------
extern "C" void kernel_launch(void* const* d_in, const int* in_sizes, int n_in,
                              void* d_out, int out_size, void* d_ws,
                              size_t ws_size, hipStream_t stream) {
  const float* x = (const float*)d_in[0];
  const float* fc = (const float*)d_in[1];
  const float* Wq = (const float*)d_in[2];
  const float* Wk = (const float*)d_in[3];
  const float* Wv = (const float*)d_in[4];
  const float* Wo = (const float*)d_in[5];
  float* out = (float*)d_out;

  char* ws = (char*)d_ws;
  size_t off = 0;
  auto alloc = [&](size_t bytes) {
    void* p = ws + off;
    off += (bytes + 255) & ~(size_t)255;
    return p;
  };
  float* metric = (float*)alloc((size_t)BB * NN * 256 * 4);
  float* best_s = (float*)alloc((size_t)BB * HALF * 4);
  int* best_b = (int*)alloc((size_t)BB * HALF * 4);
  int* order = (int*)alloc((size_t)BB * HALF * 4);
  int* keep_idx = (int*)alloc((size_t)BB * NM * 4);
  int* src_row = (int*)alloc((size_t)BB * NN * 4);
  int* partner = (int*)alloc((size_t)BB * NN * 4);
  char* bigreg = (char*)alloc((size_t)18 * 1024 * 1024);
  __bf16* xh = (__bf16*)bigreg;
  __bf16* xl = (__bf16*)(bigreg + (size_t)9 * 1024 * 1024);
  float* qb = (float*)bigreg;
  float* out_m = (float*)bigreg;
  __bf16* x_mb = (__bf16*)alloc((size_t)BB * NM * DM * 2);
  float* kb = (float*)alloc((size_t)BB * NM * NKV * HD * 4);
  float* vb = (float*)alloc((size_t)BB * NM * NKV * HD * 4);
  __bf16* qbh = (__bf16*)alloc((size_t)BB * NH * NM * 64 * 2);
  __bf16* kbh = (__bf16*)alloc((size_t)BB * NKV * NM * 64 * 2);
  __bf16* vtb = (__bf16*)alloc((size_t)BB * NKV * 64 * NM * 2);
  __bf16* attn_ob = (__bf16*)alloc((size_t)BB * NM * DM * 2);
  __bf16* Wqt = (__bf16*)alloc((size_t)DM * DM * 2);
  __bf16* Wkth = (__bf16*)alloc((size_t)256 * DM * 2);
  __bf16* Wktl = (__bf16*)alloc((size_t)256 * DM * 2);
  __bf16* Wvt = (__bf16*)alloc((size_t)256 * DM * 2);
  __bf16* Wot = (__bf16*)alloc((size_t)DM * DM * 2);

  // ---- weight/input converts
  hilo_split<<<(BB * NN * DM / 4) / 256, 256, 0, stream>>>(x, xh, xl);
  transpose_hilo<<<dim3(16, 4), 256, 0, stream>>>(Wk, Wkth, Wktl, DM, 256);
  transpose_bf16<<<dim3(16, 16), 256, 0, stream>>>(Wq, Wqt, DM, DM);
  transpose_bf16<<<dim3(16, 4), 256, 0, stream>>>(Wv, Wvt, DM, 256);
  transpose_bf16<<<dim3(16, 16), 256, 0, stream>>>(Wo, Wot, DM, DM);
  // ---- metric = x @ Wk (fp32-accurate via bf16 hi/lo split, 3 passes)
  gemm_bf16<<<dim3(64, 4), 256, 0, stream>>>(xh, Wkth, metric, BB * NN, 256, DM, 0);
  gemm_bf16<<<dim3(64, 4), 256, 0, stream>>>(xh, Wktl, metric, BB * NN, 256, DM, 1);
  gemm_bf16<<<dim3(64, 4), 256, 0, stream>>>(xl, Wkth, metric, BB * NN, 256, DM, 1);
  // ---- selection (fp32, exact)
  normalize_rows<<<BB * NN, 256, 0, stream>>>(metric);
  scores_argmax<<<dim3(HALF / 8, BB), 256, 0, stream>>>(metric, best_s, best_b);
  sort_desc<<<BB, 512, 0, stream>>>(best_s, order);
  select_and_index<<<BB, 256, 0, stream>>>(best_b, order, keep_idx, src_row,
                                           partner);
  merge_kernel<<<BB * NM, 256, 0, stream>>>(x, keep_idx, partner, x_mb);
  // ---- projections (bf16 MFMA)
  gemm_bf16<<<dim3(56, 16), 256, 0, stream>>>(x_mb, Wqt, qb, BB * NM, DM, DM, 0);
  gemm_bf16<<<dim3(56, 4), 256, 0, stream>>>(x_mb, Wkth, kb, BB * NM, 256, DM, 0);
  gemm_bf16<<<dim3(56, 4), 256, 0, stream>>>(x_mb, Wvt, vb, BB * NM, 256, DM, 0);
  // ---- RoPE + repack
  rope_repack<<<BB * NM, 256, 0, stream>>>(qb, fc, qbh, NH, 0.125f);
  rope_repack<<<BB * NM, 128, 0, stream>>>(kb, fc, kbh, NKV, 1.0f);
  v_repack<<<BB * NKV * (NM / 64), 256, 0, stream>>>(vb, vtb);
  // ---- attention
  attn_mfma<<<BB * NKV * (NM / 16), 256, 0, stream>>>(qbh, kbh, vtb, attn_ob);
  // ---- output projection + unmerge
  gemm_bf16<<<dim3(56, 16), 256, 0, stream>>>(attn_ob, Wot, out_m, BB * NM, DM,
                                              DM, 0);
  scatter_out<<<BB * NN, 256, 0, stream>>>(out_m, src_row, out);
}

// Round 7
// 379.531 us; speedup vs baseline: 17.3027x; 1.2615x over previous
//
#include <hip/hip_runtime.h>
#include <hip/hip_bf16.h>
#include <math.h>

// Problem constants
#define BB 2
#define NN 2048
#define DM 1024
#define NH 16
#define NKV 4
#define HD 64
#define RR 256
#define HALF 1024
#define NM 1792   // NN - RR
#define NT 28     // key tiles of 64
#define NSPL 2    // attention split-K

typedef __bf16 bf16x8 __attribute__((ext_vector_type(8)));
typedef float f32x4 __attribute__((ext_vector_type(4)));

__device__ inline unsigned pk2(float a, float b) {
  union { __bf16 h; unsigned short u; } ua, ub;
  ua.h = (__bf16)a;
  ub.h = (__bf16)b;
  return (unsigned)ua.u | ((unsigned)ub.u << 16);
}

__device__ inline unsigned shu(unsigned v, int s) {
  return (unsigned)__shfl((int)v, s, 64);
}

// ---------------------------------------------------------------------------
// bf16 MFMA GEMM: C[M x N] = A[M x K] @ Bt[N x K]^T.  BM=BN=BK=64.
// Fragment-linear LDS (lane*16B reads).
// ---------------------------------------------------------------------------
__global__ __launch_bounds__(256) void gemm_bf16(
    const __bf16* __restrict__ A, const __bf16* __restrict__ Bt,
    float* __restrict__ C, int M, int N, int K) {
  __shared__ __align__(16) __bf16 As[4096];
  __shared__ __align__(16) __bf16 Bs[4096];
  const int bm0 = blockIdx.x * 64;
  const int bn0 = blockIdx.y * 64;
  const int w = threadIdx.x >> 6;
  const int lane = threadIdx.x & 63;
  f32x4 acc[4];
#pragma unroll
  for (int nt = 0; nt < 4; ++nt) acc[nt] = (f32x4){0.f, 0.f, 0.f, 0.f};
  for (int kk = 0; kk < K; kk += 64) {
    __syncthreads();
#pragma unroll
    for (int t2 = threadIdx.x; t2 < 512; t2 += 256) {
      const int blk = t2 >> 7, s = (t2 >> 6) & 1, l = t2 & 63;
      const int kc = kk + s * 32 + ((l >> 4) << 3);
      *(float4*)&As[t2 * 8] =
          *(const float4*)(A + (size_t)(bm0 + blk * 16 + (l & 15)) * K + kc);
      *(float4*)&Bs[t2 * 8] =
          *(const float4*)(Bt + (size_t)(bn0 + blk * 16 + (l & 15)) * K + kc);
    }
    __syncthreads();
#pragma unroll
    for (int s = 0; s < 2; ++s) {
      bf16x8 a = *(const bf16x8*)&As[((w * 2 + s) * 64 + lane) * 8];
#pragma unroll
      for (int nt = 0; nt < 4; ++nt) {
        bf16x8 bfr = *(const bf16x8*)&Bs[((nt * 2 + s) * 64 + lane) * 8];
        acc[nt] =
            __builtin_amdgcn_mfma_f32_16x16x32_bf16(a, bfr, acc[nt], 0, 0, 0);
      }
    }
  }
  const int g = lane >> 4, ml = lane & 15;
#pragma unroll
  for (int nt = 0; nt < 4; ++nt)
#pragma unroll
    for (int r = 0; r < 4; ++r)
      C[(size_t)(bm0 + w * 16 + g * 4 + r) * N + bn0 + nt * 16 + ml] =
          acc[nt][r];
}

// ---------------------------------------------------------------------------
// fp32-accurate MFMA GEMM via on-the-fly bf16 hi/lo split (3 MFMAs/fragment).
// C[z] = A[z][M x K] @ Bt[z][N x K]^T.  Inputs fp32.
// ---------------------------------------------------------------------------
__global__ __launch_bounds__(256) void gemm_hilo(
    const float* __restrict__ A, const float* __restrict__ Bt,
    float* __restrict__ C, int M, int N, int K,
    size_t sA, size_t sB, size_t sC) {
  __shared__ __align__(16) __bf16 Ah[4096], Al[4096], Bh[4096], Bl[4096];
  A += blockIdx.z * sA;
  Bt += blockIdx.z * sB;
  C += blockIdx.z * sC;
  const int bm0 = blockIdx.x * 64;
  const int bn0 = blockIdx.y * 64;
  const int w = threadIdx.x >> 6;
  const int lane = threadIdx.x & 63;
  f32x4 acc[4];
#pragma unroll
  for (int nt = 0; nt < 4; ++nt) acc[nt] = (f32x4){0.f, 0.f, 0.f, 0.f};
  for (int kk = 0; kk < K; kk += 64) {
    __syncthreads();
#pragma unroll
    for (int t2 = threadIdx.x; t2 < 512; t2 += 256) {
      const int blk = t2 >> 7, s = (t2 >> 6) & 1, l = t2 & 63;
      const int row = bm0 + blk * 16 + (l & 15);
      const int rowB = bn0 + blk * 16 + (l & 15);
      const int col = kk + s * 32 + ((l >> 4) << 3);
      {
        float4 f0 = *(const float4*)(A + (size_t)row * K + col);
        float4 f1 = *(const float4*)(A + (size_t)row * K + col + 4);
        float ff[8] = {f0.x, f0.y, f0.z, f0.w, f1.x, f1.y, f1.z, f1.w};
        union { __bf16 h[8]; float4 q; } H, L;
#pragma unroll
        for (int j = 0; j < 8; ++j) {
          __bf16 hh = (__bf16)ff[j];
          H.h[j] = hh;
          L.h[j] = (__bf16)(ff[j] - (float)hh);
        }
        *(float4*)&Ah[t2 * 8] = H.q;
        *(float4*)&Al[t2 * 8] = L.q;
      }
      {
        float4 f0 = *(const float4*)(Bt + (size_t)rowB * K + col);
        float4 f1 = *(const float4*)(Bt + (size_t)rowB * K + col + 4);
        float ff[8] = {f0.x, f0.y, f0.z, f0.w, f1.x, f1.y, f1.z, f1.w};
        union { __bf16 h[8]; float4 q; } H, L;
#pragma unroll
        for (int j = 0; j < 8; ++j) {
          __bf16 hh = (__bf16)ff[j];
          H.h[j] = hh;
          L.h[j] = (__bf16)(ff[j] - (float)hh);
        }
        *(float4*)&Bh[t2 * 8] = H.q;
        *(float4*)&Bl[t2 * 8] = L.q;
      }
    }
    __syncthreads();
#pragma unroll
    for (int s = 0; s < 2; ++s) {
      bf16x8 ah = *(const bf16x8*)&Ah[((w * 2 + s) * 64 + lane) * 8];
      bf16x8 al = *(const bf16x8*)&Al[((w * 2 + s) * 64 + lane) * 8];
#pragma unroll
      for (int nt = 0; nt < 4; ++nt) {
        bf16x8 bh = *(const bf16x8*)&Bh[((nt * 2 + s) * 64 + lane) * 8];
        bf16x8 bl = *(const bf16x8*)&Bl[((nt * 2 + s) * 64 + lane) * 8];
        acc[nt] = __builtin_amdgcn_mfma_f32_16x16x32_bf16(al, bh, acc[nt], 0, 0, 0);
        acc[nt] = __builtin_amdgcn_mfma_f32_16x16x32_bf16(ah, bl, acc[nt], 0, 0, 0);
        acc[nt] = __builtin_amdgcn_mfma_f32_16x16x32_bf16(ah, bh, acc[nt], 0, 0, 0);
      }
    }
  }
  const int g = lane >> 4, ml = lane & 15;
#pragma unroll
  for (int nt = 0; nt < 4; ++nt)
#pragma unroll
    for (int r = 0; r < 4; ++r)
      C[(size_t)(bm0 + w * 16 + g * 4 + r) * N + bn0 + nt * 16 + ml] =
          acc[nt][r];
}

// ---------------------------------------------------------------------------
// Wk [1024 x 256] fp32 -> Wkt fp32 [256 x 1024] + bf16 copy
// ---------------------------------------------------------------------------
__global__ __launch_bounds__(256) void transpose_wk(
    const float* __restrict__ W, float* __restrict__ Wtf,
    __bf16* __restrict__ Wtb) {
  __shared__ float ld[64][65];
  const int k0 = blockIdx.x * 64, n0 = blockIdx.y * 64;
  for (int i = threadIdx.x; i < 1024; i += 256) {
    int r = i >> 4, c4 = i & 15;
    float4 v = *(const float4*)(W + (size_t)(k0 + r) * 256 + n0 + c4 * 4);
    ld[r][c4 * 4 + 0] = v.x;
    ld[r][c4 * 4 + 1] = v.y;
    ld[r][c4 * 4 + 2] = v.z;
    ld[r][c4 * 4 + 3] = v.w;
  }
  __syncthreads();
  for (int i = threadIdx.x; i < 4096; i += 256) {
    int n = i >> 6, k = i & 63;
    float v = ld[k][n];
    Wtf[(size_t)(n0 + n) * 1024 + k0 + k] = v;
    Wtb[(size_t)(n0 + n) * 1024 + k0 + k] = (__bf16)v;
  }
}

// ---------------------------------------------------------------------------
// W [K x N] fp32 -> Wt [N x K] bf16
// ---------------------------------------------------------------------------
__global__ __launch_bounds__(256) void transpose_bf16(
    const float* __restrict__ W, __bf16* __restrict__ Wt, int K, int N) {
  __shared__ float ld[64][65];
  const int k0 = blockIdx.x * 64, n0 = blockIdx.y * 64;
  for (int i = threadIdx.x; i < 1024; i += 256) {
    int r = i >> 4, c4 = i & 15;
    float4 v = *(const float4*)(W + (size_t)(k0 + r) * N + n0 + c4 * 4);
    ld[r][c4 * 4 + 0] = v.x;
    ld[r][c4 * 4 + 1] = v.y;
    ld[r][c4 * 4 + 2] = v.z;
    ld[r][c4 * 4 + 3] = v.w;
  }
  __syncthreads();
  for (int i = threadIdx.x; i < 4096; i += 256) {
    int n = i >> 6, k = i & 63;
    Wt[(size_t)(n0 + n) * K + k0 + k] = (__bf16)ld[k][n];
  }
}

// ---------------------------------------------------------------------------
// Normalize metric rows; split even rows -> an, odd rows -> bn (fp32)
// ---------------------------------------------------------------------------
__global__ __launch_bounds__(256) void normalize_split(
    const float* __restrict__ m, float* __restrict__ an,
    float* __restrict__ bn) {
  const int row = blockIdx.x;
  const int b = row >> 11;
  const int r = row & 2047;
  const int t = threadIdx.x;
  float v = m[(size_t)row * 256 + t];
  float ss = v * v;
#pragma unroll
  for (int o = 32; o > 0; o >>= 1) ss += __shfl_xor(ss, o, 64);
  __shared__ float wsum[4];
  if ((t & 63) == 0) wsum[t >> 6] = ss;
  __syncthreads();
  float tot = wsum[0] + wsum[1] + wsum[2] + wsum[3];
  float inv = 1.f / fmaxf(sqrtf(tot), 1e-12f);
  float* dst = (r & 1) ? bn : an;
  dst[((size_t)b * HALF + (r >> 1)) * 256 + t] = v * inv;
}

// ---------------------------------------------------------------------------
// Row argmax over scores [2][1024][1024]: wave per row, ties -> lowest j.
// ---------------------------------------------------------------------------
__global__ __launch_bounds__(256) void argmax_rows(
    const float* __restrict__ scores, float* __restrict__ best_s,
    int* __restrict__ best_b) {
  const int rid = blockIdx.x * 4 + (threadIdx.x >> 6);
  const int lane = threadIdx.x & 63;
  const float4* row = (const float4*)(scores + (size_t)rid * 1024);
  float bv = -3.4e38f;
  int bj = 0;
#pragma unroll
  for (int p = 0; p < 4; ++p) {
    float4 f = row[p * 64 + lane];
    int j0 = (p * 64 + lane) * 4;
    if (f.x > bv) { bv = f.x; bj = j0; }
    if (f.y > bv) { bv = f.y; bj = j0 + 1; }
    if (f.z > bv) { bv = f.z; bj = j0 + 2; }
    if (f.w > bv) { bv = f.w; bj = j0 + 3; }
  }
#pragma unroll
  for (int off = 1; off < 64; off <<= 1) {
    float vo = __shfl_xor(bv, off, 64);
    int jo = __shfl_xor(bj, off, 64);
    if (vo > bv || (vo == bv && jo < bj)) { bv = vo; bj = jo; }
  }
  if (lane == 0) {
    best_s[rid] = bv;
    best_b[rid] = bj;
  }
}

// ---------------------------------------------------------------------------
// Stable descending bitonic argsort of 1024 scores per batch. 512 threads.
// ---------------------------------------------------------------------------
__global__ __launch_bounds__(512) void sort_desc(const float* __restrict__ best_s,
                                                 int* __restrict__ order) {
  const int b = blockIdx.x;
  __shared__ float sv[1024];
  __shared__ int si[1024];
  for (int i = threadIdx.x; i < 1024; i += 512) {
    sv[i] = best_s[b * HALF + i];
    si[i] = i;
  }
  __syncthreads();
  for (int k = 2; k <= 1024; k <<= 1) {
    for (int j = k >> 1; j > 0; j >>= 1) {
      for (int t = threadIdx.x; t < 1024; t += 512) {
        int ixj = t ^ j;
        if (ixj > t) {
          bool dir = ((t & k) == 0);
          float va = sv[t], vb = sv[ixj];
          int ia = si[t], ib = si[ixj];
          bool before = (vb > va) || (vb == va && ib < ia);
          if (before == dir) {
            sv[t] = vb; sv[ixj] = va;
            si[t] = ib; si[ixj] = ia;
          }
        }
      }
      __syncthreads();
    }
  }
  for (int i = threadIdx.x; i < 1024; i += 512) order[b * HALF + i] = si[i];
}

// ---------------------------------------------------------------------------
// Parallel greedy selection (exact serial-scan equivalent) + index maps.
// ---------------------------------------------------------------------------
__global__ __launch_bounds__(256) void select_and_index(
    const int* __restrict__ best_b, const int* __restrict__ order,
    int* __restrict__ keep_idx, int* __restrict__ src_row,
    int* __restrict__ partner) {
  const int b = blockIdx.x;
  __shared__ int rankA[HALF];
  __shared__ int minrank[HALF];
  __shared__ int taken[HALF];
  __shared__ int sel_a[RR], sel_b[RR];
  __shared__ int removed[NN];
  __shared__ int tsum[256];
  const int t = threadIdx.x;

  for (int i = t; i < HALF; i += 256) { minrank[i] = 0x7fffffff; taken[i] = 0; }
  for (int i = t; i < NN; i += 256) {
    removed[i] = 0;
    partner[b * NN + i] = -1;
  }
  __syncthreads();
  int ord[4];
#pragma unroll
  for (int q = 0; q < 4; ++q) {
    int step = t * 4 + q;
    ord[q] = order[b * HALF + step];
    rankA[ord[q]] = step;
  }
  __syncthreads();
#pragma unroll
  for (int q = 0; q < 4; ++q) {
    int a = t * 4 + q;
    atomicMin(&minrank[best_b[b * HALF + a]], rankA[a]);
  }
  __syncthreads();
  for (int i = t; i < HALF; i += 256) {
    int mr = minrank[i];
    if (mr != 0x7fffffff) taken[mr] = 1;
  }
  __syncthreads();
  int c[4];
  int mysum = 0;
#pragma unroll
  for (int q = 0; q < 4; ++q) { c[q] = taken[t * 4 + q]; mysum += c[q]; }
  tsum[t] = mysum;
  __syncthreads();
  for (int off = 1; off < 256; off <<= 1) {
    int v = (t >= off) ? tsum[t - off] : 0;
    __syncthreads();
    tsum[t] += v;
    __syncthreads();
  }
  int run = tsum[t] - mysum;
#pragma unroll
  for (int q = 0; q < 4; ++q) {
    if (c[q] && run < RR) {
      int a = ord[q];
      sel_a[run] = 2 * a;
      sel_b[run] = 2 * best_b[b * HALF + a] + 1;
    }
    run += c[q];
  }
  __syncthreads();
  const int cnt = min(tsum[255], RR);
  if (t >= cnt) { sel_a[t] = sel_a[0]; sel_b[t] = sel_b[0]; }
  __syncthreads();
  {
    int ga = sel_a[t], gb = sel_b[t];
    removed[gb] = 1;
    partner[b * NN + ga] = gb;
  }
  __syncthreads();
  int myc = 0;
#pragma unroll
  for (int q = 0; q < 8; ++q) myc += !removed[8 * t + q];
  tsum[t] = myc;
  __syncthreads();
  for (int off = 1; off < 256; off <<= 1) {
    int v = (t >= off) ? tsum[t - off] : 0;
    __syncthreads();
    tsum[t] += v;
    __syncthreads();
  }
  int pos = tsum[t] - myc;
#pragma unroll
  for (int q = 0; q < 8; ++q) {
    int p = 8 * t + q;
    int sr = -1;
    if (!removed[p]) {
      if (pos < NM) {
        keep_idx[b * NM + pos] = p;
        sr = pos;
      }
      ++pos;
    }
    src_row[b * NN + p] = sr;
  }
  __syncthreads();
  src_row[b * NN + sel_b[t]] = src_row[b * NN + sel_a[t]];
}

// ---------------------------------------------------------------------------
// Merge -> bf16 x_mb
// ---------------------------------------------------------------------------
__global__ __launch_bounds__(256) void merge_kernel(
    const float* __restrict__ x, const int* __restrict__ keep_idx,
    const int* __restrict__ partner, __bf16* __restrict__ x_mb) {
  const int mrow = blockIdx.x;
  const int b = mrow / NM;
  const int t = mrow % NM;
  const int p = keep_idx[b * NM + t];
  const int pp = partner[b * NN + p];
  const float4* src =
      reinterpret_cast<const float4*>(x + ((size_t)b * NN + p) * DM);
  float4 val = src[threadIdx.x];
  if (pp >= 0) {
    const float4* s2 =
        reinterpret_cast<const float4*>(x + ((size_t)b * NN + pp) * DM);
    float4 v2 = s2[threadIdx.x];
    val.x = 0.5f * (val.x + v2.x);
    val.y = 0.5f * (val.y + v2.y);
    val.z = 0.5f * (val.z + v2.z);
    val.w = 0.5f * (val.w + v2.w);
  }
  union { __bf16 h[4]; uint2 u; } U;
  U.h[0] = (__bf16)val.x;
  U.h[1] = (__bf16)val.y;
  U.h[2] = (__bf16)val.z;
  U.h[3] = (__bf16)val.w;
  ((uint2*)(x_mb + (size_t)mrow * DM))[threadIdx.x] = U.u;
}

// ---------------------------------------------------------------------------
// RoPE + head-major repack + bf16 convert.
// ---------------------------------------------------------------------------
__global__ void rope_repack(const float* __restrict__ src,
                            const float* __restrict__ fc,
                            __bf16* __restrict__ dst, int heads, float scale) {
  const int row = blockIdx.x;
  const int t = row % NM;
  const int b = row / NM;
  const int npairs = heads * 32;
  for (int idx = threadIdx.x; idx < npairs; idx += blockDim.x) {
    int h = idx >> 5, u = idx & 31;
    float c = fc[(t * 32 + u) * 2];
    float s = fc[(t * 32 + u) * 2 + 1];
    const float* p = src + (size_t)row * heads * 64 + h * 64 + 2 * u;
    float x1 = p[0], x2 = p[1];
    __bf16* d = dst + ((size_t)(b * heads + h) * NM + t) * 64 + 2 * u;
    d[0] = (__bf16)((x1 * c - x2 * s) * scale);
    d[1] = (__bf16)((x1 * s + x2 * c) * scale);
  }
}

// ---------------------------------------------------------------------------
// V repack: fp32 [b, n, kvh, 64] -> bf16 transposed [b, kvh, 64, NM]
// ---------------------------------------------------------------------------
__global__ __launch_bounds__(256) void v_repack(const float* __restrict__ vb,
                                                __bf16* __restrict__ vtb) {
  __shared__ float ld[64][65];
  int bid = blockIdx.x;
  const int kt = bid % (NM / 64); bid /= (NM / 64);
  const int kvh = bid % NKV;
  const int b = bid / NKV;
  const int j0 = kt * 64;
  for (int t2 = threadIdx.x; t2 < 1024; t2 += 256) {
    int key = t2 >> 4, c4 = t2 & 15;
    float4 v4 = *reinterpret_cast<const float4*>(
        vb + (((size_t)(b * NM + j0 + key)) * NKV + kvh) * 64 + c4 * 4);
    ld[key][c4 * 4 + 0] = v4.x;
    ld[key][c4 * 4 + 1] = v4.y;
    ld[key][c4 * 4 + 2] = v4.z;
    ld[key][c4 * 4 + 3] = v4.w;
  }
  __syncthreads();
  const int dim = threadIdx.x >> 2, kc = threadIdx.x & 3;
  __bf16* out = vtb + ((size_t)(b * NKV + kvh) * 64 + dim) * NM + j0 + kc * 16;
#pragma unroll
  for (int kk = 0; kk < 16; ++kk) out[kk] = (__bf16)ld[kc * 16 + kk][dim];
}

// ---------------------------------------------------------------------------
// Flash attention, bf16 MFMA, S^T orientation, split-K over NSPL chunks.
// Partials (m, l fp32; unnormalized O in bf16) to workspace.
// ---------------------------------------------------------------------------
__global__ __launch_bounds__(256) void attn_mfma(
    const __bf16* __restrict__ qbh,  // [b, h, n, 64], pre-scaled by 0.125
    const __bf16* __restrict__ kbh,  // [b, kvh, n, 64]
    const __bf16* __restrict__ vtb,  // [b, kvh, 64, NM]
    float* __restrict__ pm, float* __restrict__ pl,
    __bf16* __restrict__ pacc) {
  __shared__ __align__(16) __bf16 Ks[4096];
  __shared__ __align__(16) __bf16 Vs[4096];
  int bid = blockIdx.x;
  const int qt = bid % (NM / 16); bid /= (NM / 16);
  const int split = bid % NSPL; bid /= NSPL;
  const int kvh = bid % NKV;
  const int b = bid / NKV;
  const int w = threadIdx.x >> 6;
  const int lane = threadIdx.x & 63;
  const int h = kvh * 4 + w;
  const int g = lane >> 4;
  const int ml = lane & 15;

  const __bf16* qrow = qbh + ((size_t)(b * NH + h) * NM + qt * 16 + ml) * 64;
  bf16x8 qa0 = *reinterpret_cast<const bf16x8*>(qrow + g * 8);
  bf16x8 qa1 = *reinterpret_cast<const bf16x8*>(qrow + 32 + g * 8);

  f32x4 acc[4];
#pragma unroll
  for (int mt = 0; mt < 4; ++mt) acc[mt] = (f32x4){0.f, 0.f, 0.f, 0.f};
  float mstate = -1e30f, lstate = 0.f;

  const __bf16* kp = kbh + (size_t)(b * NKV + kvh) * NM * 64;
  const __bf16* vp = vtb + (size_t)(b * NKV + kvh) * 64 * NM;
  const int src0 = ((lane >> 4) & 1) * 32 + ml;
  const int src1 = src0 + 16;
  const int sel = g >> 1;

  const int jt0 = split * (NT / NSPL);
  for (int jt = jt0; jt < jt0 + NT / NSPL; ++jt) {
    __syncthreads();
#pragma unroll
    for (int t2 = threadIdx.x; t2 < 512; t2 += 256) {
      const int blk = t2 >> 7, s = (t2 >> 6) & 1, l = t2 & 63;
      *(float4*)&Ks[t2 * 8] = *(const float4*)(
          kp + (size_t)(jt * 64 + blk * 16 + (l & 15)) * 64 + s * 32 +
          ((l >> 4) << 3));
      *(float4*)&Vs[t2 * 8] = *(const float4*)(
          vp + (size_t)(blk * 16 + (l & 15)) * NM + jt * 64 + s * 32 +
          ((l >> 4) << 3));
    }
    __syncthreads();
    f32x4 S[4];
#pragma unroll
    for (int nt = 0; nt < 4; ++nt) {
      bf16x8 k0 = *(const bf16x8*)&Ks[(nt * 128 + lane) * 8];
      bf16x8 k1 = *(const bf16x8*)&Ks[(nt * 128 + 64 + lane) * 8];
      f32x4 s4 = (f32x4){0.f, 0.f, 0.f, 0.f};
      s4 = __builtin_amdgcn_mfma_f32_16x16x32_bf16(k0, qa0, s4, 0, 0, 0);
      s4 = __builtin_amdgcn_mfma_f32_16x16x32_bf16(k1, qa1, s4, 0, 0, 0);
      S[nt] = s4;
    }
    float mx = S[0][0];
#pragma unroll
    for (int nt = 0; nt < 4; ++nt)
#pragma unroll
      for (int r = 0; r < 4; ++r) mx = fmaxf(mx, S[nt][r]);
    mx = fmaxf(mx, __shfl_xor(mx, 16, 64));
    mx = fmaxf(mx, __shfl_xor(mx, 32, 64));
    float mnew = fmaxf(mstate, mx);
    float alpha = __expf(mstate - mnew);
    float p[4][4];
    float rs = 0.f;
#pragma unroll
    for (int nt = 0; nt < 4; ++nt)
#pragma unroll
      for (int r = 0; r < 4; ++r) {
        p[nt][r] = __expf(S[nt][r] - mnew);
        rs += p[nt][r];
      }
    rs += __shfl_xor(rs, 16, 64);
    rs += __shfl_xor(rs, 32, 64);
    lstate = lstate * alpha + rs;
    mstate = mnew;
#pragma unroll
    for (int mt = 0; mt < 4; ++mt) {
      acc[mt][0] *= alpha; acc[mt][1] *= alpha;
      acc[mt][2] *= alpha; acc[mt][3] *= alpha;
    }
    unsigned pk[4][2];
#pragma unroll
    for (int nt = 0; nt < 4; ++nt) {
      pk[nt][0] = pk2(p[nt][0], p[nt][1]);
      pk[nt][1] = pk2(p[nt][2], p[nt][3]);
    }
    unsigned A00 = shu(pk[0][0], src0), A01 = shu(pk[0][1], src0);
    unsigned A10 = shu(pk[1][0], src0), A11 = shu(pk[1][1], src0);
    unsigned B00 = shu(pk[0][0], src1), B01 = shu(pk[0][1], src1);
    unsigned B10 = shu(pk[1][0], src1), B11 = shu(pk[1][1], src1);
    unsigned C00 = shu(pk[2][0], src0), C01 = shu(pk[2][1], src0);
    unsigned C10 = shu(pk[3][0], src0), C11 = shu(pk[3][1], src0);
    unsigned D00 = shu(pk[2][0], src1), D01 = shu(pk[2][1], src1);
    unsigned D10 = shu(pk[3][0], src1), D11 = shu(pk[3][1], src1);
    union { uint4 u; bf16x8 v; } P0, P1;
    P0.u.x = sel ? A10 : A00; P0.u.y = sel ? A11 : A01;
    P0.u.z = sel ? B10 : B00; P0.u.w = sel ? B11 : B01;
    P1.u.x = sel ? C10 : C00; P1.u.y = sel ? C11 : C01;
    P1.u.z = sel ? D10 : D00; P1.u.w = sel ? D11 : D01;
#pragma unroll
    for (int mt = 0; mt < 4; ++mt) {
      bf16x8 v0 = *(const bf16x8*)&Vs[(mt * 128 + lane) * 8];
      bf16x8 v1 = *(const bf16x8*)&Vs[(mt * 128 + 64 + lane) * 8];
      acc[mt] = __builtin_amdgcn_mfma_f32_16x16x32_bf16(v0, P0.v, acc[mt], 0, 0, 0);
      acc[mt] = __builtin_amdgcn_mfma_f32_16x16x32_bf16(v1, P1.v, acc[mt], 0, 0, 0);
    }
  }
  // write partials (unnormalized)
  const size_t row = (size_t)(b * NH + h) * NM + qt * 16 + ml;
  if (g == 0) {
    pm[row * NSPL + split] = mstate;
    pl[row * NSPL + split] = lstate;
  }
  __bf16* pa = pacc + (row * NSPL + split) * 64;
#pragma unroll
  for (int mt = 0; mt < 4; ++mt) {
    uint2 u;
    u.x = pk2(acc[mt][0], acc[mt][1]);
    u.y = pk2(acc[mt][2], acc[mt][3]);
    *reinterpret_cast<uint2*>(pa + mt * 16 + g * 4) = u;
  }
}

// ---------------------------------------------------------------------------
// Split-K combine -> bf16 attn_ob [b, n, h*64+d]
// ---------------------------------------------------------------------------
__global__ __launch_bounds__(256) void attn_combine(
    const float* __restrict__ pm, const float* __restrict__ pl,
    const __bf16* __restrict__ pacc, __bf16* __restrict__ attn_ob) {
  const size_t rid = (size_t)blockIdx.x * 4 + (threadIdx.x >> 6);
  const int d = threadIdx.x & 63;
  float m0 = pm[rid * NSPL + 0], m1 = pm[rid * NSPL + 1];
  float M = fmaxf(m0, m1);
  float w0 = __expf(m0 - M), w1 = __expf(m1 - M);
  float a0 = (float)pacc[(rid * NSPL + 0) * 64 + d];
  float a1 = (float)pacc[(rid * NSPL + 1) * 64 + d];
  float den = w0 * pl[rid * NSPL + 0] + w1 * pl[rid * NSPL + 1];
  float o = (w0 * a0 + w1 * a1) / den;
  const int q = (int)(rid % NM);
  const int h = (int)((rid / NM) % NH);
  const int b = (int)(rid / ((size_t)NM * NH));
  attn_ob[((size_t)(b * NM + q)) * DM + h * 64 + d] = (__bf16)o;
}

// ---------------------------------------------------------------------------
// Unmerge scatter
// ---------------------------------------------------------------------------
__global__ __launch_bounds__(256) void scatter_out(
    const float* __restrict__ out_m, const int* __restrict__ src_row,
    float* __restrict__ out) {
  const int row = blockIdx.x;
  const int b = row >> 11;
  const int p = row & (NN - 1);
  const int sr = src_row[b * NN + p];
  float4 val = make_float4(0.f, 0.f, 0.f, 0.f);
  if (sr >= 0)
    val = reinterpret_cast<const float4*>(out_m +
                                          ((size_t)(b * NM + sr)) * DM)[threadIdx.x];
  reinterpret_cast<float4*>(out + (size_t)row * DM)[threadIdx.x] = val;
}

// ---------------------------------------------------------------------------
extern "C" void kernel_launch(void* const* d_in, const int* in_sizes, int n_in,
                              void* d_out, int out_size, void* d_ws,
                              size_t ws_size, hipStream_t stream) {
  const float* x = (const float*)d_in[0];
  const float* fc = (const float*)d_in[1];
  const float* Wq = (const float*)d_in[2];
  const float* Wk = (const float*)d_in[3];
  const float* Wv = (const float*)d_in[4];
  const float* Wo = (const float*)d_in[5];
  float* out = (float*)d_out;

  char* ws = (char*)d_ws;
  size_t off = 0;
  auto alloc = [&](size_t bytes) {
    void* p = ws + off;
    off += (bytes + 255) & ~(size_t)255;
    return p;
  };
  float* metric = (float*)alloc((size_t)BB * NN * 256 * 4);  // 4 MB
  float* best_s = (float*)alloc((size_t)BB * HALF * 4);
  int* best_b = (int*)alloc((size_t)BB * HALF * 4);
  int* order = (int*)alloc((size_t)BB * HALF * 4);
  int* keep_idx = (int*)alloc((size_t)BB * NM * 4);
  int* src_row = (int*)alloc((size_t)BB * NN * 4);
  int* partner = (int*)alloc((size_t)BB * NN * 4);
  // big region, phase-aliased:
  //  phase A (selection): scores(8.4) | an(2.1 @9MB) | bn(2.1 @11.5MB)
  //  phase B: qb fp32 (14.3)    phase C: pacc bf16 (14.7)   phase D: out_m (14.3)
  char* bigreg = (char*)alloc((size_t)18 * 1024 * 1024);
  float* scores = (float*)bigreg;
  float* an = (float*)(bigreg + (size_t)9 * 1024 * 1024);
  float* bn = (float*)(bigreg + (size_t)(11 * 1024 + 512) * 1024);
  float* qb = (float*)bigreg;
  __bf16* pacc = (__bf16*)bigreg;
  float* out_m = (float*)bigreg;
  __bf16* x_mb = (__bf16*)alloc((size_t)BB * NM * DM * 2);
  float* kb = (float*)alloc((size_t)BB * NM * NKV * HD * 4);
  float* vb = (float*)alloc((size_t)BB * NM * NKV * HD * 4);
  __bf16* qbh = (__bf16*)alloc((size_t)BB * NH * NM * 64 * 2);
  __bf16* kbh = (__bf16*)alloc((size_t)BB * NKV * NM * 64 * 2);
  __bf16* vtb = (__bf16*)alloc((size_t)BB * NKV * 64 * NM * 2);
  __bf16* attn_ob = (__bf16*)alloc((size_t)BB * NM * DM * 2);
  float* pm = (float*)alloc((size_t)BB * NH * NM * NSPL * 4);
  float* pl = (float*)alloc((size_t)BB * NH * NM * NSPL * 4);
  float* Wktf = (float*)alloc((size_t)256 * DM * 4);
  __bf16* Wktb = (__bf16*)alloc((size_t)256 * DM * 2);
  __bf16* Wqt = (__bf16*)alloc((size_t)DM * DM * 2);
  __bf16* Wvt = (__bf16*)alloc((size_t)256 * DM * 2);
  __bf16* Wot = (__bf16*)alloc((size_t)DM * DM * 2);

  // ---- weight converts
  transpose_wk<<<dim3(16, 4), 256, 0, stream>>>(Wk, Wktf, Wktb);
  transpose_bf16<<<dim3(16, 16), 256, 0, stream>>>(Wq, Wqt, DM, DM);
  transpose_bf16<<<dim3(16, 4), 256, 0, stream>>>(Wv, Wvt, DM, 256);
  transpose_bf16<<<dim3(16, 16), 256, 0, stream>>>(Wo, Wot, DM, DM);
  // ---- metric = x @ Wk (fp32-accurate fused hi/lo MFMA, 1 pass)
  gemm_hilo<<<dim3(64, 4, 1), 256, 0, stream>>>(x, Wktf, metric, BB * NN, 256,
                                                DM, 0, 0, 0);
  // ---- selection: normalize/split, MFMA scores, argmax, sort, greedy
  normalize_split<<<BB * NN, 256, 0, stream>>>(metric, an, bn);
  gemm_hilo<<<dim3(16, 16, 2), 256, 0, stream>>>(
      an, bn, scores, HALF, HALF, 256, (size_t)HALF * 256, (size_t)HALF * 256,
      (size_t)HALF * HALF);
  argmax_rows<<<(BB * HALF) / 4, 256, 0, stream>>>(scores, best_s, best_b);
  sort_desc<<<BB, 512, 0, stream>>>(best_s, order);
  select_and_index<<<BB, 256, 0, stream>>>(best_b, order, keep_idx, src_row,
                                           partner);
  merge_kernel<<<BB * NM, 256, 0, stream>>>(x, keep_idx, partner, x_mb);
  // ---- projections (bf16 MFMA)
  gemm_bf16<<<dim3(56, 16), 256, 0, stream>>>(x_mb, Wqt, qb, BB * NM, DM, DM);
  gemm_bf16<<<dim3(56, 4), 256, 0, stream>>>(x_mb, Wktb, kb, BB * NM, 256, DM);
  gemm_bf16<<<dim3(56, 4), 256, 0, stream>>>(x_mb, Wvt, vb, BB * NM, 256, DM);
  // ---- RoPE + repack
  rope_repack<<<BB * NM, 256, 0, stream>>>(qb, fc, qbh, NH, 0.125f);
  rope_repack<<<BB * NM, 128, 0, stream>>>(kb, fc, kbh, NKV, 1.0f);
  v_repack<<<BB * NKV * (NM / 64), 256, 0, stream>>>(vb, vtb);
  // ---- attention (split-K x2) + combine
  attn_mfma<<<BB * NKV * NSPL * (NM / 16), 256, 0, stream>>>(qbh, kbh, vtb, pm,
                                                             pl, pacc);
  attn_combine<<<(BB * NH * NM) / 4, 256, 0, stream>>>(pm, pl, pacc, attn_ob);
  // ---- output projection + unmerge
  gemm_bf16<<<dim3(56, 16), 256, 0, stream>>>(attn_ob, Wot, out_m, BB * NM, DM,
                                              DM);
  scatter_out<<<BB * NN, 256, 0, stream>>>(out_m, src_row, out);
}

// Round 8
// 339.391 us; speedup vs baseline: 19.3491x; 1.1183x over previous
//
#include <hip/hip_runtime.h>
#include <hip/hip_bf16.h>
#include <math.h>

// Problem constants
#define BB 2
#define NN 2048
#define DM 1024
#define NH 16
#define NKV 4
#define HD 64
#define RR 256
#define HALF 1024
#define NM 1792   // NN - RR
#define NT 28     // key tiles of 64
#define NSPL 2    // attention split-K

typedef __bf16 bf16x8 __attribute__((ext_vector_type(8)));
typedef float f32x4 __attribute__((ext_vector_type(4)));

__device__ inline unsigned pk2(float a, float b) {
  union { __bf16 h; unsigned short u; } ua, ub;
  ua.h = (__bf16)a;
  ub.h = (__bf16)b;
  return (unsigned)ua.u | ((unsigned)ub.u << 16);
}

__device__ inline unsigned shu(unsigned v, int s) {
  return (unsigned)__shfl((int)v, s, 64);
}

// ---------------------------------------------------------------------------
// bf16 MFMA GEMM: C[M x N] = A[M x K] @ Bt[N x K]^T.  BM=BN=BK=64.
// Fragment-linear LDS (lane*16B reads).
// ---------------------------------------------------------------------------
__global__ __launch_bounds__(256) void gemm_bf16(
    const __bf16* __restrict__ A, const __bf16* __restrict__ Bt,
    float* __restrict__ C, int M, int N, int K) {
  __shared__ __align__(16) __bf16 As[4096];
  __shared__ __align__(16) __bf16 Bs[4096];
  const int bm0 = blockIdx.x * 64;
  const int bn0 = blockIdx.y * 64;
  const int w = threadIdx.x >> 6;
  const int lane = threadIdx.x & 63;
  f32x4 acc[4];
#pragma unroll
  for (int nt = 0; nt < 4; ++nt) acc[nt] = (f32x4){0.f, 0.f, 0.f, 0.f};
  for (int kk = 0; kk < K; kk += 64) {
    __syncthreads();
#pragma unroll
    for (int t2 = threadIdx.x; t2 < 512; t2 += 256) {
      const int blk = t2 >> 7, s = (t2 >> 6) & 1, l = t2 & 63;
      const int kc = kk + s * 32 + ((l >> 4) << 3);
      *(float4*)&As[t2 * 8] =
          *(const float4*)(A + (size_t)(bm0 + blk * 16 + (l & 15)) * K + kc);
      *(float4*)&Bs[t2 * 8] =
          *(const float4*)(Bt + (size_t)(bn0 + blk * 16 + (l & 15)) * K + kc);
    }
    __syncthreads();
#pragma unroll
    for (int s = 0; s < 2; ++s) {
      bf16x8 a = *(const bf16x8*)&As[((w * 2 + s) * 64 + lane) * 8];
#pragma unroll
      for (int nt = 0; nt < 4; ++nt) {
        bf16x8 bfr = *(const bf16x8*)&Bs[((nt * 2 + s) * 64 + lane) * 8];
        acc[nt] =
            __builtin_amdgcn_mfma_f32_16x16x32_bf16(a, bfr, acc[nt], 0, 0, 0);
      }
    }
  }
  const int g = lane >> 4, ml = lane & 15;
#pragma unroll
  for (int nt = 0; nt < 4; ++nt)
#pragma unroll
    for (int r = 0; r < 4; ++r)
      C[(size_t)(bm0 + w * 16 + g * 4 + r) * N + bn0 + nt * 16 + ml] =
          acc[nt][r];
}

// ---------------------------------------------------------------------------
// Wo GEMM with fused unmerge-scatter epilogue. A bf16, Bt bf16, out fp32
// scattered to [b, NN, DM] via keep_idx (primary) and dst2 (duplicate).
// ---------------------------------------------------------------------------
__global__ __launch_bounds__(256) void gemm_wo(
    const __bf16* __restrict__ A, const __bf16* __restrict__ Bt,
    const int* __restrict__ keep_idx, const int* __restrict__ dst2,
    float* __restrict__ out, int M, int N, int K) {
  __shared__ __align__(16) __bf16 As[4096];
  __shared__ __align__(16) __bf16 Bs[4096];
  const int bm0 = blockIdx.x * 64;
  const int bn0 = blockIdx.y * 64;
  const int w = threadIdx.x >> 6;
  const int lane = threadIdx.x & 63;
  f32x4 acc[4];
#pragma unroll
  for (int nt = 0; nt < 4; ++nt) acc[nt] = (f32x4){0.f, 0.f, 0.f, 0.f};
  for (int kk = 0; kk < K; kk += 64) {
    __syncthreads();
#pragma unroll
    for (int t2 = threadIdx.x; t2 < 512; t2 += 256) {
      const int blk = t2 >> 7, s = (t2 >> 6) & 1, l = t2 & 63;
      const int kc = kk + s * 32 + ((l >> 4) << 3);
      *(float4*)&As[t2 * 8] =
          *(const float4*)(A + (size_t)(bm0 + blk * 16 + (l & 15)) * K + kc);
      *(float4*)&Bs[t2 * 8] =
          *(const float4*)(Bt + (size_t)(bn0 + blk * 16 + (l & 15)) * K + kc);
    }
    __syncthreads();
#pragma unroll
    for (int s = 0; s < 2; ++s) {
      bf16x8 a = *(const bf16x8*)&As[((w * 2 + s) * 64 + lane) * 8];
#pragma unroll
      for (int nt = 0; nt < 4; ++nt) {
        bf16x8 bfr = *(const bf16x8*)&Bs[((nt * 2 + s) * 64 + lane) * 8];
        acc[nt] =
            __builtin_amdgcn_mfma_f32_16x16x32_bf16(a, bfr, acc[nt], 0, 0, 0);
      }
    }
  }
  const int g = lane >> 4, ml = lane & 15;
#pragma unroll
  for (int r = 0; r < 4; ++r) {
    const int row = bm0 + w * 16 + g * 4 + r;
    const int bb = row / NM, tt = row % NM;
    const int p1 = keep_idx[bb * NM + tt];
    const int p2 = dst2[bb * NM + tt];
#pragma unroll
    for (int nt = 0; nt < 4; ++nt) {
      const int col = bn0 + nt * 16 + ml;
      float v = acc[nt][r];
      out[((size_t)(bb * NN + p1)) * DM + col] = v;
      if (p2 >= 0) out[((size_t)(bb * NN + p2)) * DM + col] = v;
    }
  }
}

// ---------------------------------------------------------------------------
// fp32-accurate MFMA GEMM: A fp32 (split to bf16 hi/lo in-kernel),
// B pre-split bf16 (Bh, Bl). Split-K via blockIdx.z (separate outputs).
// ---------------------------------------------------------------------------
__global__ __launch_bounds__(256) void gemm_hiloA(
    const float* __restrict__ A, const __bf16* __restrict__ Bh,
    const __bf16* __restrict__ Bl, float* __restrict__ C0,
    float* __restrict__ C1, int M, int N, int K) {
  __shared__ __align__(16) __bf16 Ah[4096], Al[4096], Bhs[4096], Bls[4096];
  const int z = blockIdx.z;
  float* C = z ? C1 : C0;
  const int kof = z * (K / 2);
  const int bm0 = blockIdx.x * 64;
  const int bn0 = blockIdx.y * 64;
  const int w = threadIdx.x >> 6;
  const int lane = threadIdx.x & 63;
  f32x4 acc[4];
#pragma unroll
  for (int nt = 0; nt < 4; ++nt) acc[nt] = (f32x4){0.f, 0.f, 0.f, 0.f};
  for (int kk = kof; kk < kof + K / 2; kk += 64) {
    __syncthreads();
#pragma unroll
    for (int t2 = threadIdx.x; t2 < 512; t2 += 256) {
      const int blk = t2 >> 7, s = (t2 >> 6) & 1, l = t2 & 63;
      const int row = bm0 + blk * 16 + (l & 15);
      const int rowB = bn0 + blk * 16 + (l & 15);
      const int col = kk + s * 32 + ((l >> 4) << 3);
      {
        float4 f0 = *(const float4*)(A + (size_t)row * K + col);
        float4 f1 = *(const float4*)(A + (size_t)row * K + col + 4);
        float ff[8] = {f0.x, f0.y, f0.z, f0.w, f1.x, f1.y, f1.z, f1.w};
        union { __bf16 h[8]; float4 q; } H, L;
#pragma unroll
        for (int j = 0; j < 8; ++j) {
          __bf16 hh = (__bf16)ff[j];
          H.h[j] = hh;
          L.h[j] = (__bf16)(ff[j] - (float)hh);
        }
        *(float4*)&Ah[t2 * 8] = H.q;
        *(float4*)&Al[t2 * 8] = L.q;
      }
      *(float4*)&Bhs[t2 * 8] = *(const float4*)(Bh + (size_t)rowB * K + col);
      *(float4*)&Bls[t2 * 8] = *(const float4*)(Bl + (size_t)rowB * K + col);
    }
    __syncthreads();
#pragma unroll
    for (int s = 0; s < 2; ++s) {
      bf16x8 ah = *(const bf16x8*)&Ah[((w * 2 + s) * 64 + lane) * 8];
      bf16x8 al = *(const bf16x8*)&Al[((w * 2 + s) * 64 + lane) * 8];
#pragma unroll
      for (int nt = 0; nt < 4; ++nt) {
        bf16x8 bh = *(const bf16x8*)&Bhs[((nt * 2 + s) * 64 + lane) * 8];
        bf16x8 bl = *(const bf16x8*)&Bls[((nt * 2 + s) * 64 + lane) * 8];
        acc[nt] = __builtin_amdgcn_mfma_f32_16x16x32_bf16(al, bh, acc[nt], 0, 0, 0);
        acc[nt] = __builtin_amdgcn_mfma_f32_16x16x32_bf16(ah, bl, acc[nt], 0, 0, 0);
        acc[nt] = __builtin_amdgcn_mfma_f32_16x16x32_bf16(ah, bh, acc[nt], 0, 0, 0);
      }
    }
  }
  const int g = lane >> 4, ml = lane & 15;
#pragma unroll
  for (int nt = 0; nt < 4; ++nt)
#pragma unroll
    for (int r = 0; r < 4; ++r)
      C[(size_t)(bm0 + w * 16 + g * 4 + r) * N + bn0 + nt * 16 + ml] =
          acc[nt][r];
}

// ---------------------------------------------------------------------------
// Scores GEMM: both operands pre-split bf16 hi/lo. z = batch.
// C[z][M x N] = (Ah+Al)[z] @ (Bh+Bl)[z]^T (3-term).
// ---------------------------------------------------------------------------
__global__ __launch_bounds__(256) void gemm_sc3(
    const __bf16* __restrict__ Ah, const __bf16* __restrict__ Al,
    const __bf16* __restrict__ Bh, const __bf16* __restrict__ Bl,
    float* __restrict__ C) {
  __shared__ __align__(16) __bf16 Ahs[4096], Als[4096], Bhs[4096], Bls[4096];
  const size_t zo = (size_t)blockIdx.z * HALF * 256;
  C += (size_t)blockIdx.z * HALF * HALF;
  const int bm0 = blockIdx.x * 64;
  const int bn0 = blockIdx.y * 64;
  const int w = threadIdx.x >> 6;
  const int lane = threadIdx.x & 63;
  f32x4 acc[4];
#pragma unroll
  for (int nt = 0; nt < 4; ++nt) acc[nt] = (f32x4){0.f, 0.f, 0.f, 0.f};
  for (int kk = 0; kk < 256; kk += 64) {
    __syncthreads();
#pragma unroll
    for (int t2 = threadIdx.x; t2 < 512; t2 += 256) {
      const int blk = t2 >> 7, s = (t2 >> 6) & 1, l = t2 & 63;
      const size_t ra = zo + (size_t)(bm0 + blk * 16 + (l & 15)) * 256;
      const size_t rb = zo + (size_t)(bn0 + blk * 16 + (l & 15)) * 256;
      const int col = kk + s * 32 + ((l >> 4) << 3);
      *(float4*)&Ahs[t2 * 8] = *(const float4*)(Ah + ra + col);
      *(float4*)&Als[t2 * 8] = *(const float4*)(Al + ra + col);
      *(float4*)&Bhs[t2 * 8] = *(const float4*)(Bh + rb + col);
      *(float4*)&Bls[t2 * 8] = *(const float4*)(Bl + rb + col);
    }
    __syncthreads();
#pragma unroll
    for (int s = 0; s < 2; ++s) {
      bf16x8 ah = *(const bf16x8*)&Ahs[((w * 2 + s) * 64 + lane) * 8];
      bf16x8 al = *(const bf16x8*)&Als[((w * 2 + s) * 64 + lane) * 8];
#pragma unroll
      for (int nt = 0; nt < 4; ++nt) {
        bf16x8 bh = *(const bf16x8*)&Bhs[((nt * 2 + s) * 64 + lane) * 8];
        bf16x8 bl = *(const bf16x8*)&Bls[((nt * 2 + s) * 64 + lane) * 8];
        acc[nt] = __builtin_amdgcn_mfma_f32_16x16x32_bf16(al, bh, acc[nt], 0, 0, 0);
        acc[nt] = __builtin_amdgcn_mfma_f32_16x16x32_bf16(ah, bl, acc[nt], 0, 0, 0);
        acc[nt] = __builtin_amdgcn_mfma_f32_16x16x32_bf16(ah, bh, acc[nt], 0, 0, 0);
      }
    }
  }
  const int g = lane >> 4, ml = lane & 15;
#pragma unroll
  for (int nt = 0; nt < 4; ++nt)
#pragma unroll
    for (int r = 0; r < 4; ++r)
      C[(size_t)(bm0 + w * 16 + g * 4 + r) * HALF + bn0 + nt * 16 + ml] =
          acc[nt][r];
}

// ---------------------------------------------------------------------------
// Wk [1024 x 256] fp32 -> bf16 hi/lo transposed [256 x 1024]
// ---------------------------------------------------------------------------
__global__ __launch_bounds__(256) void transpose_wk(
    const float* __restrict__ W, __bf16* __restrict__ Wh,
    __bf16* __restrict__ Wl) {
  __shared__ float ld[64][65];
  const int k0 = blockIdx.x * 64, n0 = blockIdx.y * 64;
  for (int i = threadIdx.x; i < 1024; i += 256) {
    int r = i >> 4, c4 = i & 15;
    float4 v = *(const float4*)(W + (size_t)(k0 + r) * 256 + n0 + c4 * 4);
    ld[r][c4 * 4 + 0] = v.x;
    ld[r][c4 * 4 + 1] = v.y;
    ld[r][c4 * 4 + 2] = v.z;
    ld[r][c4 * 4 + 3] = v.w;
  }
  __syncthreads();
  for (int i = threadIdx.x; i < 4096; i += 256) {
    int n = i >> 6, k = i & 63;
    float v = ld[k][n];
    __bf16 hh = (__bf16)v;
    Wh[(size_t)(n0 + n) * 1024 + k0 + k] = hh;
    Wl[(size_t)(n0 + n) * 1024 + k0 + k] = (__bf16)(v - (float)hh);
  }
}

// ---------------------------------------------------------------------------
// W [K x N] fp32 -> Wt [N x K] bf16
// ---------------------------------------------------------------------------
__global__ __launch_bounds__(256) void transpose_bf16(
    const float* __restrict__ W, __bf16* __restrict__ Wt, int K, int N) {
  __shared__ float ld[64][65];
  const int k0 = blockIdx.x * 64, n0 = blockIdx.y * 64;
  for (int i = threadIdx.x; i < 1024; i += 256) {
    int r = i >> 4, c4 = i & 15;
    float4 v = *(const float4*)(W + (size_t)(k0 + r) * N + n0 + c4 * 4);
    ld[r][c4 * 4 + 0] = v.x;
    ld[r][c4 * 4 + 1] = v.y;
    ld[r][c4 * 4 + 2] = v.z;
    ld[r][c4 * 4 + 3] = v.w;
  }
  __syncthreads();
  for (int i = threadIdx.x; i < 4096; i += 256) {
    int n = i >> 6, k = i & 63;
    Wt[(size_t)(n0 + n) * K + k0 + k] = (__bf16)ld[k][n];
  }
}

// ---------------------------------------------------------------------------
// Normalize metric rows (sum of split-K halves); write bf16 hi/lo,
// even rows -> an*, odd rows -> bn*.
// ---------------------------------------------------------------------------
__global__ __launch_bounds__(256) void normalize_split(
    const float* __restrict__ m0, const float* __restrict__ m1,
    __bf16* __restrict__ anh, __bf16* __restrict__ anl,
    __bf16* __restrict__ bnh, __bf16* __restrict__ bnl) {
  const int row = blockIdx.x;
  const int b = row >> 11;
  const int r = row & 2047;
  const int t = threadIdx.x;
  float v = m0[(size_t)row * 256 + t] + m1[(size_t)row * 256 + t];
  float ss = v * v;
#pragma unroll
  for (int o = 32; o > 0; o >>= 1) ss += __shfl_xor(ss, o, 64);
  __shared__ float wsum[4];
  if ((t & 63) == 0) wsum[t >> 6] = ss;
  __syncthreads();
  float tot = wsum[0] + wsum[1] + wsum[2] + wsum[3];
  float inv = 1.f / fmaxf(sqrtf(tot), 1e-12f);
  float nv = v * inv;
  __bf16 hh = (__bf16)nv;
  __bf16 ll = (__bf16)(nv - (float)hh);
  size_t o = ((size_t)b * HALF + (r >> 1)) * 256 + t;
  if (r & 1) {
    bnh[o] = hh;
    bnl[o] = ll;
  } else {
    anh[o] = hh;
    anl[o] = ll;
  }
}

// ---------------------------------------------------------------------------
// Row argmax over scores [2][1024][1024]: wave per row, ties -> lowest j.
// ---------------------------------------------------------------------------
__global__ __launch_bounds__(256) void argmax_rows(
    const float* __restrict__ scores, float* __restrict__ best_s,
    int* __restrict__ best_b) {
  const int rid = blockIdx.x * 4 + (threadIdx.x >> 6);
  const int lane = threadIdx.x & 63;
  const float4* row = (const float4*)(scores + (size_t)rid * 1024);
  float bv = -3.4e38f;
  int bj = 0;
#pragma unroll
  for (int p = 0; p < 4; ++p) {
    float4 f = row[p * 64 + lane];
    int j0 = (p * 64 + lane) * 4;
    if (f.x > bv) { bv = f.x; bj = j0; }
    if (f.y > bv) { bv = f.y; bj = j0 + 1; }
    if (f.z > bv) { bv = f.z; bj = j0 + 2; }
    if (f.w > bv) { bv = f.w; bj = j0 + 3; }
  }
#pragma unroll
  for (int off = 1; off < 64; off <<= 1) {
    float vo = __shfl_xor(bv, off, 64);
    int jo = __shfl_xor(bj, off, 64);
    if (vo > bv || (vo == bv && jo < bj)) { bv = vo; bj = jo; }
  }
  if (lane == 0) {
    best_s[rid] = bv;
    best_b[rid] = bj;
  }
}

// ---------------------------------------------------------------------------
// Stable descending bitonic argsort of 1024 scores per batch. 512 threads.
// ---------------------------------------------------------------------------
__global__ __launch_bounds__(512) void sort_desc(const float* __restrict__ best_s,
                                                 int* __restrict__ order) {
  const int b = blockIdx.x;
  __shared__ float sv[1024];
  __shared__ int si[1024];
  for (int i = threadIdx.x; i < 1024; i += 512) {
    sv[i] = best_s[b * HALF + i];
    si[i] = i;
  }
  __syncthreads();
  for (int k = 2; k <= 1024; k <<= 1) {
    for (int j = k >> 1; j > 0; j >>= 1) {
      for (int t = threadIdx.x; t < 1024; t += 512) {
        int ixj = t ^ j;
        if (ixj > t) {
          bool dir = ((t & k) == 0);
          float va = sv[t], vb = sv[ixj];
          int ia = si[t], ib = si[ixj];
          bool before = (vb > va) || (vb == va && ib < ia);
          if (before == dir) {
            sv[t] = vb; sv[ixj] = va;
            si[t] = ib; si[ixj] = ia;
          }
        }
      }
      __syncthreads();
    }
  }
  for (int i = threadIdx.x; i < 1024; i += 512) order[b * HALF + i] = si[i];
}

// ---------------------------------------------------------------------------
// Parallel greedy selection (exact serial-scan equivalent) + index maps.
// Also emits dst2: for each merged row, the duplicate output position (-1
// if none) so the Wo GEMM can scatter directly.
// ---------------------------------------------------------------------------
__global__ __launch_bounds__(256) void select_and_index(
    const int* __restrict__ best_b, const int* __restrict__ order,
    int* __restrict__ keep_idx, int* __restrict__ partner,
    int* __restrict__ dst2) {
  const int b = blockIdx.x;
  __shared__ int rankA[HALF];
  __shared__ int minrank[HALF];
  __shared__ int taken[HALF];
  __shared__ int sel_a[RR], sel_b[RR];
  __shared__ int removed[NN];
  __shared__ int src_row[NN];
  __shared__ int tsum[256];
  const int t = threadIdx.x;

  for (int i = t; i < HALF; i += 256) { minrank[i] = 0x7fffffff; taken[i] = 0; }
  for (int i = t; i < NN; i += 256) {
    removed[i] = 0;
    partner[b * NN + i] = -1;
  }
  for (int i = t; i < NM; i += 256) dst2[b * NM + i] = -1;
  __syncthreads();
  int ord[4];
#pragma unroll
  for (int q = 0; q < 4; ++q) {
    int step = t * 4 + q;
    ord[q] = order[b * HALF + step];
    rankA[ord[q]] = step;
  }
  __syncthreads();
#pragma unroll
  for (int q = 0; q < 4; ++q) {
    int a = t * 4 + q;
    atomicMin(&minrank[best_b[b * HALF + a]], rankA[a]);
  }
  __syncthreads();
  for (int i = t; i < HALF; i += 256) {
    int mr = minrank[i];
    if (mr != 0x7fffffff) taken[mr] = 1;
  }
  __syncthreads();
  int c[4];
  int mysum = 0;
#pragma unroll
  for (int q = 0; q < 4; ++q) { c[q] = taken[t * 4 + q]; mysum += c[q]; }
  tsum[t] = mysum;
  __syncthreads();
  for (int off = 1; off < 256; off <<= 1) {
    int v = (t >= off) ? tsum[t - off] : 0;
    __syncthreads();
    tsum[t] += v;
    __syncthreads();
  }
  int run = tsum[t] - mysum;
#pragma unroll
  for (int q = 0; q < 4; ++q) {
    if (c[q] && run < RR) {
      int a = ord[q];
      sel_a[run] = 2 * a;
      sel_b[run] = 2 * best_b[b * HALF + a] + 1;
    }
    run += c[q];
  }
  __syncthreads();
  const int cnt = min(tsum[255], RR);
  if (t >= cnt) { sel_a[t] = sel_a[0]; sel_b[t] = sel_b[0]; }
  __syncthreads();
  {
    int ga = sel_a[t], gb = sel_b[t];
    removed[gb] = 1;
    partner[b * NN + ga] = gb;
  }
  __syncthreads();
  int myc = 0;
#pragma unroll
  for (int q = 0; q < 8; ++q) myc += !removed[8 * t + q];
  tsum[t] = myc;
  __syncthreads();
  for (int off = 1; off < 256; off <<= 1) {
    int v = (t >= off) ? tsum[t - off] : 0;
    __syncthreads();
    tsum[t] += v;
    __syncthreads();
  }
  int pos = tsum[t] - myc;
#pragma unroll
  for (int q = 0; q < 8; ++q) {
    int p = 8 * t + q;
    int sr = -1;
    if (!removed[p]) {
      if (pos < NM) {
        keep_idx[b * NM + pos] = p;
        sr = pos;
      }
      ++pos;
    }
    src_row[p] = sr;
  }
  __syncthreads();
  {
    int sr = src_row[sel_a[t]];
    dst2[b * NM + sr] = sel_b[t];
  }
}

// ---------------------------------------------------------------------------
// Merge -> bf16 x_mb
// ---------------------------------------------------------------------------
__global__ __launch_bounds__(256) void merge_kernel(
    const float* __restrict__ x, const int* __restrict__ keep_idx,
    const int* __restrict__ partner, __bf16* __restrict__ x_mb) {
  const int mrow = blockIdx.x;
  const int b = mrow / NM;
  const int t = mrow % NM;
  const int p = keep_idx[b * NM + t];
  const int pp = partner[b * NN + p];
  const float4* src =
      reinterpret_cast<const float4*>(x + ((size_t)b * NN + p) * DM);
  float4 val = src[threadIdx.x];
  if (pp >= 0) {
    const float4* s2 =
        reinterpret_cast<const float4*>(x + ((size_t)b * NN + pp) * DM);
    float4 v2 = s2[threadIdx.x];
    val.x = 0.5f * (val.x + v2.x);
    val.y = 0.5f * (val.y + v2.y);
    val.z = 0.5f * (val.z + v2.z);
    val.w = 0.5f * (val.w + v2.w);
  }
  union { __bf16 h[4]; uint2 u; } U;
  U.h[0] = (__bf16)val.x;
  U.h[1] = (__bf16)val.y;
  U.h[2] = (__bf16)val.z;
  U.h[3] = (__bf16)val.w;
  ((uint2*)(x_mb + (size_t)mrow * DM))[threadIdx.x] = U.u;
}

// ---------------------------------------------------------------------------
// Fused RoPE for q and k + head-major repack + bf16 convert.
// ---------------------------------------------------------------------------
__global__ __launch_bounds__(256) void rope_fused(
    const float* __restrict__ qb, const float* __restrict__ kb,
    const float* __restrict__ fc, __bf16* __restrict__ qbh,
    __bf16* __restrict__ kbh) {
  const int row = blockIdx.x;
  const int t = row % NM;
  const int b = row / NM;
  for (int idx = threadIdx.x; idx < 640; idx += 256) {
    int u = idx & 31;
    float c = fc[(t * 32 + u) * 2];
    float s = fc[(t * 32 + u) * 2 + 1];
    if (idx < 512) {
      int h = idx >> 5;
      const float* p = qb + (size_t)row * DM + h * 64 + 2 * u;
      float x1 = p[0], x2 = p[1];
      __bf16* d = qbh + ((size_t)(b * NH + h) * NM + t) * 64 + 2 * u;
      d[0] = (__bf16)((x1 * c - x2 * s) * 0.125f);
      d[1] = (__bf16)((x1 * s + x2 * c) * 0.125f);
    } else {
      int h = (idx - 512) >> 5;
      const float* p = kb + (size_t)row * 256 + h * 64 + 2 * u;
      float x1 = p[0], x2 = p[1];
      __bf16* d = kbh + ((size_t)(b * NKV + h) * NM + t) * 64 + 2 * u;
      d[0] = (__bf16)(x1 * c - x2 * s);
      d[1] = (__bf16)(x1 * s + x2 * c);
    }
  }
}

// ---------------------------------------------------------------------------
// V repack: fp32 [b, n, kvh, 64] -> bf16 transposed [b, kvh, 64, NM]
// ---------------------------------------------------------------------------
__global__ __launch_bounds__(256) void v_repack(const float* __restrict__ vb,
                                                __bf16* __restrict__ vtb) {
  __shared__ float ld[64][65];
  int bid = blockIdx.x;
  const int kt = bid % (NM / 64); bid /= (NM / 64);
  const int kvh = bid % NKV;
  const int b = bid / NKV;
  const int j0 = kt * 64;
  for (int t2 = threadIdx.x; t2 < 1024; t2 += 256) {
    int key = t2 >> 4, c4 = t2 & 15;
    float4 v4 = *reinterpret_cast<const float4*>(
        vb + (((size_t)(b * NM + j0 + key)) * NKV + kvh) * 64 + c4 * 4);
    ld[key][c4 * 4 + 0] = v4.x;
    ld[key][c4 * 4 + 1] = v4.y;
    ld[key][c4 * 4 + 2] = v4.z;
    ld[key][c4 * 4 + 3] = v4.w;
  }
  __syncthreads();
  const int dim = threadIdx.x >> 2, kc = threadIdx.x & 3;
  __bf16* out = vtb + ((size_t)(b * NKV + kvh) * 64 + dim) * NM + j0 + kc * 16;
#pragma unroll
  for (int kk = 0; kk < 16; ++kk) out[kk] = (__bf16)ld[kc * 16 + kk][dim];
}

// ---------------------------------------------------------------------------
// Flash attention, bf16 MFMA, S^T orientation, fixed-shift softmax (no max:
// scores bounded, exp(s) safe in fp32), split-K over NSPL, 8-wave blocks
// covering 2 q-tiles x 4 GQA heads per staged K/V tile.
// ---------------------------------------------------------------------------
__global__ __launch_bounds__(512) void attn_mfma(
    const __bf16* __restrict__ qbh,  // [b, h, n, 64], pre-scaled by 0.125
    const __bf16* __restrict__ kbh,  // [b, kvh, n, 64]
    const __bf16* __restrict__ vtb,  // [b, kvh, 64, NM]
    float* __restrict__ pl, __bf16* __restrict__ pacc) {
  __shared__ __align__(16) __bf16 Ks[4096];
  __shared__ __align__(16) __bf16 Vs[4096];
  int bid = blockIdx.x;
  const int qt2 = bid % (NM / 32); bid /= (NM / 32);
  const int split = bid % NSPL; bid /= NSPL;
  const int kvh = bid % NKV;
  const int b = bid / NKV;
  const int w = threadIdx.x >> 6;
  const int lane = threadIdx.x & 63;
  const int h = kvh * 4 + (w & 3);
  const int qt = qt2 * 32 + (w >> 2) * 16;
  const int g = lane >> 4;
  const int ml = lane & 15;

  const __bf16* qrow = qbh + ((size_t)(b * NH + h) * NM + qt + ml) * 64;
  bf16x8 qa0 = *reinterpret_cast<const bf16x8*>(qrow + g * 8);
  bf16x8 qa1 = *reinterpret_cast<const bf16x8*>(qrow + 32 + g * 8);

  f32x4 acc[4];
#pragma unroll
  for (int mt = 0; mt < 4; ++mt) acc[mt] = (f32x4){0.f, 0.f, 0.f, 0.f};
  float lsum = 0.f;

  const __bf16* kp = kbh + (size_t)(b * NKV + kvh) * NM * 64;
  const __bf16* vp = vtb + (size_t)(b * NKV + kvh) * 64 * NM;
  const int src0 = ((lane >> 4) & 1) * 32 + ml;
  const int src1 = src0 + 16;
  const int sel = g >> 1;

  const int jt0 = split * (NT / NSPL);
  for (int jt = jt0; jt < jt0 + NT / NSPL; ++jt) {
    __syncthreads();
    {
      const int t2 = threadIdx.x;  // 512 threads: 1 K chunk + 1 V chunk each
      const int blk = t2 >> 7, s = (t2 >> 6) & 1, l = t2 & 63;
      *(float4*)&Ks[t2 * 8] = *(const float4*)(
          kp + (size_t)(jt * 64 + blk * 16 + (l & 15)) * 64 + s * 32 +
          ((l >> 4) << 3));
      *(float4*)&Vs[t2 * 8] = *(const float4*)(
          vp + (size_t)(blk * 16 + (l & 15)) * NM + jt * 64 + s * 32 +
          ((l >> 4) << 3));
    }
    __syncthreads();
    f32x4 S[4];
#pragma unroll
    for (int nt = 0; nt < 4; ++nt) {
      bf16x8 k0 = *(const bf16x8*)&Ks[(nt * 128 + lane) * 8];
      bf16x8 k1 = *(const bf16x8*)&Ks[(nt * 128 + 64 + lane) * 8];
      f32x4 s4 = (f32x4){0.f, 0.f, 0.f, 0.f};
      s4 = __builtin_amdgcn_mfma_f32_16x16x32_bf16(k0, qa0, s4, 0, 0, 0);
      s4 = __builtin_amdgcn_mfma_f32_16x16x32_bf16(k1, qa1, s4, 0, 0, 0);
      S[nt] = s4;
    }
    float p[4][4];
#pragma unroll
    for (int nt = 0; nt < 4; ++nt)
#pragma unroll
      for (int r = 0; r < 4; ++r) {
        p[nt][r] = __expf(S[nt][r]);
        lsum += p[nt][r];
      }
    unsigned pk[4][2];
#pragma unroll
    for (int nt = 0; nt < 4; ++nt) {
      pk[nt][0] = pk2(p[nt][0], p[nt][1]);
      pk[nt][1] = pk2(p[nt][2], p[nt][3]);
    }
    unsigned A00 = shu(pk[0][0], src0), A01 = shu(pk[0][1], src0);
    unsigned A10 = shu(pk[1][0], src0), A11 = shu(pk[1][1], src0);
    unsigned B00 = shu(pk[0][0], src1), B01 = shu(pk[0][1], src1);
    unsigned B10 = shu(pk[1][0], src1), B11 = shu(pk[1][1], src1);
    unsigned C00 = shu(pk[2][0], src0), C01 = shu(pk[2][1], src0);
    unsigned C10 = shu(pk[3][0], src0), C11 = shu(pk[3][1], src0);
    unsigned D00 = shu(pk[2][0], src1), D01 = shu(pk[2][1], src1);
    unsigned D10 = shu(pk[3][0], src1), D11 = shu(pk[3][1], src1);
    union { uint4 u; bf16x8 v; } P0, P1;
    P0.u.x = sel ? A10 : A00; P0.u.y = sel ? A11 : A01;
    P0.u.z = sel ? B10 : B00; P0.u.w = sel ? B11 : B01;
    P1.u.x = sel ? C10 : C00; P1.u.y = sel ? C11 : C01;
    P1.u.z = sel ? D10 : D00; P1.u.w = sel ? D11 : D01;
#pragma unroll
    for (int mt = 0; mt < 4; ++mt) {
      bf16x8 v0 = *(const bf16x8*)&Vs[(mt * 128 + lane) * 8];
      bf16x8 v1 = *(const bf16x8*)&Vs[(mt * 128 + 64 + lane) * 8];
      acc[mt] = __builtin_amdgcn_mfma_f32_16x16x32_bf16(v0, P0.v, acc[mt], 0, 0, 0);
      acc[mt] = __builtin_amdgcn_mfma_f32_16x16x32_bf16(v1, P1.v, acc[mt], 0, 0, 0);
    }
  }
  // l reduction deferred to the end (no per-tile rescale with fixed shift)
  lsum += __shfl_xor(lsum, 16, 64);
  lsum += __shfl_xor(lsum, 32, 64);
  const size_t row = (size_t)(b * NH + h) * NM + qt + ml;
  if (g == 0) pl[row * NSPL + split] = lsum;
  __bf16* pa = pacc + (row * NSPL + split) * 64;
#pragma unroll
  for (int mt = 0; mt < 4; ++mt) {
    uint2 u;
    u.x = pk2(acc[mt][0], acc[mt][1]);
    u.y = pk2(acc[mt][2], acc[mt][3]);
    *reinterpret_cast<uint2*>(pa + mt * 16 + g * 4) = u;
  }
}

// ---------------------------------------------------------------------------
// Split-K combine (fixed shift: plain sums) -> bf16 attn_ob [b, n, h*64+d]
// ---------------------------------------------------------------------------
__global__ __launch_bounds__(256) void attn_combine(
    const float* __restrict__ pl, const __bf16* __restrict__ pacc,
    __bf16* __restrict__ attn_ob) {
  const size_t rid = (size_t)blockIdx.x * 4 + (threadIdx.x >> 6);
  const int d = threadIdx.x & 63;
  float a0 = (float)pacc[(rid * NSPL + 0) * 64 + d];
  float a1 = (float)pacc[(rid * NSPL + 1) * 64 + d];
  float den = pl[rid * NSPL + 0] + pl[rid * NSPL + 1];
  float o = (a0 + a1) / den;
  const int q = (int)(rid % NM);
  const int h = (int)((rid / NM) % NH);
  const int b = (int)(rid / ((size_t)NM * NH));
  attn_ob[((size_t)(b * NM + q)) * DM + h * 64 + d] = (__bf16)o;
}

// ---------------------------------------------------------------------------
extern "C" void kernel_launch(void* const* d_in, const int* in_sizes, int n_in,
                              void* d_out, int out_size, void* d_ws,
                              size_t ws_size, hipStream_t stream) {
  const float* x = (const float*)d_in[0];
  const float* fc = (const float*)d_in[1];
  const float* Wq = (const float*)d_in[2];
  const float* Wk = (const float*)d_in[3];
  const float* Wv = (const float*)d_in[4];
  const float* Wo = (const float*)d_in[5];
  float* out = (float*)d_out;

  char* ws = (char*)d_ws;
  size_t off = 0;
  auto alloc = [&](size_t bytes) {
    void* p = ws + off;
    off += (bytes + 255) & ~(size_t)255;
    return p;
  };
  float* metric0 = (float*)alloc((size_t)BB * NN * 256 * 4);
  float* metric1 = (float*)alloc((size_t)BB * NN * 256 * 4);
  float* best_s = (float*)alloc((size_t)BB * HALF * 4);
  int* best_b = (int*)alloc((size_t)BB * HALF * 4);
  int* order = (int*)alloc((size_t)BB * HALF * 4);
  int* keep_idx = (int*)alloc((size_t)BB * NM * 4);
  int* partner = (int*)alloc((size_t)BB * NN * 4);
  int* dst2 = (int*)alloc((size_t)BB * NM * 4);
  // big region, phase-aliased:
  //  A: scores(8.4MB @0) | anh/anl/bnh/bnl (1MB each @9.5..13.5MB)
  //  B: qb fp32 (14.3MB @0)    C: pacc bf16 (14.7MB @0)
  char* bigreg = (char*)alloc((size_t)18 * 1024 * 1024);
  float* scores = (float*)bigreg;
  __bf16* anh = (__bf16*)(bigreg + (size_t)9500 * 1024);
  __bf16* anl = (__bf16*)(bigreg + (size_t)10600 * 1024);
  __bf16* bnh = (__bf16*)(bigreg + (size_t)11700 * 1024);
  __bf16* bnl = (__bf16*)(bigreg + (size_t)12800 * 1024);
  float* qb = (float*)bigreg;
  __bf16* pacc = (__bf16*)bigreg;
  __bf16* x_mb = (__bf16*)alloc((size_t)BB * NM * DM * 2);
  float* kb = (float*)alloc((size_t)BB * NM * NKV * HD * 4);
  float* vb = (float*)alloc((size_t)BB * NM * NKV * HD * 4);
  __bf16* qbh = (__bf16*)alloc((size_t)BB * NH * NM * 64 * 2);
  __bf16* kbh = (__bf16*)alloc((size_t)BB * NKV * NM * 64 * 2);
  __bf16* vtb = (__bf16*)alloc((size_t)BB * NKV * 64 * NM * 2);
  __bf16* attn_ob = (__bf16*)alloc((size_t)BB * NM * DM * 2);
  float* pl = (float*)alloc((size_t)BB * NH * NM * NSPL * 4);
  __bf16* Wkth = (__bf16*)alloc((size_t)256 * DM * 2);
  __bf16* Wktl = (__bf16*)alloc((size_t)256 * DM * 2);
  __bf16* Wqt = (__bf16*)alloc((size_t)DM * DM * 2);
  __bf16* Wvt = (__bf16*)alloc((size_t)256 * DM * 2);
  __bf16* Wot = (__bf16*)alloc((size_t)DM * DM * 2);

  // ---- weight converts
  transpose_wk<<<dim3(16, 4), 256, 0, stream>>>(Wk, Wkth, Wktl);
  transpose_bf16<<<dim3(16, 16), 256, 0, stream>>>(Wq, Wqt, DM, DM);
  transpose_bf16<<<dim3(16, 4), 256, 0, stream>>>(Wv, Wvt, DM, 256);
  transpose_bf16<<<dim3(16, 16), 256, 0, stream>>>(Wo, Wot, DM, DM);
  // ---- metric = x @ Wk (fp32-accurate hi/lo MFMA, split-K x2)
  gemm_hiloA<<<dim3(64, 4, 2), 256, 0, stream>>>(x, Wkth, Wktl, metric0,
                                                 metric1, BB * NN, 256, DM);
  // ---- selection: normalize (+sum halves), MFMA scores, argmax, sort, greedy
  normalize_split<<<BB * NN, 256, 0, stream>>>(metric0, metric1, anh, anl, bnh,
                                               bnl);
  gemm_sc3<<<dim3(16, 16, 2), 256, 0, stream>>>(anh, anl, bnh, bnl, scores);
  argmax_rows<<<(BB * HALF) / 4, 256, 0, stream>>>(scores, best_s, best_b);
  sort_desc<<<BB, 512, 0, stream>>>(best_s, order);
  select_and_index<<<BB, 256, 0, stream>>>(best_b, order, keep_idx, partner,
                                           dst2);
  merge_kernel<<<BB * NM, 256, 0, stream>>>(x, keep_idx, partner, x_mb);
  // ---- projections (bf16 MFMA)
  gemm_bf16<<<dim3(56, 16), 256, 0, stream>>>(x_mb, Wqt, qb, BB * NM, DM, DM);
  gemm_bf16<<<dim3(56, 4), 256, 0, stream>>>(x_mb, Wkth, kb, BB * NM, 256, DM);
  gemm_bf16<<<dim3(56, 4), 256, 0, stream>>>(x_mb, Wvt, vb, BB * NM, 256, DM);
  // ---- RoPE (fused q+k) + V repack
  rope_fused<<<BB * NM, 256, 0, stream>>>(qb, kb, fc, qbh, kbh);
  v_repack<<<BB * NKV * (NM / 64), 256, 0, stream>>>(vb, vtb);
  // ---- attention (8-wave blocks, split-K x2) + combine
  attn_mfma<<<BB * NKV * NSPL * (NM / 32), 512, 0, stream>>>(qbh, kbh, vtb, pl,
                                                             pacc);
  attn_combine<<<(BB * NH * NM) / 4, 256, 0, stream>>>(pl, pacc, attn_ob);
  // ---- output projection with fused unmerge scatter
  gemm_wo<<<dim3(56, 16), 256, 0, stream>>>(attn_ob, Wot, keep_idx, dst2, out,
                                            BB * NM, DM, DM);
}

// Round 9
// 306.567 us; speedup vs baseline: 21.4208x; 1.1071x over previous
//
#include <hip/hip_runtime.h>
#include <hip/hip_bf16.h>
#include <math.h>

// Problem constants
#define BB 2
#define NN 2048
#define DM 1024
#define NH 16
#define NKV 4
#define HD 64
#define RR 256
#define HALF 1024
#define NM 1792   // NN - RR
#define NT 28     // key tiles of 64
#define NSPL 4    // attention split-K

typedef __bf16 bf16x8 __attribute__((ext_vector_type(8)));
typedef float f32x4 __attribute__((ext_vector_type(4)));

__device__ inline unsigned pk2(float a, float b) {
  union { __bf16 h; unsigned short u; } ua, ub;
  ua.h = (__bf16)a;
  ub.h = (__bf16)b;
  return (unsigned)ua.u | ((unsigned)ub.u << 16);
}

__device__ inline unsigned shu(unsigned v, int s) {
  return (unsigned)__shfl((int)v, s, 64);
}

// ---------------------------------------------------------------------------
// bf16 MFMA GEMM: C[M x N] = A[M x K] @ Bt[N x K]^T.  BM=BN=BK=64.
// ---------------------------------------------------------------------------
__global__ __launch_bounds__(256) void gemm_bf16(
    const __bf16* __restrict__ A, const __bf16* __restrict__ Bt,
    float* __restrict__ C, int M, int N, int K) {
  __shared__ __align__(16) __bf16 As[4096];
  __shared__ __align__(16) __bf16 Bs[4096];
  const int bm0 = blockIdx.x * 64;
  const int bn0 = blockIdx.y * 64;
  const int w = threadIdx.x >> 6;
  const int lane = threadIdx.x & 63;
  f32x4 acc[4];
#pragma unroll
  for (int nt = 0; nt < 4; ++nt) acc[nt] = (f32x4){0.f, 0.f, 0.f, 0.f};
  for (int kk = 0; kk < K; kk += 64) {
    __syncthreads();
#pragma unroll
    for (int t2 = threadIdx.x; t2 < 512; t2 += 256) {
      const int blk = t2 >> 7, s = (t2 >> 6) & 1, l = t2 & 63;
      const int kc = kk + s * 32 + ((l >> 4) << 3);
      *(float4*)&As[t2 * 8] =
          *(const float4*)(A + (size_t)(bm0 + blk * 16 + (l & 15)) * K + kc);
      *(float4*)&Bs[t2 * 8] =
          *(const float4*)(Bt + (size_t)(bn0 + blk * 16 + (l & 15)) * K + kc);
    }
    __syncthreads();
#pragma unroll
    for (int s = 0; s < 2; ++s) {
      bf16x8 a = *(const bf16x8*)&As[((w * 2 + s) * 64 + lane) * 8];
#pragma unroll
      for (int nt = 0; nt < 4; ++nt) {
        bf16x8 bfr = *(const bf16x8*)&Bs[((nt * 2 + s) * 64 + lane) * 8];
        acc[nt] =
            __builtin_amdgcn_mfma_f32_16x16x32_bf16(a, bfr, acc[nt], 0, 0, 0);
      }
    }
  }
  const int g = lane >> 4, ml = lane & 15;
#pragma unroll
  for (int nt = 0; nt < 4; ++nt)
#pragma unroll
    for (int r = 0; r < 4; ++r)
      C[(size_t)(bm0 + w * 16 + g * 4 + r) * N + bn0 + nt * 16 + ml] =
          acc[nt][r];
}

// ---------------------------------------------------------------------------
// Wo GEMM with fused unmerge-scatter epilogue.
// ---------------------------------------------------------------------------
__global__ __launch_bounds__(256) void gemm_wo(
    const __bf16* __restrict__ A, const __bf16* __restrict__ Bt,
    const int* __restrict__ keep_idx, const int* __restrict__ dst2,
    float* __restrict__ out, int M, int N, int K) {
  __shared__ __align__(16) __bf16 As[4096];
  __shared__ __align__(16) __bf16 Bs[4096];
  const int bm0 = blockIdx.x * 64;
  const int bn0 = blockIdx.y * 64;
  const int w = threadIdx.x >> 6;
  const int lane = threadIdx.x & 63;
  f32x4 acc[4];
#pragma unroll
  for (int nt = 0; nt < 4; ++nt) acc[nt] = (f32x4){0.f, 0.f, 0.f, 0.f};
  for (int kk = 0; kk < K; kk += 64) {
    __syncthreads();
#pragma unroll
    for (int t2 = threadIdx.x; t2 < 512; t2 += 256) {
      const int blk = t2 >> 7, s = (t2 >> 6) & 1, l = t2 & 63;
      const int kc = kk + s * 32 + ((l >> 4) << 3);
      *(float4*)&As[t2 * 8] =
          *(const float4*)(A + (size_t)(bm0 + blk * 16 + (l & 15)) * K + kc);
      *(float4*)&Bs[t2 * 8] =
          *(const float4*)(Bt + (size_t)(bn0 + blk * 16 + (l & 15)) * K + kc);
    }
    __syncthreads();
#pragma unroll
    for (int s = 0; s < 2; ++s) {
      bf16x8 a = *(const bf16x8*)&As[((w * 2 + s) * 64 + lane) * 8];
#pragma unroll
      for (int nt = 0; nt < 4; ++nt) {
        bf16x8 bfr = *(const bf16x8*)&Bs[((nt * 2 + s) * 64 + lane) * 8];
        acc[nt] =
            __builtin_amdgcn_mfma_f32_16x16x32_bf16(a, bfr, acc[nt], 0, 0, 0);
      }
    }
  }
  const int g = lane >> 4, ml = lane & 15;
#pragma unroll
  for (int r = 0; r < 4; ++r) {
    const int row = bm0 + w * 16 + g * 4 + r;
    const int bb = row / NM, tt = row % NM;
    const int p1 = keep_idx[bb * NM + tt];
    const int p2 = dst2[bb * NM + tt];
#pragma unroll
    for (int nt = 0; nt < 4; ++nt) {
      const int col = bn0 + nt * 16 + ml;
      float v = acc[nt][r];
      out[((size_t)(bb * NN + p1)) * DM + col] = v;
      if (p2 >= 0) out[((size_t)(bb * NN + p2)) * DM + col] = v;
    }
  }
}

// ---------------------------------------------------------------------------
// 3-term hi/lo MFMA GEMM (fp32-accurate): C = (Ah+Al)(Bh+Bl)^T dropping ll.
// Split-K via blockIdx.z (separate outputs C0/C1).
// ---------------------------------------------------------------------------
__global__ __launch_bounds__(256) void gemm3t(
    const __bf16* __restrict__ Ah, const __bf16* __restrict__ Al,
    const __bf16* __restrict__ Bh, const __bf16* __restrict__ Bl,
    float* __restrict__ C0, float* __restrict__ C1, int M, int N, int K) {
  __shared__ __align__(16) __bf16 Ahs[4096], Als[4096], Bhs[4096], Bls[4096];
  const int z = blockIdx.z;
  float* C = z ? C1 : C0;
  const int kof = z * (K / 2);
  const int bm0 = blockIdx.x * 64;
  const int bn0 = blockIdx.y * 64;
  const int w = threadIdx.x >> 6;
  const int lane = threadIdx.x & 63;
  f32x4 acc[4];
#pragma unroll
  for (int nt = 0; nt < 4; ++nt) acc[nt] = (f32x4){0.f, 0.f, 0.f, 0.f};
  for (int kk = kof; kk < kof + K / 2; kk += 64) {
    __syncthreads();
#pragma unroll
    for (int t2 = threadIdx.x; t2 < 512; t2 += 256) {
      const int blk = t2 >> 7, s = (t2 >> 6) & 1, l = t2 & 63;
      const size_t ra = (size_t)(bm0 + blk * 16 + (l & 15)) * K;
      const size_t rb = (size_t)(bn0 + blk * 16 + (l & 15)) * K;
      const int col = kk + s * 32 + ((l >> 4) << 3);
      *(float4*)&Ahs[t2 * 8] = *(const float4*)(Ah + ra + col);
      *(float4*)&Als[t2 * 8] = *(const float4*)(Al + ra + col);
      *(float4*)&Bhs[t2 * 8] = *(const float4*)(Bh + rb + col);
      *(float4*)&Bls[t2 * 8] = *(const float4*)(Bl + rb + col);
    }
    __syncthreads();
#pragma unroll
    for (int s = 0; s < 2; ++s) {
      bf16x8 ah = *(const bf16x8*)&Ahs[((w * 2 + s) * 64 + lane) * 8];
      bf16x8 al = *(const bf16x8*)&Als[((w * 2 + s) * 64 + lane) * 8];
#pragma unroll
      for (int nt = 0; nt < 4; ++nt) {
        bf16x8 bh = *(const bf16x8*)&Bhs[((nt * 2 + s) * 64 + lane) * 8];
        bf16x8 bl = *(const bf16x8*)&Bls[((nt * 2 + s) * 64 + lane) * 8];
        acc[nt] = __builtin_amdgcn_mfma_f32_16x16x32_bf16(al, bh, acc[nt], 0, 0, 0);
        acc[nt] = __builtin_amdgcn_mfma_f32_16x16x32_bf16(ah, bl, acc[nt], 0, 0, 0);
        acc[nt] = __builtin_amdgcn_mfma_f32_16x16x32_bf16(ah, bh, acc[nt], 0, 0, 0);
      }
    }
  }
  const int g = lane >> 4, ml = lane & 15;
#pragma unroll
  for (int nt = 0; nt < 4; ++nt)
#pragma unroll
    for (int r = 0; r < 4; ++r)
      C[(size_t)(bm0 + w * 16 + g * 4 + r) * N + bn0 + nt * 16 + ml] =
          acc[nt][r];
}

// ---------------------------------------------------------------------------
// Scores 3-term GEMM with fused per-tile row-argmax epilogue (no score
// materialization). z = batch. Partials: sval/sidx [z*HALF+row][16 colblocks].
// ---------------------------------------------------------------------------
__global__ __launch_bounds__(256) void gemm_scam(
    const __bf16* __restrict__ Ah, const __bf16* __restrict__ Al,
    const __bf16* __restrict__ Bh, const __bf16* __restrict__ Bl,
    float* __restrict__ sval, int* __restrict__ sidx) {
  __shared__ __align__(16) __bf16 Ahs[4096], Als[4096], Bhs[4096], Bls[4096];
  const size_t zo = (size_t)blockIdx.z * HALF * 256;
  const int bm0 = blockIdx.x * 64;
  const int bn0 = blockIdx.y * 64;
  const int w = threadIdx.x >> 6;
  const int lane = threadIdx.x & 63;
  f32x4 acc[4];
#pragma unroll
  for (int nt = 0; nt < 4; ++nt) acc[nt] = (f32x4){0.f, 0.f, 0.f, 0.f};
  for (int kk = 0; kk < 256; kk += 64) {
    __syncthreads();
#pragma unroll
    for (int t2 = threadIdx.x; t2 < 512; t2 += 256) {
      const int blk = t2 >> 7, s = (t2 >> 6) & 1, l = t2 & 63;
      const size_t ra = zo + (size_t)(bm0 + blk * 16 + (l & 15)) * 256;
      const size_t rb = zo + (size_t)(bn0 + blk * 16 + (l & 15)) * 256;
      const int col = kk + s * 32 + ((l >> 4) << 3);
      *(float4*)&Ahs[t2 * 8] = *(const float4*)(Ah + ra + col);
      *(float4*)&Als[t2 * 8] = *(const float4*)(Al + ra + col);
      *(float4*)&Bhs[t2 * 8] = *(const float4*)(Bh + rb + col);
      *(float4*)&Bls[t2 * 8] = *(const float4*)(Bl + rb + col);
    }
    __syncthreads();
#pragma unroll
    for (int s = 0; s < 2; ++s) {
      bf16x8 ah = *(const bf16x8*)&Ahs[((w * 2 + s) * 64 + lane) * 8];
      bf16x8 al = *(const bf16x8*)&Als[((w * 2 + s) * 64 + lane) * 8];
#pragma unroll
      for (int nt = 0; nt < 4; ++nt) {
        bf16x8 bh = *(const bf16x8*)&Bhs[((nt * 2 + s) * 64 + lane) * 8];
        bf16x8 bl = *(const bf16x8*)&Bls[((nt * 2 + s) * 64 + lane) * 8];
        acc[nt] = __builtin_amdgcn_mfma_f32_16x16x32_bf16(al, bh, acc[nt], 0, 0, 0);
        acc[nt] = __builtin_amdgcn_mfma_f32_16x16x32_bf16(ah, bl, acc[nt], 0, 0, 0);
        acc[nt] = __builtin_amdgcn_mfma_f32_16x16x32_bf16(ah, bh, acc[nt], 0, 0, 0);
      }
    }
  }
  // epilogue: row-argmax within this 64x64 tile (ties -> lowest col)
  const int g = lane >> 4, ml = lane & 15;
#pragma unroll
  for (int r = 0; r < 4; ++r) {
    float bv = acc[0][r];
    int bc = bn0 + ml;
#pragma unroll
    for (int nt = 1; nt < 4; ++nt) {
      float v = acc[nt][r];
      int c = bn0 + nt * 16 + ml;
      if (v > bv) { bv = v; bc = c; }
    }
#pragma unroll
    for (int off = 1; off < 16; off <<= 1) {
      float vo = __shfl_xor(bv, off, 64);
      int co = __shfl_xor(bc, off, 64);
      if (vo > bv || (vo == bv && co < bc)) { bv = vo; bc = co; }
    }
    if (ml == 0) {
      const int row = bm0 + w * 16 + g * 4 + r;
      const size_t o = ((size_t)blockIdx.z * HALF + row) * 16 + (bn0 >> 6);
      sval[o] = bv;
      sidx[o] = bc;
    }
  }
}

// ---------------------------------------------------------------------------
// Reduce 16 argmax partials per row -> best_s / best_b. 16 rows per block.
// ---------------------------------------------------------------------------
__global__ __launch_bounds__(256) void argmax_reduce(
    const float* __restrict__ sval, const int* __restrict__ sidx,
    float* __restrict__ best_s, int* __restrict__ best_b) {
  const int lane = threadIdx.x & 63;
  const int e = lane & 15;
  const int rid = blockIdx.x * 16 + (threadIdx.x >> 6) * 4 + (lane >> 4);
  float bv = sval[rid * 16 + e];
  int bc = sidx[rid * 16 + e];
#pragma unroll
  for (int off = 1; off < 16; off <<= 1) {
    float vo = __shfl_xor(bv, off, 64);
    int co = __shfl_xor(bc, off, 64);
    if (vo > bv || (vo == bv && co < bc)) { bv = vo; bc = co; }
  }
  if (e == 0) {
    best_s[rid] = bv;
    best_b[rid] = bc;
  }
}

// ---------------------------------------------------------------------------
// x -> (xh, xl) bf16 split
// ---------------------------------------------------------------------------
__global__ __launch_bounds__(256) void hilo_split(const float* __restrict__ x,
                                                  __bf16* __restrict__ xh,
                                                  __bf16* __restrict__ xl) {
  const int i = blockIdx.x * 256 + threadIdx.x;
  float4 v = ((const float4*)x)[i];
  float f[4] = {v.x, v.y, v.z, v.w};
  union { __bf16 h[4]; uint2 u; } H, L;
#pragma unroll
  for (int j = 0; j < 4; ++j) {
    __bf16 hh = (__bf16)f[j];
    H.h[j] = hh;
    L.h[j] = (__bf16)(f[j] - (float)hh);
  }
  ((uint2*)xh)[i] = H.u;
  ((uint2*)xl)[i] = L.u;
}

// ---------------------------------------------------------------------------
// Fused weight transposes: Wq/Wk/Wv -> Wqkvt concat [1536 x 1024] bf16
// (rows 0-1023 Wq^T, 1024-1279 Wk^T-hi, 1280-1535 Wv^T), Wk^T-lo -> Wktl,
// Wo -> Wot [1024 x 1024] bf16. 640 blocks.
// ---------------------------------------------------------------------------
__global__ __launch_bounds__(256) void transpose_all(
    const float* __restrict__ Wq, const float* __restrict__ Wk,
    const float* __restrict__ Wv, const float* __restrict__ Wo,
    __bf16* __restrict__ Wqkvt, __bf16* __restrict__ Wktl,
    __bf16* __restrict__ Wot) {
  __shared__ float ld[64][65];
  const int z = blockIdx.x;
  const float* src;
  __bf16* dsth;
  __bf16* dstl = nullptr;
  int N, k0, n0, rowoff;
  if (z < 256) {
    src = Wq; N = 1024; k0 = (z >> 4) << 6; n0 = (z & 15) << 6;
    dsth = Wqkvt; rowoff = 0;
  } else if (z < 320) {
    int zz = z - 256;
    src = Wk; N = 256; k0 = (zz >> 2) << 6; n0 = (zz & 3) << 6;
    dsth = Wqkvt; rowoff = 1024; dstl = Wktl;
  } else if (z < 384) {
    int zz = z - 320;
    src = Wv; N = 256; k0 = (zz >> 2) << 6; n0 = (zz & 3) << 6;
    dsth = Wqkvt; rowoff = 1280;
  } else {
    int zz = z - 384;
    src = Wo; N = 1024; k0 = (zz >> 4) << 6; n0 = (zz & 15) << 6;
    dsth = Wot; rowoff = 0;
  }
  for (int i = threadIdx.x; i < 1024; i += 256) {
    int r = i >> 4, c4 = i & 15;
    float4 v = *(const float4*)(src + (size_t)(k0 + r) * N + n0 + c4 * 4);
    ld[r][c4 * 4 + 0] = v.x;
    ld[r][c4 * 4 + 1] = v.y;
    ld[r][c4 * 4 + 2] = v.z;
    ld[r][c4 * 4 + 3] = v.w;
  }
  __syncthreads();
  for (int i = threadIdx.x; i < 4096; i += 256) {
    int n = i >> 6, k = i & 63;
    float v = ld[k][n];
    __bf16 hh = (__bf16)v;
    dsth[(size_t)(rowoff + n0 + n) * 1024 + k0 + k] = hh;
    if (dstl)
      dstl[(size_t)(n0 + n) * 1024 + k0 + k] = (__bf16)(v - (float)hh);
  }
}

// ---------------------------------------------------------------------------
// Normalize metric rows (sum of split-K halves); write bf16 hi/lo,
// even rows -> an*, odd rows -> bn*.
// ---------------------------------------------------------------------------
__global__ __launch_bounds__(256) void normalize_split(
    const float* __restrict__ m0, const float* __restrict__ m1,
    __bf16* __restrict__ anh, __bf16* __restrict__ anl,
    __bf16* __restrict__ bnh, __bf16* __restrict__ bnl) {
  const int row = blockIdx.x;
  const int b = row >> 11;
  const int r = row & 2047;
  const int t = threadIdx.x;
  float v = m0[(size_t)row * 256 + t] + m1[(size_t)row * 256 + t];
  float ss = v * v;
#pragma unroll
  for (int o = 32; o > 0; o >>= 1) ss += __shfl_xor(ss, o, 64);
  __shared__ float wsum[4];
  if ((t & 63) == 0) wsum[t >> 6] = ss;
  __syncthreads();
  float tot = wsum[0] + wsum[1] + wsum[2] + wsum[3];
  float inv = 1.f / fmaxf(sqrtf(tot), 1e-12f);
  float nv = v * inv;
  __bf16 hh = (__bf16)nv;
  __bf16 ll = (__bf16)(nv - (float)hh);
  size_t o = ((size_t)b * HALF + (r >> 1)) * 256 + t;
  if (r & 1) {
    bnh[o] = hh;
    bnl[o] = ll;
  } else {
    anh[o] = hh;
    anl[o] = ll;
  }
}

// ---------------------------------------------------------------------------
// Stable descending bitonic argsort of 1024 scores per batch. 512 threads.
// ---------------------------------------------------------------------------
__global__ __launch_bounds__(512) void sort_desc(const float* __restrict__ best_s,
                                                 int* __restrict__ order) {
  const int b = blockIdx.x;
  __shared__ float sv[1024];
  __shared__ int si[1024];
  for (int i = threadIdx.x; i < 1024; i += 512) {
    sv[i] = best_s[b * HALF + i];
    si[i] = i;
  }
  __syncthreads();
  for (int k = 2; k <= 1024; k <<= 1) {
    for (int j = k >> 1; j > 0; j >>= 1) {
      for (int t = threadIdx.x; t < 1024; t += 512) {
        int ixj = t ^ j;
        if (ixj > t) {
          bool dir = ((t & k) == 0);
          float va = sv[t], vb = sv[ixj];
          int ia = si[t], ib = si[ixj];
          bool before = (vb > va) || (vb == va && ib < ia);
          if (before == dir) {
            sv[t] = vb; sv[ixj] = va;
            si[t] = ib; si[ixj] = ia;
          }
        }
      }
      __syncthreads();
    }
  }
  for (int i = threadIdx.x; i < 1024; i += 512) order[b * HALF + i] = si[i];
}

// ---------------------------------------------------------------------------
// Parallel greedy selection (exact serial-scan equivalent) + index maps.
// ---------------------------------------------------------------------------
__global__ __launch_bounds__(256) void select_and_index(
    const int* __restrict__ best_b, const int* __restrict__ order,
    int* __restrict__ keep_idx, int* __restrict__ partner,
    int* __restrict__ dst2) {
  const int b = blockIdx.x;
  __shared__ int rankA[HALF];
  __shared__ int minrank[HALF];
  __shared__ int taken[HALF];
  __shared__ int sel_a[RR], sel_b[RR];
  __shared__ int removed[NN];
  __shared__ int src_row[NN];
  __shared__ int tsum[256];
  const int t = threadIdx.x;

  for (int i = t; i < HALF; i += 256) { minrank[i] = 0x7fffffff; taken[i] = 0; }
  for (int i = t; i < NN; i += 256) {
    removed[i] = 0;
    partner[b * NN + i] = -1;
  }
  for (int i = t; i < NM; i += 256) dst2[b * NM + i] = -1;
  __syncthreads();
  int ord[4];
#pragma unroll
  for (int q = 0; q < 4; ++q) {
    int step = t * 4 + q;
    ord[q] = order[b * HALF + step];
    rankA[ord[q]] = step;
  }
  __syncthreads();
#pragma unroll
  for (int q = 0; q < 4; ++q) {
    int a = t * 4 + q;
    atomicMin(&minrank[best_b[b * HALF + a]], rankA[a]);
  }
  __syncthreads();
  for (int i = t; i < HALF; i += 256) {
    int mr = minrank[i];
    if (mr != 0x7fffffff) taken[mr] = 1;
  }
  __syncthreads();
  int c[4];
  int mysum = 0;
#pragma unroll
  for (int q = 0; q < 4; ++q) { c[q] = taken[t * 4 + q]; mysum += c[q]; }
  tsum[t] = mysum;
  __syncthreads();
  for (int off = 1; off < 256; off <<= 1) {
    int v = (t >= off) ? tsum[t - off] : 0;
    __syncthreads();
    tsum[t] += v;
    __syncthreads();
  }
  int run = tsum[t] - mysum;
#pragma unroll
  for (int q = 0; q < 4; ++q) {
    if (c[q] && run < RR) {
      int a = ord[q];
      sel_a[run] = 2 * a;
      sel_b[run] = 2 * best_b[b * HALF + a] + 1;
    }
    run += c[q];
  }
  __syncthreads();
  const int cnt = min(tsum[255], RR);
  if (t >= cnt) { sel_a[t] = sel_a[0]; sel_b[t] = sel_b[0]; }
  __syncthreads();
  {
    int ga = sel_a[t], gb = sel_b[t];
    removed[gb] = 1;
    partner[b * NN + ga] = gb;
  }
  __syncthreads();
  int myc = 0;
#pragma unroll
  for (int q = 0; q < 8; ++q) myc += !removed[8 * t + q];
  tsum[t] = myc;
  __syncthreads();
  for (int off = 1; off < 256; off <<= 1) {
    int v = (t >= off) ? tsum[t - off] : 0;
    __syncthreads();
    tsum[t] += v;
    __syncthreads();
  }
  int pos = tsum[t] - myc;
#pragma unroll
  for (int q = 0; q < 8; ++q) {
    int p = 8 * t + q;
    int sr = -1;
    if (!removed[p]) {
      if (pos < NM) {
        keep_idx[b * NM + pos] = p;
        sr = pos;
      }
      ++pos;
    }
    src_row[p] = sr;
  }
  __syncthreads();
  {
    int sr = src_row[sel_a[t]];
    dst2[b * NM + sr] = sel_b[t];
  }
}

// ---------------------------------------------------------------------------
// Merge -> bf16 x_mb
// ---------------------------------------------------------------------------
__global__ __launch_bounds__(256) void merge_kernel(
    const float* __restrict__ x, const int* __restrict__ keep_idx,
    const int* __restrict__ partner, __bf16* __restrict__ x_mb) {
  const int mrow = blockIdx.x;
  const int b = mrow / NM;
  const int t = mrow % NM;
  const int p = keep_idx[b * NM + t];
  const int pp = partner[b * NN + p];
  const float4* src =
      reinterpret_cast<const float4*>(x + ((size_t)b * NN + p) * DM);
  float4 val = src[threadIdx.x];
  if (pp >= 0) {
    const float4* s2 =
        reinterpret_cast<const float4*>(x + ((size_t)b * NN + pp) * DM);
    float4 v2 = s2[threadIdx.x];
    val.x = 0.5f * (val.x + v2.x);
    val.y = 0.5f * (val.y + v2.y);
    val.z = 0.5f * (val.z + v2.z);
    val.w = 0.5f * (val.w + v2.w);
  }
  union { __bf16 h[4]; uint2 u; } U;
  U.h[0] = (__bf16)val.x;
  U.h[1] = (__bf16)val.y;
  U.h[2] = (__bf16)val.z;
  U.h[3] = (__bf16)val.w;
  ((uint2*)(x_mb + (size_t)mrow * DM))[threadIdx.x] = U.u;
}

// ---------------------------------------------------------------------------
// Fused RoPE for q and k reading the fused QKV output [row][1536].
// ---------------------------------------------------------------------------
__global__ __launch_bounds__(256) void rope_fused(
    const float* __restrict__ qkv, const float* __restrict__ fc,
    __bf16* __restrict__ qbh, __bf16* __restrict__ kbh) {
  const int row = blockIdx.x;
  const int t = row % NM;
  const int b = row / NM;
  for (int idx = threadIdx.x; idx < 640; idx += 256) {
    int u = idx & 31;
    float c = fc[(t * 32 + u) * 2];
    float s = fc[(t * 32 + u) * 2 + 1];
    if (idx < 512) {
      int h = idx >> 5;
      const float* p = qkv + (size_t)row * 1536 + h * 64 + 2 * u;
      float x1 = p[0], x2 = p[1];
      __bf16* d = qbh + ((size_t)(b * NH + h) * NM + t) * 64 + 2 * u;
      d[0] = (__bf16)((x1 * c - x2 * s) * 0.125f);
      d[1] = (__bf16)((x1 * s + x2 * c) * 0.125f);
    } else {
      int h = (idx - 512) >> 5;
      const float* p = qkv + (size_t)row * 1536 + 1024 + h * 64 + 2 * u;
      float x1 = p[0], x2 = p[1];
      __bf16* d = kbh + ((size_t)(b * NKV + h) * NM + t) * 64 + 2 * u;
      d[0] = (__bf16)(x1 * c - x2 * s);
      d[1] = (__bf16)(x1 * s + x2 * c);
    }
  }
}

// ---------------------------------------------------------------------------
// V repack from fused QKV: fp32 [row][1280+kvh*64+d] -> bf16 [b, kvh, 64, NM]
// ---------------------------------------------------------------------------
__global__ __launch_bounds__(256) void v_repack(const float* __restrict__ qkv,
                                                __bf16* __restrict__ vtb) {
  __shared__ float ld[64][65];
  int bid = blockIdx.x;
  const int kt = bid % (NM / 64); bid /= (NM / 64);
  const int kvh = bid % NKV;
  const int b = bid / NKV;
  const int j0 = kt * 64;
  for (int t2 = threadIdx.x; t2 < 1024; t2 += 256) {
    int key = t2 >> 4, c4 = t2 & 15;
    float4 v4 = *reinterpret_cast<const float4*>(
        qkv + (size_t)(b * NM + j0 + key) * 1536 + 1280 + kvh * 64 + c4 * 4);
    ld[key][c4 * 4 + 0] = v4.x;
    ld[key][c4 * 4 + 1] = v4.y;
    ld[key][c4 * 4 + 2] = v4.z;
    ld[key][c4 * 4 + 3] = v4.w;
  }
  __syncthreads();
  const int dim = threadIdx.x >> 2, kc = threadIdx.x & 3;
  __bf16* out = vtb + ((size_t)(b * NKV + kvh) * 64 + dim) * NM + j0 + kc * 16;
#pragma unroll
  for (int kk = 0; kk < 16; ++kk) out[kk] = (__bf16)ld[kc * 16 + kk][dim];
}

// ---------------------------------------------------------------------------
// Flash attention, bf16 MFMA, S^T orientation, fixed-shift softmax,
// split-K over NSPL=4, 8-wave blocks (2 q-tiles x 4 GQA heads).
// ---------------------------------------------------------------------------
__global__ __launch_bounds__(512) void attn_mfma(
    const __bf16* __restrict__ qbh, const __bf16* __restrict__ kbh,
    const __bf16* __restrict__ vtb, float* __restrict__ pl,
    __bf16* __restrict__ pacc) {
  __shared__ __align__(16) __bf16 Ks[4096];
  __shared__ __align__(16) __bf16 Vs[4096];
  int bid = blockIdx.x;
  const int qt2 = bid % (NM / 32); bid /= (NM / 32);
  const int split = bid % NSPL; bid /= NSPL;
  const int kvh = bid % NKV;
  const int b = bid / NKV;
  const int w = threadIdx.x >> 6;
  const int lane = threadIdx.x & 63;
  const int h = kvh * 4 + (w & 3);
  const int qt = qt2 * 32 + (w >> 2) * 16;
  const int g = lane >> 4;
  const int ml = lane & 15;

  const __bf16* qrow = qbh + ((size_t)(b * NH + h) * NM + qt + ml) * 64;
  bf16x8 qa0 = *reinterpret_cast<const bf16x8*>(qrow + g * 8);
  bf16x8 qa1 = *reinterpret_cast<const bf16x8*>(qrow + 32 + g * 8);

  f32x4 acc[4];
#pragma unroll
  for (int mt = 0; mt < 4; ++mt) acc[mt] = (f32x4){0.f, 0.f, 0.f, 0.f};
  float lsum = 0.f;

  const __bf16* kp = kbh + (size_t)(b * NKV + kvh) * NM * 64;
  const __bf16* vp = vtb + (size_t)(b * NKV + kvh) * 64 * NM;
  const int src0 = ((lane >> 4) & 1) * 32 + ml;
  const int src1 = src0 + 16;
  const int sel = g >> 1;

  const int jt0 = split * (NT / NSPL);
  for (int jt = jt0; jt < jt0 + NT / NSPL; ++jt) {
    __syncthreads();
    {
      const int t2 = threadIdx.x;
      const int blk = t2 >> 7, s = (t2 >> 6) & 1, l = t2 & 63;
      *(float4*)&Ks[t2 * 8] = *(const float4*)(
          kp + (size_t)(jt * 64 + blk * 16 + (l & 15)) * 64 + s * 32 +
          ((l >> 4) << 3));
      *(float4*)&Vs[t2 * 8] = *(const float4*)(
          vp + (size_t)(blk * 16 + (l & 15)) * NM + jt * 64 + s * 32 +
          ((l >> 4) << 3));
    }
    __syncthreads();
    f32x4 S[4];
#pragma unroll
    for (int nt = 0; nt < 4; ++nt) {
      bf16x8 k0 = *(const bf16x8*)&Ks[(nt * 128 + lane) * 8];
      bf16x8 k1 = *(const bf16x8*)&Ks[(nt * 128 + 64 + lane) * 8];
      f32x4 s4 = (f32x4){0.f, 0.f, 0.f, 0.f};
      s4 = __builtin_amdgcn_mfma_f32_16x16x32_bf16(k0, qa0, s4, 0, 0, 0);
      s4 = __builtin_amdgcn_mfma_f32_16x16x32_bf16(k1, qa1, s4, 0, 0, 0);
      S[nt] = s4;
    }
    float p[4][4];
#pragma unroll
    for (int nt = 0; nt < 4; ++nt)
#pragma unroll
      for (int r = 0; r < 4; ++r) {
        p[nt][r] = __expf(S[nt][r]);
        lsum += p[nt][r];
      }
    unsigned pk[4][2];
#pragma unroll
    for (int nt = 0; nt < 4; ++nt) {
      pk[nt][0] = pk2(p[nt][0], p[nt][1]);
      pk[nt][1] = pk2(p[nt][2], p[nt][3]);
    }
    unsigned A00 = shu(pk[0][0], src0), A01 = shu(pk[0][1], src0);
    unsigned A10 = shu(pk[1][0], src0), A11 = shu(pk[1][1], src0);
    unsigned B00 = shu(pk[0][0], src1), B01 = shu(pk[0][1], src1);
    unsigned B10 = shu(pk[1][0], src1), B11 = shu(pk[1][1], src1);
    unsigned C00 = shu(pk[2][0], src0), C01 = shu(pk[2][1], src0);
    unsigned C10 = shu(pk[3][0], src0), C11 = shu(pk[3][1], src0);
    unsigned D00 = shu(pk[2][0], src1), D01 = shu(pk[2][1], src1);
    unsigned D10 = shu(pk[3][0], src1), D11 = shu(pk[3][1], src1);
    union { uint4 u; bf16x8 v; } P0, P1;
    P0.u.x = sel ? A10 : A00; P0.u.y = sel ? A11 : A01;
    P0.u.z = sel ? B10 : B00; P0.u.w = sel ? B11 : B01;
    P1.u.x = sel ? C10 : C00; P1.u.y = sel ? C11 : C01;
    P1.u.z = sel ? D10 : D00; P1.u.w = sel ? D11 : D01;
#pragma unroll
    for (int mt = 0; mt < 4; ++mt) {
      bf16x8 v0 = *(const bf16x8*)&Vs[(mt * 128 + lane) * 8];
      bf16x8 v1 = *(const bf16x8*)&Vs[(mt * 128 + 64 + lane) * 8];
      acc[mt] = __builtin_amdgcn_mfma_f32_16x16x32_bf16(v0, P0.v, acc[mt], 0, 0, 0);
      acc[mt] = __builtin_amdgcn_mfma_f32_16x16x32_bf16(v1, P1.v, acc[mt], 0, 0, 0);
    }
  }
  lsum += __shfl_xor(lsum, 16, 64);
  lsum += __shfl_xor(lsum, 32, 64);
  const size_t row = (size_t)(b * NH + h) * NM + qt + ml;
  if (g == 0) pl[row * NSPL + split] = lsum;
  __bf16* pa = pacc + (row * NSPL + split) * 64;
#pragma unroll
  for (int mt = 0; mt < 4; ++mt) {
    uint2 u;
    u.x = pk2(acc[mt][0], acc[mt][1]);
    u.y = pk2(acc[mt][2], acc[mt][3]);
    *reinterpret_cast<uint2*>(pa + mt * 16 + g * 4) = u;
  }
}

// ---------------------------------------------------------------------------
// Split-K combine (fixed shift: plain sums) -> bf16 attn_ob
// ---------------------------------------------------------------------------
__global__ __launch_bounds__(256) void attn_combine(
    const float* __restrict__ pl, const __bf16* __restrict__ pacc,
    __bf16* __restrict__ attn_ob) {
  const size_t rid = (size_t)blockIdx.x * 4 + (threadIdx.x >> 6);
  const int d = threadIdx.x & 63;
  float num = 0.f, den = 0.f;
#pragma unroll
  for (int s = 0; s < NSPL; ++s) {
    num += (float)pacc[(rid * NSPL + s) * 64 + d];
    den += pl[rid * NSPL + s];
  }
  float o = num / den;
  const int q = (int)(rid % NM);
  const int h = (int)((rid / NM) % NH);
  const int b = (int)(rid / ((size_t)NM * NH));
  attn_ob[((size_t)(b * NM + q)) * DM + h * 64 + d] = (__bf16)o;
}

// ---------------------------------------------------------------------------
extern "C" void kernel_launch(void* const* d_in, const int* in_sizes, int n_in,
                              void* d_out, int out_size, void* d_ws,
                              size_t ws_size, hipStream_t stream) {
  const float* x = (const float*)d_in[0];
  const float* fc = (const float*)d_in[1];
  const float* Wq = (const float*)d_in[2];
  const float* Wk = (const float*)d_in[3];
  const float* Wv = (const float*)d_in[4];
  const float* Wo = (const float*)d_in[5];
  float* out = (float*)d_out;

  char* ws = (char*)d_ws;
  size_t off = 0;
  auto alloc = [&](size_t bytes) {
    void* p = ws + off;
    off += (bytes + 255) & ~(size_t)255;
    return p;
  };
  float* metric0 = (float*)alloc((size_t)BB * NN * 256 * 4);
  float* metric1 = (float*)alloc((size_t)BB * NN * 256 * 4);
  float* best_s = (float*)alloc((size_t)BB * HALF * 4);
  int* best_b = (int*)alloc((size_t)BB * HALF * 4);
  int* order = (int*)alloc((size_t)BB * HALF * 4);
  int* keep_idx = (int*)alloc((size_t)BB * NM * 4);
  int* partner = (int*)alloc((size_t)BB * NN * 4);
  int* dst2 = (int*)alloc((size_t)BB * NM * 4);
  float* sval = (float*)alloc((size_t)BB * HALF * 16 * 4);
  int* sidx = (int*)alloc((size_t)BB * HALF * 16 * 4);
  // big region, phase-aliased:
  //  A1: xh@0 (8.4MB), xl@8.5MB (8.4MB)
  //  A2: anh/anl/bnh/bnl (1MB each @0/1.1/2.2/3.3MB)  [xh dead]
  //  B : qkv fp32 [3584][1536] = 22MB @0              [an* dead]
  //  C : pacc bf16 [rows][NSPL][64] = 29.4MB @0       [qkv dead]
  char* bigreg = (char*)alloc((size_t)30 * 1024 * 1024);
  __bf16* xh = (__bf16*)bigreg;
  __bf16* xl = (__bf16*)(bigreg + (size_t)8704 * 1024);
  __bf16* anh = (__bf16*)bigreg;
  __bf16* anl = (__bf16*)(bigreg + (size_t)1100 * 1024);
  __bf16* bnh = (__bf16*)(bigreg + (size_t)2200 * 1024);
  __bf16* bnl = (__bf16*)(bigreg + (size_t)3300 * 1024);
  float* qkv = (float*)bigreg;
  __bf16* pacc = (__bf16*)bigreg;
  __bf16* x_mb = (__bf16*)alloc((size_t)BB * NM * DM * 2);
  __bf16* qbh = (__bf16*)alloc((size_t)BB * NH * NM * 64 * 2);
  __bf16* kbh = (__bf16*)alloc((size_t)BB * NKV * NM * 64 * 2);
  __bf16* vtb = (__bf16*)alloc((size_t)BB * NKV * 64 * NM * 2);
  __bf16* attn_ob = (__bf16*)alloc((size_t)BB * NM * DM * 2);
  float* pl = (float*)alloc((size_t)BB * NH * NM * NSPL * 4);
  __bf16* Wqkvt = (__bf16*)alloc((size_t)1536 * DM * 2);
  __bf16* Wktl = (__bf16*)alloc((size_t)256 * DM * 2);
  __bf16* Wot = (__bf16*)alloc((size_t)DM * DM * 2);
  const __bf16* Wkth = Wqkvt + (size_t)1024 * 1024;  // Wk^T-hi inside concat

  // ---- weight converts (one launch) + x hi/lo split
  transpose_all<<<640, 256, 0, stream>>>(Wq, Wk, Wv, Wo, Wqkvt, Wktl, Wot);
  hilo_split<<<(BB * NN * DM / 4) / 256, 256, 0, stream>>>(x, xh, xl);
  // ---- metric = x @ Wk (3-term hi/lo MFMA, split-K x2)
  gemm3t<<<dim3(64, 4, 2), 256, 0, stream>>>(xh, xl, Wkth, Wktl, metric0,
                                             metric1, BB * NN, 256, DM);
  // ---- selection: normalize, scores GEMM w/ fused argmax, reduce, sort, greedy
  normalize_split<<<BB * NN, 256, 0, stream>>>(metric0, metric1, anh, anl, bnh,
                                               bnl);
  gemm_scam<<<dim3(16, 16, 2), 256, 0, stream>>>(anh, anl, bnh, bnl, sval,
                                                 sidx);
  argmax_reduce<<<(BB * HALF) / 16, 256, 0, stream>>>(sval, sidx, best_s,
                                                      best_b);
  sort_desc<<<BB, 512, 0, stream>>>(best_s, order);
  select_and_index<<<BB, 256, 0, stream>>>(best_b, order, keep_idx, partner,
                                           dst2);
  merge_kernel<<<BB * NM, 256, 0, stream>>>(x, keep_idx, partner, x_mb);
  // ---- fused QKV projection (bf16 MFMA, N=1536)
  gemm_bf16<<<dim3(56, 24), 256, 0, stream>>>(x_mb, Wqkvt, qkv, BB * NM, 1536,
                                              DM);
  // ---- RoPE (fused q+k) + V repack
  rope_fused<<<BB * NM, 256, 0, stream>>>(qkv, fc, qbh, kbh);
  v_repack<<<BB * NKV * (NM / 64), 256, 0, stream>>>(qkv, vtb);
  // ---- attention (8-wave blocks, split-K x4) + combine
  attn_mfma<<<BB * NKV * NSPL * (NM / 32), 512, 0, stream>>>(qbh, kbh, vtb, pl,
                                                             pacc);
  attn_combine<<<(BB * NH * NM) / 4, 256, 0, stream>>>(pl, pacc, attn_ob);
  // ---- output projection with fused unmerge scatter
  gemm_wo<<<dim3(56, 16), 256, 0, stream>>>(attn_ob, Wot, keep_idx, dst2, out,
                                            BB * NM, DM, DM);
}

// Round 10
// 283.603 us; speedup vs baseline: 23.1553x; 1.0810x over previous
//
#include <hip/hip_runtime.h>
#include <hip/hip_bf16.h>
#include <math.h>

// Problem constants
#define BB 2
#define NN 2048
#define DM 1024
#define NH 16
#define NKV 4
#define HD 64
#define RR 256
#define HALF 1024
#define NM 1792   // NN - RR
#define NT 28     // key tiles of 64
#define NSPL 4    // attention split-K

typedef __bf16 bf16x8 __attribute__((ext_vector_type(8)));
typedef float f32x4 __attribute__((ext_vector_type(4)));

__device__ inline unsigned pk2(float a, float b) {
  union { __bf16 h; unsigned short u; } ua, ub;
  ua.h = (__bf16)a;
  ub.h = (__bf16)b;
  return (unsigned)ua.u | ((unsigned)ub.u << 16);
}

__device__ inline unsigned shu(unsigned v, int s) {
  return (unsigned)__shfl((int)v, s, 64);
}

// Async global->LDS, 16B per lane. LDS dest = wave-uniform base + lane*16.
__device__ __forceinline__ void async16(const void* g, void* l) {
  __builtin_amdgcn_global_load_lds(
      (const __attribute__((address_space(1))) void*)g,
      (__attribute__((address_space(3))) void*)l, 16, 0, 0);
}

// ---------------------------------------------------------------------------
// bf16 MFMA GEMM: C[M x N] = A[M x K] @ Bt[N x K]^T.  Block tile 128x64,
// wave tile 32x64. Fragment-linear LDS; staging via global_load_lds (16B).
// ---------------------------------------------------------------------------
__global__ __launch_bounds__(256) void gemm_bf16(
    const __bf16* __restrict__ A, const __bf16* __restrict__ Bt,
    float* __restrict__ C, int M, int N, int K) {
  __shared__ __align__(16) __bf16 As[8192];  // 128 x 64
  __shared__ __align__(16) __bf16 Bs[4096];  // 64 x 64
  const int bm0 = blockIdx.x * 128;
  const int bn0 = blockIdx.y * 64;
  const int w = threadIdx.x >> 6;
  const int lane = threadIdx.x & 63;
  f32x4 acc[2][4];
#pragma unroll
  for (int i = 0; i < 2; ++i)
#pragma unroll
    for (int nt = 0; nt < 4; ++nt) acc[i][nt] = (f32x4){0.f, 0.f, 0.f, 0.f};
  for (int kk = 0; kk < K; kk += 64) {
    __syncthreads();
#pragma unroll
    for (int it = 0; it < 4; ++it) {
      const int c = it * 256 + w * 64 + lane;
      async16(A + (size_t)(bm0 + ((c >> 7) << 4) + (c & 15)) * K + kk +
                  (((c >> 6) & 1) << 5) + (((c >> 4) & 3) << 3),
              &As[(it * 256 + w * 64) * 8]);
    }
#pragma unroll
    for (int it = 0; it < 2; ++it) {
      const int c = it * 256 + w * 64 + lane;
      async16(Bt + (size_t)(bn0 + ((c >> 7) << 4) + (c & 15)) * K + kk +
                  (((c >> 6) & 1) << 5) + (((c >> 4) & 3) << 3),
              &Bs[(it * 256 + w * 64) * 8]);
    }
    __syncthreads();
#pragma unroll
    for (int s = 0; s < 2; ++s) {
      bf16x8 a0 = *(const bf16x8*)&As[((2 * w) * 128 + s * 64 + lane) * 8];
      bf16x8 a1 = *(const bf16x8*)&As[((2 * w + 1) * 128 + s * 64 + lane) * 8];
#pragma unroll
      for (int nt = 0; nt < 4; ++nt) {
        bf16x8 bfr = *(const bf16x8*)&Bs[(nt * 128 + s * 64 + lane) * 8];
        acc[0][nt] =
            __builtin_amdgcn_mfma_f32_16x16x32_bf16(a0, bfr, acc[0][nt], 0, 0, 0);
        acc[1][nt] =
            __builtin_amdgcn_mfma_f32_16x16x32_bf16(a1, bfr, acc[1][nt], 0, 0, 0);
      }
    }
  }
  const int g = lane >> 4, ml = lane & 15;
#pragma unroll
  for (int i = 0; i < 2; ++i)
#pragma unroll
    for (int nt = 0; nt < 4; ++nt)
#pragma unroll
      for (int r = 0; r < 4; ++r)
        C[(size_t)(bm0 + (2 * w + i) * 16 + g * 4 + r) * N + bn0 + nt * 16 +
          ml] = acc[i][nt][r];
}

// ---------------------------------------------------------------------------
// Wo GEMM (128x64 tiles, async staging) with fused unmerge-scatter epilogue.
// ---------------------------------------------------------------------------
__global__ __launch_bounds__(256) void gemm_wo(
    const __bf16* __restrict__ A, const __bf16* __restrict__ Bt,
    const int* __restrict__ keep_idx, const int* __restrict__ dst2,
    float* __restrict__ out, int M, int N, int K) {
  __shared__ __align__(16) __bf16 As[8192];
  __shared__ __align__(16) __bf16 Bs[4096];
  const int bm0 = blockIdx.x * 128;
  const int bn0 = blockIdx.y * 64;
  const int w = threadIdx.x >> 6;
  const int lane = threadIdx.x & 63;
  f32x4 acc[2][4];
#pragma unroll
  for (int i = 0; i < 2; ++i)
#pragma unroll
    for (int nt = 0; nt < 4; ++nt) acc[i][nt] = (f32x4){0.f, 0.f, 0.f, 0.f};
  for (int kk = 0; kk < K; kk += 64) {
    __syncthreads();
#pragma unroll
    for (int it = 0; it < 4; ++it) {
      const int c = it * 256 + w * 64 + lane;
      async16(A + (size_t)(bm0 + ((c >> 7) << 4) + (c & 15)) * K + kk +
                  (((c >> 6) & 1) << 5) + (((c >> 4) & 3) << 3),
              &As[(it * 256 + w * 64) * 8]);
    }
#pragma unroll
    for (int it = 0; it < 2; ++it) {
      const int c = it * 256 + w * 64 + lane;
      async16(Bt + (size_t)(bn0 + ((c >> 7) << 4) + (c & 15)) * K + kk +
                  (((c >> 6) & 1) << 5) + (((c >> 4) & 3) << 3),
              &Bs[(it * 256 + w * 64) * 8]);
    }
    __syncthreads();
#pragma unroll
    for (int s = 0; s < 2; ++s) {
      bf16x8 a0 = *(const bf16x8*)&As[((2 * w) * 128 + s * 64 + lane) * 8];
      bf16x8 a1 = *(const bf16x8*)&As[((2 * w + 1) * 128 + s * 64 + lane) * 8];
#pragma unroll
      for (int nt = 0; nt < 4; ++nt) {
        bf16x8 bfr = *(const bf16x8*)&Bs[(nt * 128 + s * 64 + lane) * 8];
        acc[0][nt] =
            __builtin_amdgcn_mfma_f32_16x16x32_bf16(a0, bfr, acc[0][nt], 0, 0, 0);
        acc[1][nt] =
            __builtin_amdgcn_mfma_f32_16x16x32_bf16(a1, bfr, acc[1][nt], 0, 0, 0);
      }
    }
  }
  const int g = lane >> 4, ml = lane & 15;
#pragma unroll
  for (int i = 0; i < 2; ++i)
#pragma unroll
    for (int r = 0; r < 4; ++r) {
      const int row = bm0 + (2 * w + i) * 16 + g * 4 + r;
      const int bb = row / NM, tt = row % NM;
      const int p1 = keep_idx[bb * NM + tt];
      const int p2 = dst2[bb * NM + tt];
#pragma unroll
      for (int nt = 0; nt < 4; ++nt) {
        const int col = bn0 + nt * 16 + ml;
        float v = acc[i][nt][r];
        out[((size_t)(bb * NN + p1)) * DM + col] = v;
        if (p2 >= 0) out[((size_t)(bb * NN + p2)) * DM + col] = v;
      }
    }
}

// ---------------------------------------------------------------------------
// 3-term hi/lo MFMA GEMM (fp32-accurate), async staging, 64x64 tiles.
// Split-K via blockIdx.z (separate outputs C0/C1).
// ---------------------------------------------------------------------------
__global__ __launch_bounds__(256) void gemm3t(
    const __bf16* __restrict__ Ah, const __bf16* __restrict__ Al,
    const __bf16* __restrict__ Bh, const __bf16* __restrict__ Bl,
    float* __restrict__ C0, float* __restrict__ C1, int M, int N, int K) {
  __shared__ __align__(16) __bf16 Ahs[4096], Als[4096], Bhs[4096], Bls[4096];
  const int z = blockIdx.z;
  float* C = z ? C1 : C0;
  const int kof = z * (K / 2);
  const int bm0 = blockIdx.x * 64;
  const int bn0 = blockIdx.y * 64;
  const int w = threadIdx.x >> 6;
  const int lane = threadIdx.x & 63;
  f32x4 acc[4];
#pragma unroll
  for (int nt = 0; nt < 4; ++nt) acc[nt] = (f32x4){0.f, 0.f, 0.f, 0.f};
  for (int kk = kof; kk < kof + K / 2; kk += 64) {
    __syncthreads();
#pragma unroll
    for (int it = 0; it < 2; ++it) {
      const int c = it * 256 + w * 64 + lane;
      const size_t ra = (size_t)(bm0 + ((c >> 7) << 4) + (c & 15)) * K;
      const size_t rb = (size_t)(bn0 + ((c >> 7) << 4) + (c & 15)) * K;
      const int col = kk + (((c >> 6) & 1) << 5) + (((c >> 4) & 3) << 3);
      const int lb = (it * 256 + w * 64) * 8;
      async16(Ah + ra + col, &Ahs[lb]);
      async16(Al + ra + col, &Als[lb]);
      async16(Bh + rb + col, &Bhs[lb]);
      async16(Bl + rb + col, &Bls[lb]);
    }
    __syncthreads();
#pragma unroll
    for (int s = 0; s < 2; ++s) {
      bf16x8 ah = *(const bf16x8*)&Ahs[((w * 2 + s) * 64 + lane) * 8];
      bf16x8 al = *(const bf16x8*)&Als[((w * 2 + s) * 64 + lane) * 8];
#pragma unroll
      for (int nt = 0; nt < 4; ++nt) {
        bf16x8 bh = *(const bf16x8*)&Bhs[((nt * 2 + s) * 64 + lane) * 8];
        bf16x8 bl = *(const bf16x8*)&Bls[((nt * 2 + s) * 64 + lane) * 8];
        acc[nt] = __builtin_amdgcn_mfma_f32_16x16x32_bf16(al, bh, acc[nt], 0, 0, 0);
        acc[nt] = __builtin_amdgcn_mfma_f32_16x16x32_bf16(ah, bl, acc[nt], 0, 0, 0);
        acc[nt] = __builtin_amdgcn_mfma_f32_16x16x32_bf16(ah, bh, acc[nt], 0, 0, 0);
      }
    }
  }
  const int g = lane >> 4, ml = lane & 15;
#pragma unroll
  for (int nt = 0; nt < 4; ++nt)
#pragma unroll
    for (int r = 0; r < 4; ++r)
      C[(size_t)(bm0 + w * 16 + g * 4 + r) * N + bn0 + nt * 16 + ml] =
          acc[nt][r];
}

// ---------------------------------------------------------------------------
// Scores 3-term GEMM with fused per-tile row-argmax epilogue (async staging).
// ---------------------------------------------------------------------------
__global__ __launch_bounds__(256) void gemm_scam(
    const __bf16* __restrict__ Ah, const __bf16* __restrict__ Al,
    const __bf16* __restrict__ Bh, const __bf16* __restrict__ Bl,
    float* __restrict__ sval, int* __restrict__ sidx) {
  __shared__ __align__(16) __bf16 Ahs[4096], Als[4096], Bhs[4096], Bls[4096];
  const size_t zo = (size_t)blockIdx.z * HALF * 256;
  const int bm0 = blockIdx.x * 64;
  const int bn0 = blockIdx.y * 64;
  const int w = threadIdx.x >> 6;
  const int lane = threadIdx.x & 63;
  f32x4 acc[4];
#pragma unroll
  for (int nt = 0; nt < 4; ++nt) acc[nt] = (f32x4){0.f, 0.f, 0.f, 0.f};
  for (int kk = 0; kk < 256; kk += 64) {
    __syncthreads();
#pragma unroll
    for (int it = 0; it < 2; ++it) {
      const int c = it * 256 + w * 64 + lane;
      const size_t ra = zo + (size_t)(bm0 + ((c >> 7) << 4) + (c & 15)) * 256;
      const size_t rb = zo + (size_t)(bn0 + ((c >> 7) << 4) + (c & 15)) * 256;
      const int col = kk + (((c >> 6) & 1) << 5) + (((c >> 4) & 3) << 3);
      const int lb = (it * 256 + w * 64) * 8;
      async16(Ah + ra + col, &Ahs[lb]);
      async16(Al + ra + col, &Als[lb]);
      async16(Bh + rb + col, &Bhs[lb]);
      async16(Bl + rb + col, &Bls[lb]);
    }
    __syncthreads();
#pragma unroll
    for (int s = 0; s < 2; ++s) {
      bf16x8 ah = *(const bf16x8*)&Ahs[((w * 2 + s) * 64 + lane) * 8];
      bf16x8 al = *(const bf16x8*)&Als[((w * 2 + s) * 64 + lane) * 8];
#pragma unroll
      for (int nt = 0; nt < 4; ++nt) {
        bf16x8 bh = *(const bf16x8*)&Bhs[((nt * 2 + s) * 64 + lane) * 8];
        bf16x8 bl = *(const bf16x8*)&Bls[((nt * 2 + s) * 64 + lane) * 8];
        acc[nt] = __builtin_amdgcn_mfma_f32_16x16x32_bf16(al, bh, acc[nt], 0, 0, 0);
        acc[nt] = __builtin_amdgcn_mfma_f32_16x16x32_bf16(ah, bl, acc[nt], 0, 0, 0);
        acc[nt] = __builtin_amdgcn_mfma_f32_16x16x32_bf16(ah, bh, acc[nt], 0, 0, 0);
      }
    }
  }
  // epilogue: row-argmax within this 64x64 tile (ties -> lowest col)
  const int g = lane >> 4, ml = lane & 15;
#pragma unroll
  for (int r = 0; r < 4; ++r) {
    float bv = acc[0][r];
    int bc = bn0 + ml;
#pragma unroll
    for (int nt = 1; nt < 4; ++nt) {
      float v = acc[nt][r];
      int c = bn0 + nt * 16 + ml;
      if (v > bv) { bv = v; bc = c; }
    }
#pragma unroll
    for (int off = 1; off < 16; off <<= 1) {
      float vo = __shfl_xor(bv, off, 64);
      int co = __shfl_xor(bc, off, 64);
      if (vo > bv || (vo == bv && co < bc)) { bv = vo; bc = co; }
    }
    if (ml == 0) {
      const int row = bm0 + w * 16 + g * 4 + r;
      const size_t o = ((size_t)blockIdx.z * HALF + row) * 16 + (bn0 >> 6);
      sval[o] = bv;
      sidx[o] = bc;
    }
  }
}

// ---------------------------------------------------------------------------
// Reduce 16 argmax partials per row -> best_s / best_b. 16 rows per block.
// ---------------------------------------------------------------------------
__global__ __launch_bounds__(256) void argmax_reduce(
    const float* __restrict__ sval, const int* __restrict__ sidx,
    float* __restrict__ best_s, int* __restrict__ best_b) {
  const int lane = threadIdx.x & 63;
  const int e = lane & 15;
  const int rid = blockIdx.x * 16 + (threadIdx.x >> 6) * 4 + (lane >> 4);
  float bv = sval[rid * 16 + e];
  int bc = sidx[rid * 16 + e];
#pragma unroll
  for (int off = 1; off < 16; off <<= 1) {
    float vo = __shfl_xor(bv, off, 64);
    int co = __shfl_xor(bc, off, 64);
    if (vo > bv || (vo == bv && co < bc)) { bv = vo; bc = co; }
  }
  if (e == 0) {
    best_s[rid] = bv;
    best_b[rid] = bc;
  }
}

// ---------------------------------------------------------------------------
// x -> (xh, xl) bf16 split
// ---------------------------------------------------------------------------
__global__ __launch_bounds__(256) void hilo_split(const float* __restrict__ x,
                                                  __bf16* __restrict__ xh,
                                                  __bf16* __restrict__ xl) {
  const int i = blockIdx.x * 256 + threadIdx.x;
  float4 v = ((const float4*)x)[i];
  float f[4] = {v.x, v.y, v.z, v.w};
  union { __bf16 h[4]; uint2 u; } H, L;
#pragma unroll
  for (int j = 0; j < 4; ++j) {
    __bf16 hh = (__bf16)f[j];
    H.h[j] = hh;
    L.h[j] = (__bf16)(f[j] - (float)hh);
  }
  ((uint2*)xh)[i] = H.u;
  ((uint2*)xl)[i] = L.u;
}

// ---------------------------------------------------------------------------
// Fused weight transposes (as R9).
// ---------------------------------------------------------------------------
__global__ __launch_bounds__(256) void transpose_all(
    const float* __restrict__ Wq, const float* __restrict__ Wk,
    const float* __restrict__ Wv, const float* __restrict__ Wo,
    __bf16* __restrict__ Wqkvt, __bf16* __restrict__ Wktl,
    __bf16* __restrict__ Wot) {
  __shared__ float ld[64][65];
  const int z = blockIdx.x;
  const float* src;
  __bf16* dsth;
  __bf16* dstl = nullptr;
  int N, k0, n0, rowoff;
  if (z < 256) {
    src = Wq; N = 1024; k0 = (z >> 4) << 6; n0 = (z & 15) << 6;
    dsth = Wqkvt; rowoff = 0;
  } else if (z < 320) {
    int zz = z - 256;
    src = Wk; N = 256; k0 = (zz >> 2) << 6; n0 = (zz & 3) << 6;
    dsth = Wqkvt; rowoff = 1024; dstl = Wktl;
  } else if (z < 384) {
    int zz = z - 320;
    src = Wv; N = 256; k0 = (zz >> 2) << 6; n0 = (zz & 3) << 6;
    dsth = Wqkvt; rowoff = 1280;
  } else {
    int zz = z - 384;
    src = Wo; N = 1024; k0 = (zz >> 4) << 6; n0 = (zz & 15) << 6;
    dsth = Wot; rowoff = 0;
  }
  for (int i = threadIdx.x; i < 1024; i += 256) {
    int r = i >> 4, c4 = i & 15;
    float4 v = *(const float4*)(src + (size_t)(k0 + r) * N + n0 + c4 * 4);
    ld[r][c4 * 4 + 0] = v.x;
    ld[r][c4 * 4 + 1] = v.y;
    ld[r][c4 * 4 + 2] = v.z;
    ld[r][c4 * 4 + 3] = v.w;
  }
  __syncthreads();
  for (int i = threadIdx.x; i < 4096; i += 256) {
    int n = i >> 6, k = i & 63;
    float v = ld[k][n];
    __bf16 hh = (__bf16)v;
    dsth[(size_t)(rowoff + n0 + n) * 1024 + k0 + k] = hh;
    if (dstl)
      dstl[(size_t)(n0 + n) * 1024 + k0 + k] = (__bf16)(v - (float)hh);
  }
}

// ---------------------------------------------------------------------------
// Normalize metric rows (sum of split-K halves); write bf16 hi/lo.
// ---------------------------------------------------------------------------
__global__ __launch_bounds__(256) void normalize_split(
    const float* __restrict__ m0, const float* __restrict__ m1,
    __bf16* __restrict__ anh, __bf16* __restrict__ anl,
    __bf16* __restrict__ bnh, __bf16* __restrict__ bnl) {
  const int row = blockIdx.x;
  const int b = row >> 11;
  const int r = row & 2047;
  const int t = threadIdx.x;
  float v = m0[(size_t)row * 256 + t] + m1[(size_t)row * 256 + t];
  float ss = v * v;
#pragma unroll
  for (int o = 32; o > 0; o >>= 1) ss += __shfl_xor(ss, o, 64);
  __shared__ float wsum[4];
  if ((t & 63) == 0) wsum[t >> 6] = ss;
  __syncthreads();
  float tot = wsum[0] + wsum[1] + wsum[2] + wsum[3];
  float inv = 1.f / fmaxf(sqrtf(tot), 1e-12f);
  float nv = v * inv;
  __bf16 hh = (__bf16)nv;
  __bf16 ll = (__bf16)(nv - (float)hh);
  size_t o = ((size_t)b * HALF + (r >> 1)) * 256 + t;
  if (r & 1) {
    bnh[o] = hh;
    bnl[o] = ll;
  } else {
    anh[o] = hh;
    anl[o] = ll;
  }
}

// ---------------------------------------------------------------------------
// Stable descending bitonic argsort of 1024 scores per batch. 512 threads.
// ---------------------------------------------------------------------------
__global__ __launch_bounds__(512) void sort_desc(const float* __restrict__ best_s,
                                                 int* __restrict__ order) {
  const int b = blockIdx.x;
  __shared__ float sv[1024];
  __shared__ int si[1024];
  for (int i = threadIdx.x; i < 1024; i += 512) {
    sv[i] = best_s[b * HALF + i];
    si[i] = i;
  }
  __syncthreads();
  for (int k = 2; k <= 1024; k <<= 1) {
    for (int j = k >> 1; j > 0; j >>= 1) {
      for (int t = threadIdx.x; t < 1024; t += 512) {
        int ixj = t ^ j;
        if (ixj > t) {
          bool dir = ((t & k) == 0);
          float va = sv[t], vb = sv[ixj];
          int ia = si[t], ib = si[ixj];
          bool before = (vb > va) || (vb == va && ib < ia);
          if (before == dir) {
            sv[t] = vb; sv[ixj] = va;
            si[t] = ib; si[ixj] = ia;
          }
        }
      }
      __syncthreads();
    }
  }
  for (int i = threadIdx.x; i < 1024; i += 512) order[b * HALF + i] = si[i];
}

// ---------------------------------------------------------------------------
// Parallel greedy selection (exact serial-scan equivalent) + index maps.
// ---------------------------------------------------------------------------
__global__ __launch_bounds__(256) void select_and_index(
    const int* __restrict__ best_b, const int* __restrict__ order,
    int* __restrict__ keep_idx, int* __restrict__ partner,
    int* __restrict__ dst2) {
  const int b = blockIdx.x;
  __shared__ int rankA[HALF];
  __shared__ int minrank[HALF];
  __shared__ int taken[HALF];
  __shared__ int sel_a[RR], sel_b[RR];
  __shared__ int removed[NN];
  __shared__ int src_row[NN];
  __shared__ int tsum[256];
  const int t = threadIdx.x;

  for (int i = t; i < HALF; i += 256) { minrank[i] = 0x7fffffff; taken[i] = 0; }
  for (int i = t; i < NN; i += 256) {
    removed[i] = 0;
    partner[b * NN + i] = -1;
  }
  for (int i = t; i < NM; i += 256) dst2[b * NM + i] = -1;
  __syncthreads();
  int ord[4];
#pragma unroll
  for (int q = 0; q < 4; ++q) {
    int step = t * 4 + q;
    ord[q] = order[b * HALF + step];
    rankA[ord[q]] = step;
  }
  __syncthreads();
#pragma unroll
  for (int q = 0; q < 4; ++q) {
    int a = t * 4 + q;
    atomicMin(&minrank[best_b[b * HALF + a]], rankA[a]);
  }
  __syncthreads();
  for (int i = t; i < HALF; i += 256) {
    int mr = minrank[i];
    if (mr != 0x7fffffff) taken[mr] = 1;
  }
  __syncthreads();
  int c[4];
  int mysum = 0;
#pragma unroll
  for (int q = 0; q < 4; ++q) { c[q] = taken[t * 4 + q]; mysum += c[q]; }
  tsum[t] = mysum;
  __syncthreads();
  for (int off = 1; off < 256; off <<= 1) {
    int v = (t >= off) ? tsum[t - off] : 0;
    __syncthreads();
    tsum[t] += v;
    __syncthreads();
  }
  int run = tsum[t] - mysum;
#pragma unroll
  for (int q = 0; q < 4; ++q) {
    if (c[q] && run < RR) {
      int a = ord[q];
      sel_a[run] = 2 * a;
      sel_b[run] = 2 * best_b[b * HALF + a] + 1;
    }
    run += c[q];
  }
  __syncthreads();
  const int cnt = min(tsum[255], RR);
  if (t >= cnt) { sel_a[t] = sel_a[0]; sel_b[t] = sel_b[0]; }
  __syncthreads();
  {
    int ga = sel_a[t], gb = sel_b[t];
    removed[gb] = 1;
    partner[b * NN + ga] = gb;
  }
  __syncthreads();
  int myc = 0;
#pragma unroll
  for (int q = 0; q < 8; ++q) myc += !removed[8 * t + q];
  tsum[t] = myc;
  __syncthreads();
  for (int off = 1; off < 256; off <<= 1) {
    int v = (t >= off) ? tsum[t - off] : 0;
    __syncthreads();
    tsum[t] += v;
    __syncthreads();
  }
  int pos = tsum[t] - myc;
#pragma unroll
  for (int q = 0; q < 8; ++q) {
    int p = 8 * t + q;
    int sr = -1;
    if (!removed[p]) {
      if (pos < NM) {
        keep_idx[b * NM + pos] = p;
        sr = pos;
      }
      ++pos;
    }
    src_row[p] = sr;
  }
  __syncthreads();
  {
    int sr = src_row[sel_a[t]];
    dst2[b * NM + sr] = sel_b[t];
  }
}

// ---------------------------------------------------------------------------
// Merge -> bf16 x_mb
// ---------------------------------------------------------------------------
__global__ __launch_bounds__(256) void merge_kernel(
    const float* __restrict__ x, const int* __restrict__ keep_idx,
    const int* __restrict__ partner, __bf16* __restrict__ x_mb) {
  const int mrow = blockIdx.x;
  const int b = mrow / NM;
  const int t = mrow % NM;
  const int p = keep_idx[b * NM + t];
  const int pp = partner[b * NN + p];
  const float4* src =
      reinterpret_cast<const float4*>(x + ((size_t)b * NN + p) * DM);
  float4 val = src[threadIdx.x];
  if (pp >= 0) {
    const float4* s2 =
        reinterpret_cast<const float4*>(x + ((size_t)b * NN + pp) * DM);
    float4 v2 = s2[threadIdx.x];
    val.x = 0.5f * (val.x + v2.x);
    val.y = 0.5f * (val.y + v2.y);
    val.z = 0.5f * (val.z + v2.z);
    val.w = 0.5f * (val.w + v2.w);
  }
  union { __bf16 h[4]; uint2 u; } U;
  U.h[0] = (__bf16)val.x;
  U.h[1] = (__bf16)val.y;
  U.h[2] = (__bf16)val.z;
  U.h[3] = (__bf16)val.w;
  ((uint2*)(x_mb + (size_t)mrow * DM))[threadIdx.x] = U.u;
}

// ---------------------------------------------------------------------------
// Fused RoPE for q and k reading the fused QKV output [row][1536].
// ---------------------------------------------------------------------------
__global__ __launch_bounds__(256) void rope_fused(
    const float* __restrict__ qkv, const float* __restrict__ fc,
    __bf16* __restrict__ qbh, __bf16* __restrict__ kbh) {
  const int row = blockIdx.x;
  const int t = row % NM;
  const int b = row / NM;
  for (int idx = threadIdx.x; idx < 640; idx += 256) {
    int u = idx & 31;
    float c = fc[(t * 32 + u) * 2];
    float s = fc[(t * 32 + u) * 2 + 1];
    if (idx < 512) {
      int h = idx >> 5;
      const float* p = qkv + (size_t)row * 1536 + h * 64 + 2 * u;
      float x1 = p[0], x2 = p[1];
      __bf16* d = qbh + ((size_t)(b * NH + h) * NM + t) * 64 + 2 * u;
      d[0] = (__bf16)((x1 * c - x2 * s) * 0.125f);
      d[1] = (__bf16)((x1 * s + x2 * c) * 0.125f);
    } else {
      int h = (idx - 512) >> 5;
      const float* p = qkv + (size_t)row * 1536 + 1024 + h * 64 + 2 * u;
      float x1 = p[0], x2 = p[1];
      __bf16* d = kbh + ((size_t)(b * NKV + h) * NM + t) * 64 + 2 * u;
      d[0] = (__bf16)(x1 * c - x2 * s);
      d[1] = (__bf16)(x1 * s + x2 * c);
    }
  }
}

// ---------------------------------------------------------------------------
// V repack from fused QKV: fp32 [row][1280+kvh*64+d] -> bf16 [b, kvh, 64, NM]
// ---------------------------------------------------------------------------
__global__ __launch_bounds__(256) void v_repack(const float* __restrict__ qkv,
                                                __bf16* __restrict__ vtb) {
  __shared__ float ld[64][65];
  int bid = blockIdx.x;
  const int kt = bid % (NM / 64); bid /= (NM / 64);
  const int kvh = bid % NKV;
  const int b = bid / NKV;
  const int j0 = kt * 64;
  for (int t2 = threadIdx.x; t2 < 1024; t2 += 256) {
    int key = t2 >> 4, c4 = t2 & 15;
    float4 v4 = *reinterpret_cast<const float4*>(
        qkv + (size_t)(b * NM + j0 + key) * 1536 + 1280 + kvh * 64 + c4 * 4);
    ld[key][c4 * 4 + 0] = v4.x;
    ld[key][c4 * 4 + 1] = v4.y;
    ld[key][c4 * 4 + 2] = v4.z;
    ld[key][c4 * 4 + 3] = v4.w;
  }
  __syncthreads();
  const int dim = threadIdx.x >> 2, kc = threadIdx.x & 3;
  __bf16* out = vtb + ((size_t)(b * NKV + kvh) * 64 + dim) * NM + j0 + kc * 16;
#pragma unroll
  for (int kk = 0; kk < 16; ++kk) out[kk] = (__bf16)ld[kc * 16 + kk][dim];
}

// ---------------------------------------------------------------------------
// Flash attention, bf16 MFMA, S^T orientation, fixed-shift softmax,
// split-K over NSPL=4, 8-wave blocks, async K/V staging.
// ---------------------------------------------------------------------------
__global__ __launch_bounds__(512) void attn_mfma(
    const __bf16* __restrict__ qbh, const __bf16* __restrict__ kbh,
    const __bf16* __restrict__ vtb, float* __restrict__ pl,
    __bf16* __restrict__ pacc) {
  __shared__ __align__(16) __bf16 Ks[4096];
  __shared__ __align__(16) __bf16 Vs[4096];
  int bid = blockIdx.x;
  const int qt2 = bid % (NM / 32); bid /= (NM / 32);
  const int split = bid % NSPL; bid /= NSPL;
  const int kvh = bid % NKV;
  const int b = bid / NKV;
  const int w = threadIdx.x >> 6;
  const int lane = threadIdx.x & 63;
  const int h = kvh * 4 + (w & 3);
  const int qt = qt2 * 32 + (w >> 2) * 16;
  const int g = lane >> 4;
  const int ml = lane & 15;

  const __bf16* qrow = qbh + ((size_t)(b * NH + h) * NM + qt + ml) * 64;
  bf16x8 qa0 = *reinterpret_cast<const bf16x8*>(qrow + g * 8);
  bf16x8 qa1 = *reinterpret_cast<const bf16x8*>(qrow + 32 + g * 8);

  f32x4 acc[4];
#pragma unroll
  for (int mt = 0; mt < 4; ++mt) acc[mt] = (f32x4){0.f, 0.f, 0.f, 0.f};
  float lsum = 0.f;

  const __bf16* kp = kbh + (size_t)(b * NKV + kvh) * NM * 64;
  const __bf16* vp = vtb + (size_t)(b * NKV + kvh) * 64 * NM;
  const int src0 = ((lane >> 4) & 1) * 32 + ml;
  const int src1 = src0 + 16;
  const int sel = g >> 1;

  const int jt0 = split * (NT / NSPL);
  for (int jt = jt0; jt < jt0 + NT / NSPL; ++jt) {
    __syncthreads();
    {
      const int c = threadIdx.x;  // 512 chunks each for Ks and Vs
      const int lb = (w * 64) * 8;
      async16(kp + (size_t)(jt * 64 + ((c >> 7) << 4) + (c & 15)) * 64 +
                  (((c >> 6) & 1) << 5) + (((c >> 4) & 3) << 3),
              &Ks[lb]);
      async16(vp + (size_t)(((c >> 7) << 4) + (c & 15)) * NM + jt * 64 +
                  (((c >> 6) & 1) << 5) + (((c >> 4) & 3) << 3),
              &Vs[lb]);
    }
    __syncthreads();
    f32x4 S[4];
#pragma unroll
    for (int nt = 0; nt < 4; ++nt) {
      bf16x8 k0 = *(const bf16x8*)&Ks[(nt * 128 + lane) * 8];
      bf16x8 k1 = *(const bf16x8*)&Ks[(nt * 128 + 64 + lane) * 8];
      f32x4 s4 = (f32x4){0.f, 0.f, 0.f, 0.f};
      s4 = __builtin_amdgcn_mfma_f32_16x16x32_bf16(k0, qa0, s4, 0, 0, 0);
      s4 = __builtin_amdgcn_mfma_f32_16x16x32_bf16(k1, qa1, s4, 0, 0, 0);
      S[nt] = s4;
    }
    float p[4][4];
#pragma unroll
    for (int nt = 0; nt < 4; ++nt)
#pragma unroll
      for (int r = 0; r < 4; ++r) {
        p[nt][r] = __expf(S[nt][r]);
        lsum += p[nt][r];
      }
    unsigned pk[4][2];
#pragma unroll
    for (int nt = 0; nt < 4; ++nt) {
      pk[nt][0] = pk2(p[nt][0], p[nt][1]);
      pk[nt][1] = pk2(p[nt][2], p[nt][3]);
    }
    unsigned A00 = shu(pk[0][0], src0), A01 = shu(pk[0][1], src0);
    unsigned A10 = shu(pk[1][0], src0), A11 = shu(pk[1][1], src0);
    unsigned B00 = shu(pk[0][0], src1), B01 = shu(pk[0][1], src1);
    unsigned B10 = shu(pk[1][0], src1), B11 = shu(pk[1][1], src1);
    unsigned C00 = shu(pk[2][0], src0), C01 = shu(pk[2][1], src0);
    unsigned C10 = shu(pk[3][0], src0), C11 = shu(pk[3][1], src0);
    unsigned D00 = shu(pk[2][0], src1), D01 = shu(pk[2][1], src1);
    unsigned D10 = shu(pk[3][0], src1), D11 = shu(pk[3][1], src1);
    union { uint4 u; bf16x8 v; } P0, P1;
    P0.u.x = sel ? A10 : A00; P0.u.y = sel ? A11 : A01;
    P0.u.z = sel ? B10 : B00; P0.u.w = sel ? B11 : B01;
    P1.u.x = sel ? C10 : C00; P1.u.y = sel ? C11 : C01;
    P1.u.z = sel ? D10 : D00; P1.u.w = sel ? D11 : D01;
#pragma unroll
    for (int mt = 0; mt < 4; ++mt) {
      bf16x8 v0 = *(const bf16x8*)&Vs[(mt * 128 + lane) * 8];
      bf16x8 v1 = *(const bf16x8*)&Vs[(mt * 128 + 64 + lane) * 8];
      acc[mt] = __builtin_amdgcn_mfma_f32_16x16x32_bf16(v0, P0.v, acc[mt], 0, 0, 0);
      acc[mt] = __builtin_amdgcn_mfma_f32_16x16x32_bf16(v1, P1.v, acc[mt], 0, 0, 0);
    }
  }
  lsum += __shfl_xor(lsum, 16, 64);
  lsum += __shfl_xor(lsum, 32, 64);
  const size_t row = (size_t)(b * NH + h) * NM + qt + ml;
  if (g == 0) pl[row * NSPL + split] = lsum;
  __bf16* pa = pacc + (row * NSPL + split) * 64;
#pragma unroll
  for (int mt = 0; mt < 4; ++mt) {
    uint2 u;
    u.x = pk2(acc[mt][0], acc[mt][1]);
    u.y = pk2(acc[mt][2], acc[mt][3]);
    *reinterpret_cast<uint2*>(pa + mt * 16 + g * 4) = u;
  }
}

// ---------------------------------------------------------------------------
// Split-K combine (fixed shift: plain sums) -> bf16 attn_ob
// ---------------------------------------------------------------------------
__global__ __launch_bounds__(256) void attn_combine(
    const float* __restrict__ pl, const __bf16* __restrict__ pacc,
    __bf16* __restrict__ attn_ob) {
  const size_t rid = (size_t)blockIdx.x * 4 + (threadIdx.x >> 6);
  const int d = threadIdx.x & 63;
  float num = 0.f, den = 0.f;
#pragma unroll
  for (int s = 0; s < NSPL; ++s) {
    num += (float)pacc[(rid * NSPL + s) * 64 + d];
    den += pl[rid * NSPL + s];
  }
  float o = num / den;
  const int q = (int)(rid % NM);
  const int h = (int)((rid / NM) % NH);
  const int b = (int)(rid / ((size_t)NM * NH));
  attn_ob[((size_t)(b * NM + q)) * DM + h * 64 + d] = (__bf16)o;
}

// ---------------------------------------------------------------------------
extern "C" void kernel_launch(void* const* d_in, const int* in_sizes, int n_in,
                              void* d_out, int out_size, void* d_ws,
                              size_t ws_size, hipStream_t stream) {
  const float* x = (const float*)d_in[0];
  const float* fc = (const float*)d_in[1];
  const float* Wq = (const float*)d_in[2];
  const float* Wk = (const float*)d_in[3];
  const float* Wv = (const float*)d_in[4];
  const float* Wo = (const float*)d_in[5];
  float* out = (float*)d_out;

  char* ws = (char*)d_ws;
  size_t off = 0;
  auto alloc = [&](size_t bytes) {
    void* p = ws + off;
    off += (bytes + 255) & ~(size_t)255;
    return p;
  };
  float* metric0 = (float*)alloc((size_t)BB * NN * 256 * 4);
  float* metric1 = (float*)alloc((size_t)BB * NN * 256 * 4);
  float* best_s = (float*)alloc((size_t)BB * HALF * 4);
  int* best_b = (int*)alloc((size_t)BB * HALF * 4);
  int* order = (int*)alloc((size_t)BB * HALF * 4);
  int* keep_idx = (int*)alloc((size_t)BB * NM * 4);
  int* partner = (int*)alloc((size_t)BB * NN * 4);
  int* dst2 = (int*)alloc((size_t)BB * NM * 4);
  float* sval = (float*)alloc((size_t)BB * HALF * 16 * 4);
  int* sidx = (int*)alloc((size_t)BB * HALF * 16 * 4);
  char* bigreg = (char*)alloc((size_t)30 * 1024 * 1024);
  __bf16* xh = (__bf16*)bigreg;
  __bf16* xl = (__bf16*)(bigreg + (size_t)8704 * 1024);
  __bf16* anh = (__bf16*)bigreg;
  __bf16* anl = (__bf16*)(bigreg + (size_t)1100 * 1024);
  __bf16* bnh = (__bf16*)(bigreg + (size_t)2200 * 1024);
  __bf16* bnl = (__bf16*)(bigreg + (size_t)3300 * 1024);
  float* qkv = (float*)bigreg;
  __bf16* pacc = (__bf16*)bigreg;
  __bf16* x_mb = (__bf16*)alloc((size_t)BB * NM * DM * 2);
  __bf16* qbh = (__bf16*)alloc((size_t)BB * NH * NM * 64 * 2);
  __bf16* kbh = (__bf16*)alloc((size_t)BB * NKV * NM * 64 * 2);
  __bf16* vtb = (__bf16*)alloc((size_t)BB * NKV * 64 * NM * 2);
  __bf16* attn_ob = (__bf16*)alloc((size_t)BB * NM * DM * 2);
  float* pl = (float*)alloc((size_t)BB * NH * NM * NSPL * 4);
  __bf16* Wqkvt = (__bf16*)alloc((size_t)1536 * DM * 2);
  __bf16* Wktl = (__bf16*)alloc((size_t)256 * DM * 2);
  __bf16* Wot = (__bf16*)alloc((size_t)DM * DM * 2);
  const __bf16* Wkth = Wqkvt + (size_t)1024 * 1024;

  transpose_all<<<640, 256, 0, stream>>>(Wq, Wk, Wv, Wo, Wqkvt, Wktl, Wot);
  hilo_split<<<(BB * NN * DM / 4) / 256, 256, 0, stream>>>(x, xh, xl);
  gemm3t<<<dim3(64, 4, 2), 256, 0, stream>>>(xh, xl, Wkth, Wktl, metric0,
                                             metric1, BB * NN, 256, DM);
  normalize_split<<<BB * NN, 256, 0, stream>>>(metric0, metric1, anh, anl, bnh,
                                               bnl);
  gemm_scam<<<dim3(16, 16, 2), 256, 0, stream>>>(anh, anl, bnh, bnl, sval,
                                                 sidx);
  argmax_reduce<<<(BB * HALF) / 16, 256, 0, stream>>>(sval, sidx, best_s,
                                                      best_b);
  sort_desc<<<BB, 512, 0, stream>>>(best_s, order);
  select_and_index<<<BB, 256, 0, stream>>>(best_b, order, keep_idx, partner,
                                           dst2);
  merge_kernel<<<BB * NM, 256, 0, stream>>>(x, keep_idx, partner, x_mb);
  gemm_bf16<<<dim3(28, 24), 256, 0, stream>>>(x_mb, Wqkvt, qkv, BB * NM, 1536,
                                              DM);
  rope_fused<<<BB * NM, 256, 0, stream>>>(qkv, fc, qbh, kbh);
  v_repack<<<BB * NKV * (NM / 64), 256, 0, stream>>>(qkv, vtb);
  attn_mfma<<<BB * NKV * NSPL * (NM / 32), 512, 0, stream>>>(qbh, kbh, vtb, pl,
                                                             pacc);
  attn_combine<<<(BB * NH * NM) / 4, 256, 0, stream>>>(pl, pacc, attn_ob);
  gemm_wo<<<dim3(28, 16), 256, 0, stream>>>(attn_ob, Wot, keep_idx, dst2, out,
                                            BB * NM, DM, DM);
}